// Round 1
// baseline (9597.569 us; speedup 1.0000x reference)
//
#include <hip/hip_runtime.h>
#include <math.h>

#define N_NODES 50000
#define N_EDGES 500000
#define G_GRAPHS 100
#define NPG 500
#define NPROT 400
#define H 128
#define PN 35
#define LN 11
#define DIN 261      // 2H + 1 + 4
#define KPAD 288     // 9 blocks of 32
#define NKB 9
#define EB 16        // edges per workgroup
#define NB 16        // nodes per workgroup
#define EPSV 1e-5f

__device__ __forceinline__ float silu_f(float x) {
    return x / (1.0f + __expf(-x));
}

// ---------------- projection ----------------
__global__ __launch_bounds__(128) void proj_kernel(
    const float* __restrict__ x, const float* __restrict__ Wp, const float* __restrict__ bp,
    const float* __restrict__ Wl, const float* __restrict__ bl, float* __restrict__ h)
{
    __shared__ float xs[NB][36];
    int tid = threadIdx.x;
    int n0 = blockIdx.x * NB;
    for (int idx = tid; idx < NB * PN; idx += 128) {
        int n = idx / PN, k = idx % PN;
        xs[n][k] = x[(size_t)(n0 + n) * PN + k];
    }
    __syncthreads();
    for (int n = 0; n < NB; n++) {
        int node = n0 + n;
        bool isp = (node % NPG) < NPROT;
        float acc;
        if (isp) {
            acc = bp[tid];
            for (int k = 0; k < PN; k++) acc = fmaf(xs[n][k], Wp[k * H + tid], acc);
        } else {
            acc = bl[tid];
            for (int k = 0; k < LN; k++) acc = fmaf(xs[n][k], Wl[k * H + tid], acc);
        }
        h[(size_t)node * H + tid] = acc;
    }
}

// ---------------- batchnorm ----------------
__global__ __launch_bounds__(128) void bn_stats_kernel(const float* __restrict__ h, float* __restrict__ bnS)
{
    int tid = threadIdx.x;
    size_t base = (size_t)blockIdx.x * NPG * H;
    float s1 = 0.f, s2 = 0.f;
    for (int i = 0; i < NPG; i++) {
        float v = h[base + (size_t)i * H + tid];
        s1 += v; s2 += v * v;
    }
    atomicAdd(&bnS[tid], s1);
    atomicAdd(&bnS[H + tid], s2);
}

__global__ void bn_final_kernel(const float* __restrict__ bnS, const float* __restrict__ gamma,
                                const float* __restrict__ beta, float* __restrict__ bnP)
{
    int j = threadIdx.x;
    float mu = bnS[j] / (float)N_NODES;
    float var = bnS[H + j] / (float)N_NODES - mu * mu;
    float inv = rsqrtf(var + EPSV);
    float sc = gamma[j] * inv;
    bnP[j] = sc;
    bnP[H + j] = beta[j] - mu * sc;
}

__global__ __launch_bounds__(256) void bn_apply_kernel(float* __restrict__ h, const float* __restrict__ bnP)
{
    int idx = blockIdx.x * 256 + threadIdx.x;   // float4 index, total N*H/4
    float4 v = ((float4*)h)[idx];
    int j4 = (idx & 31) * 4;
    v.x = fmaf(v.x, bnP[j4 + 0], bnP[H + j4 + 0]);
    v.y = fmaf(v.y, bnP[j4 + 1], bnP[H + j4 + 1]);
    v.z = fmaf(v.z, bnP[j4 + 2], bnP[H + j4 + 2]);
    v.w = fmaf(v.w, bnP[j4 + 3], bnP[H + j4 + 3]);
    ((float4*)h)[idx] = v;
}

// ---------------- degree ----------------
__global__ void deg_kernel(const int* __restrict__ ei, float* __restrict__ deg)
{
    int e = blockIdx.x * 256 + threadIdx.x;
    if (e < N_EDGES) atomicAdd(&deg[ei[e]], 1.0f);
}

// ---------------- edge MLP + scatter ----------------
__global__ __launch_bounds__(128) void edge_kernel(
    const float* __restrict__ pos, const float* __restrict__ h,
    const int* __restrict__ ei, const float* __restrict__ eattr,
    const float* __restrict__ ew1, const float* __restrict__ eb1,
    const float* __restrict__ ew2, const float* __restrict__ eb2,
    const float* __restrict__ cw1, const float* __restrict__ cb1,
    const float* __restrict__ cw2,
    float* __restrict__ magg, float* __restrict__ posagg)
{
    __shared__ float feat[EB][KPAD];   // 18.4 KB
    __shared__ float4 wt[8 * H];       // 16 KB (32-k slab, transposed by 4)
    __shared__ float t1[EB][H];        // 8 KB
    __shared__ float t2[EB][H];        // 8 KB
    __shared__ float relS[EB][4];
    __shared__ float wS[EB];
    __shared__ int rowS[EB], colS[EB];

    int tid = threadIdx.x;
    int e0 = blockIdx.x * EB;

    if (tid < EB) {
        int e = e0 + tid;
        int r = ei[e], c = ei[N_EDGES + e];
        rowS[tid] = r; colS[tid] = c;
        float rx = pos[r * 3 + 0] - pos[c * 3 + 0];
        float ry = pos[r * 3 + 1] - pos[c * 3 + 1];
        float rz = pos[r * 3 + 2] - pos[c * 3 + 2];
        relS[tid][0] = rx; relS[tid][1] = ry; relS[tid][2] = rz;
        feat[tid][2 * H]     = rx * rx + ry * ry + rz * rz;
        feat[tid][2 * H + 1] = eattr[e * 4 + 0];
        feat[tid][2 * H + 2] = eattr[e * 4 + 1];
        feat[tid][2 * H + 3] = eattr[e * 4 + 2];
        feat[tid][2 * H + 4] = eattr[e * 4 + 3];
    }
    if (tid < KPAD - DIN) {
        for (int e = 0; e < EB; e++) feat[e][DIN + tid] = 0.0f;
    }
    __syncthreads();
    for (int e = 0; e < EB; e++) {
        feat[e][tid]     = h[(size_t)rowS[e] * H + tid];
        feat[e][H + tid] = h[(size_t)colS[e] * H + tid];
    }

    int c = tid & 63;
    int half = tid >> 6;   // wave 0 -> edges 0..7, wave 1 -> edges 8..15
    float acc0[8], acc1[8];

    // ---- stage B: t1 = silu(feat @ ew1 + eb1), K = 261 (padded 288) ----
    #pragma unroll
    for (int e = 0; e < 8; e++) { acc0[e] = 0.f; acc1[e] = 0.f; }
    for (int kb = 0; kb < NKB; kb++) {
        __syncthreads();
        #pragma unroll
        for (int q = 0; q < 8; q++) {
            int k0 = kb * 32 + q * 4;
            float4 w4;
            w4.x = (k0 + 0 < DIN) ? ew1[(k0 + 0) * H + tid] : 0.0f;
            w4.y = (k0 + 1 < DIN) ? ew1[(k0 + 1) * H + tid] : 0.0f;
            w4.z = (k0 + 2 < DIN) ? ew1[(k0 + 2) * H + tid] : 0.0f;
            w4.w = (k0 + 3 < DIN) ? ew1[(k0 + 3) * H + tid] : 0.0f;
            wt[q * H + tid] = w4;
        }
        __syncthreads();
        #pragma unroll
        for (int q = 0; q < 8; q++) {
            float4 wa = wt[q * H + c];
            float4 wb = wt[q * H + c + 64];
            int k0 = kb * 32 + q * 4;
            #pragma unroll
            for (int e = 0; e < 8; e++) {
                const float4 f = *(const float4*)&feat[half * 8 + e][k0];
                acc0[e] = fmaf(f.x, wa.x, fmaf(f.y, wa.y, fmaf(f.z, wa.z, fmaf(f.w, wa.w, acc0[e]))));
                acc1[e] = fmaf(f.x, wb.x, fmaf(f.y, wb.y, fmaf(f.z, wb.z, fmaf(f.w, wb.w, acc1[e]))));
            }
        }
    }
    {
        float bb0 = eb1[c], bb1 = eb1[c + 64];
        #pragma unroll
        for (int e = 0; e < 8; e++) {
            t1[half * 8 + e][c]      = silu_f(acc0[e] + bb0);
            t1[half * 8 + e][c + 64] = silu_f(acc1[e] + bb1);
        }
    }

    // ---- stage C: t2 = silu(t1 @ ew2 + eb2), K = 128 ----
    #pragma unroll
    for (int e = 0; e < 8; e++) { acc0[e] = 0.f; acc1[e] = 0.f; }
    for (int kb = 0; kb < 4; kb++) {
        __syncthreads();
        #pragma unroll
        for (int q = 0; q < 8; q++) {
            int k0 = kb * 32 + q * 4;
            float4 w4;
            w4.x = ew2[(k0 + 0) * H + tid];
            w4.y = ew2[(k0 + 1) * H + tid];
            w4.z = ew2[(k0 + 2) * H + tid];
            w4.w = ew2[(k0 + 3) * H + tid];
            wt[q * H + tid] = w4;
        }
        __syncthreads();
        #pragma unroll
        for (int q = 0; q < 8; q++) {
            float4 wa = wt[q * H + c];
            float4 wb = wt[q * H + c + 64];
            int k0 = kb * 32 + q * 4;
            #pragma unroll
            for (int e = 0; e < 8; e++) {
                const float4 f = *(const float4*)&t1[half * 8 + e][k0];
                acc0[e] = fmaf(f.x, wa.x, fmaf(f.y, wa.y, fmaf(f.z, wa.z, fmaf(f.w, wa.w, acc0[e]))));
                acc1[e] = fmaf(f.x, wb.x, fmaf(f.y, wb.y, fmaf(f.z, wb.z, fmaf(f.w, wb.w, acc1[e]))));
            }
        }
    }
    {
        float bb0 = eb2[c], bb1 = eb2[c + 64];
        #pragma unroll
        for (int e = 0; e < 8; e++) {
            t2[half * 8 + e][c]      = silu_f(acc0[e] + bb0);
            t2[half * 8 + e][c + 64] = silu_f(acc1[e] + bb1);
        }
    }

    // ---- stage D: w = silu(t2 @ cw1 + cb1) @ cw2 ----
    #pragma unroll
    for (int e = 0; e < 8; e++) { acc0[e] = 0.f; acc1[e] = 0.f; }
    for (int kb = 0; kb < 4; kb++) {
        __syncthreads();
        #pragma unroll
        for (int q = 0; q < 8; q++) {
            int k0 = kb * 32 + q * 4;
            float4 w4;
            w4.x = cw1[(k0 + 0) * H + tid];
            w4.y = cw1[(k0 + 1) * H + tid];
            w4.z = cw1[(k0 + 2) * H + tid];
            w4.w = cw1[(k0 + 3) * H + tid];
            wt[q * H + tid] = w4;
        }
        __syncthreads();
        #pragma unroll
        for (int q = 0; q < 8; q++) {
            float4 wa = wt[q * H + c];
            float4 wb = wt[q * H + c + 64];
            int k0 = kb * 32 + q * 4;
            #pragma unroll
            for (int e = 0; e < 8; e++) {
                const float4 f = *(const float4*)&t2[half * 8 + e][k0];
                acc0[e] = fmaf(f.x, wa.x, fmaf(f.y, wa.y, fmaf(f.z, wa.z, fmaf(f.w, wa.w, acc0[e]))));
                acc1[e] = fmaf(f.x, wb.x, fmaf(f.y, wb.y, fmaf(f.z, wb.z, fmaf(f.w, wb.w, acc1[e]))));
            }
        }
    }
    {
        float bb0 = cb1[c], bb1 = cb1[c + 64];
        float c2a = cw2[c], c2b = cw2[c + 64];
        #pragma unroll
        for (int e = 0; e < 8; e++) {
            float v = silu_f(acc0[e] + bb0) * c2a + silu_f(acc1[e] + bb1) * c2b;
            #pragma unroll
            for (int off = 32; off > 0; off >>= 1) v += __shfl_xor(v, off, 64);
            if (c == 0) wS[half * 8 + e] = v;
        }
    }
    __syncthreads();

    // ---- stage E: scatter ----
    for (int e = 0; e < EB; e++) {
        atomicAdd(&magg[(size_t)rowS[e] * H + tid], t2[e][tid]);
    }
    if (tid < EB * 3) {
        int e = tid / 3, ax = tid % 3;
        atomicAdd(&posagg[rowS[e] * 3 + ax], relS[e][ax] * wS[e]);
    }
}

// ---------------- node update ----------------
__global__ __launch_bounds__(128) void node_kernel(
    float* __restrict__ h, const float* __restrict__ magg,
    const float* __restrict__ posagg, const float* __restrict__ deg,
    float* __restrict__ pos,
    const float* __restrict__ nw1, const float* __restrict__ nb1,
    const float* __restrict__ nw2, const float* __restrict__ nb2)
{
    __shared__ float cat[NB][256];   // 16 KB
    __shared__ float4 wt[8 * H];     // 16 KB
    __shared__ float u1[NB][H];      // 8 KB
    int tid = threadIdx.x;
    int n0 = blockIdx.x * NB;

    if (tid < NB * 3) {
        int n = tid / 3, ax = tid % 3;
        int node = n0 + n;
        float d = fmaxf(deg[node], 1.0f);
        pos[node * 3 + ax] += posagg[node * 3 + ax] / d;
    }
    for (int n = 0; n < NB; n++) {
        cat[n][tid]     = h[(size_t)(n0 + n) * H + tid];
        cat[n][H + tid] = magg[(size_t)(n0 + n) * H + tid];
    }

    int c = tid & 63;
    int half = tid >> 6;
    float acc0[8], acc1[8];

    #pragma unroll
    for (int e = 0; e < 8; e++) { acc0[e] = 0.f; acc1[e] = 0.f; }
    for (int kb = 0; kb < 8; kb++) {          // K = 256
        __syncthreads();
        #pragma unroll
        for (int q = 0; q < 8; q++) {
            int k0 = kb * 32 + q * 4;
            float4 w4;
            w4.x = nw1[(k0 + 0) * H + tid];
            w4.y = nw1[(k0 + 1) * H + tid];
            w4.z = nw1[(k0 + 2) * H + tid];
            w4.w = nw1[(k0 + 3) * H + tid];
            wt[q * H + tid] = w4;
        }
        __syncthreads();
        #pragma unroll
        for (int q = 0; q < 8; q++) {
            float4 wa = wt[q * H + c];
            float4 wb = wt[q * H + c + 64];
            int k0 = kb * 32 + q * 4;
            #pragma unroll
            for (int e = 0; e < 8; e++) {
                const float4 f = *(const float4*)&cat[half * 8 + e][k0];
                acc0[e] = fmaf(f.x, wa.x, fmaf(f.y, wa.y, fmaf(f.z, wa.z, fmaf(f.w, wa.w, acc0[e]))));
                acc1[e] = fmaf(f.x, wb.x, fmaf(f.y, wb.y, fmaf(f.z, wb.z, fmaf(f.w, wb.w, acc1[e]))));
            }
        }
    }
    {
        float bb0 = nb1[c], bb1 = nb1[c + 64];
        #pragma unroll
        for (int e = 0; e < 8; e++) {
            u1[half * 8 + e][c]      = silu_f(acc0[e] + bb0);
            u1[half * 8 + e][c + 64] = silu_f(acc1[e] + bb1);
        }
    }

    #pragma unroll
    for (int e = 0; e < 8; e++) { acc0[e] = 0.f; acc1[e] = 0.f; }
    for (int kb = 0; kb < 4; kb++) {          // K = 128
        __syncthreads();
        #pragma unroll
        for (int q = 0; q < 8; q++) {
            int k0 = kb * 32 + q * 4;
            float4 w4;
            w4.x = nw2[(k0 + 0) * H + tid];
            w4.y = nw2[(k0 + 1) * H + tid];
            w4.z = nw2[(k0 + 2) * H + tid];
            w4.w = nw2[(k0 + 3) * H + tid];
            wt[q * H + tid] = w4;
        }
        __syncthreads();
        #pragma unroll
        for (int q = 0; q < 8; q++) {
            float4 wa = wt[q * H + c];
            float4 wb = wt[q * H + c + 64];
            int k0 = kb * 32 + q * 4;
            #pragma unroll
            for (int e = 0; e < 8; e++) {
                const float4 f = *(const float4*)&u1[half * 8 + e][k0];
                acc0[e] = fmaf(f.x, wa.x, fmaf(f.y, wa.y, fmaf(f.z, wa.z, fmaf(f.w, wa.w, acc0[e]))));
                acc1[e] = fmaf(f.x, wb.x, fmaf(f.y, wb.y, fmaf(f.z, wb.z, fmaf(f.w, wb.w, acc1[e]))));
            }
        }
    }
    {
        float bb0 = nb2[c], bb1 = nb2[c + 64];
        #pragma unroll
        for (int e = 0; e < 8; e++) {
            int node = n0 + half * 8 + e;
            h[(size_t)node * H + c]      += acc0[e] + bb0;
            h[(size_t)node * H + c + 64] += acc1[e] + bb1;
        }
    }
}

// ---------------- pooling + head ----------------
__global__ __launch_bounds__(128) void head_kernel(
    const float* __restrict__ h,
    const float* __restrict__ h1w, const float* __restrict__ h1b,
    const float* __restrict__ h2w, const float* __restrict__ h2b,
    const float* __restrict__ h3w, const float* __restrict__ h3b,
    float* __restrict__ out)
{
    __shared__ float gfeat[256];
    __shared__ float z1[128];
    __shared__ float z2[64];
    int tid = threadIdx.x;
    int g = blockIdx.x;
    size_t base = (size_t)g * NPG * H;
    float s = 0.f;
    for (int i = 0; i < NPG; i++) s += h[base + (size_t)i * H + tid];
    gfeat[tid] = s;
    gfeat[H + tid] = s / (float)NPG;
    __syncthreads();
    float a = h1b[tid];
    for (int k = 0; k < 256; k++) a = fmaf(gfeat[k], h1w[k * H + tid], a);
    z1[tid] = fmaxf(a, 0.0f);
    __syncthreads();
    if (tid < 64) {
        float a2 = h2b[tid];
        for (int k = 0; k < 128; k++) a2 = fmaf(z1[k], h2w[k * 64 + tid], a2);
        z2[tid] = fmaxf(a2, 0.0f);
    }
    __syncthreads();
    if (tid < 64) {
        float v = z2[tid] * h3w[tid];
        #pragma unroll
        for (int off = 32; off > 0; off >>= 1) v += __shfl_xor(v, off, 64);
        if (tid == 0) out[g] = v + h3b[0];
    }
}

extern "C" void kernel_launch(void* const* d_in, const int* in_sizes, int n_in,
                              void* d_out, int out_size, void* d_ws, size_t ws_size,
                              hipStream_t stream) {
    const float* x      = (const float*)d_in[0];
    const float* pos_in = (const float*)d_in[1];
    const int*   ei     = (const int*)d_in[2];
    const float* eattr  = (const float*)d_in[3];
    // d_in[4]=batch, d_in[5]=is_protein: derived arithmetically instead
    const float* Wp    = (const float*)d_in[6];
    const float* bp    = (const float*)d_in[7];
    const float* Wl    = (const float*)d_in[8];
    const float* bl    = (const float*)d_in[9];
    const float* gamma = (const float*)d_in[10];
    const float* beta  = (const float*)d_in[11];
    const float* ew1   = (const float*)d_in[12];
    const float* eb1   = (const float*)d_in[13];
    const float* ew2   = (const float*)d_in[14];
    const float* eb2   = (const float*)d_in[15];
    const float* cw1   = (const float*)d_in[16];
    const float* cb1   = (const float*)d_in[17];
    const float* cw2   = (const float*)d_in[18];
    const float* nw1   = (const float*)d_in[19];
    const float* nb1   = (const float*)d_in[20];
    const float* nw2   = (const float*)d_in[21];
    const float* nb2   = (const float*)d_in[22];
    const float* h1w   = (const float*)d_in[23];
    const float* h1b   = (const float*)d_in[24];
    const float* h2w   = (const float*)d_in[25];
    const float* h2b   = (const float*)d_in[26];
    const float* h3w   = (const float*)d_in[27];
    const float* h3b   = (const float*)d_in[28];
    float* out = (float*)d_out;

    float* ws   = (float*)d_ws;
    float* hbuf = ws;                                  // N*H
    float* magg = hbuf + (size_t)N_NODES * H;          // N*H
    float* posb = magg + (size_t)N_NODES * H;          // N*3
    float* pagg = posb + (size_t)N_NODES * 3;          // N*3
    float* deg  = pagg + (size_t)N_NODES * 3;          // N
    float* bnS  = deg + N_NODES;                       // 256
    float* bnP  = bnS + 256;                           // 256

    hipMemcpyAsync(posb, pos_in, (size_t)N_NODES * 3 * sizeof(float),
                   hipMemcpyDeviceToDevice, stream);
    hipMemsetAsync(deg, 0, N_NODES * sizeof(float), stream);
    hipMemsetAsync(bnS, 0, 256 * sizeof(float), stream);

    proj_kernel<<<N_NODES / NB, 128, 0, stream>>>(x, Wp, bp, Wl, bl, hbuf);
    bn_stats_kernel<<<N_NODES / NPG, 128, 0, stream>>>(hbuf, bnS);
    bn_final_kernel<<<1, 128, 0, stream>>>(bnS, gamma, beta, bnP);
    bn_apply_kernel<<<(N_NODES * H / 4) / 256, 256, 0, stream>>>(hbuf, bnP);
    deg_kernel<<<(N_EDGES + 255) / 256, 256, 0, stream>>>(ei, deg);

    for (int l = 0; l < 4; l++) {
        hipMemsetAsync(magg, 0, (size_t)N_NODES * H * sizeof(float), stream);
        hipMemsetAsync(pagg, 0, (size_t)N_NODES * 3 * sizeof(float), stream);
        edge_kernel<<<N_EDGES / EB, 128, 0, stream>>>(
            posb, hbuf, ei, eattr,
            ew1 + (size_t)l * DIN * H, eb1 + (size_t)l * H,
            ew2 + (size_t)l * H * H,  eb2 + (size_t)l * H,
            cw1 + (size_t)l * H * H,  cb1 + (size_t)l * H,
            cw2 + (size_t)l * H,
            magg, pagg);
        node_kernel<<<N_NODES / NB, 128, 0, stream>>>(
            hbuf, magg, pagg, deg, posb,
            nw1 + (size_t)l * 2 * H * H, nb1 + (size_t)l * H,
            nw2 + (size_t)l * H * H,     nb2 + (size_t)l * H);
    }

    head_kernel<<<G_GRAPHS, 128, 0, stream>>>(hbuf, h1w, h1b, h2w, h2b, h3w, h3b, out);
}

// Round 3
// 4210.115 us; speedup vs baseline: 2.2796x; 2.2796x over previous
//
#include <hip/hip_runtime.h>
#include <math.h>

#define N_NODES 50000
#define N_EDGES 500000
#define G_GRAPHS 100
#define NPG 500
#define NPROT 400
#define H 128
#define PN 35
#define LN 11
#define DIN 261      // 2H + 1 + 4
#define KP1 288      // stage-1 K padded to 9 slabs of 32
#define NKB1 9
#define EB2 32       // edges per block (MFMA edge kernel)
#define FST 292      // featA row stride in fp32 (292%32=4 -> 2-way bank alias, free)
#define WSTR 40      // weight slab row stride in bf16 (80B = 20 dw -> 2-way free)
#define NB 16        // nodes per workgroup (node kernel)
#define EPSV 1e-5f

typedef __attribute__((ext_vector_type(8))) short bf8_t;   // 8 bf16 (4 VGPRs)
typedef __attribute__((ext_vector_type(4))) float f4_t;

__device__ __forceinline__ float silu_f(float x) {
    return x / (1.0f + __expf(-x));
}
__device__ __forceinline__ short f2b(float f) {
    __bf16 b = (__bf16)f;                 // RNE hardware cvt
    return __builtin_bit_cast(short, b);
}
__device__ __forceinline__ float b2f(short s) {
    unsigned u = ((unsigned)(unsigned short)s) << 16;
    return __builtin_bit_cast(float, u);
}

// ---------------- weight prep: transpose + split fp32 -> bf16 hi/lo ----------------
// src: [L=4][K][H], dstH/dstL: [L=4][H][Kpad]
__global__ void wprep_kernel(const float* __restrict__ src, short* __restrict__ dstH,
                             short* __restrict__ dstL, int K, int Kpad) {
    int idx = blockIdx.x * 256 + threadIdx.x;
    int total = 4 * H * Kpad;
    if (idx >= total) return;
    int l = idx / (H * Kpad);
    int rem = idx - l * (H * Kpad);
    int n = rem / Kpad;
    int k = rem - n * Kpad;
    float v = (k < K) ? src[((size_t)l * K + k) * H + n] : 0.0f;
    short hi = f2b(v);
    float r = v - b2f(hi);
    dstH[idx] = hi;
    dstL[idx] = f2b(r);
}

// ---------------- projection ----------------
__global__ __launch_bounds__(128) void proj_kernel(
    const float* __restrict__ x, const float* __restrict__ Wp, const float* __restrict__ bp,
    const float* __restrict__ Wl, const float* __restrict__ bl, float* __restrict__ h)
{
    __shared__ float xs[NB][36];
    int tid = threadIdx.x;
    int n0 = blockIdx.x * NB;
    for (int idx = tid; idx < NB * PN; idx += 128) {
        int n = idx / PN, k = idx % PN;
        xs[n][k] = x[(size_t)(n0 + n) * PN + k];
    }
    __syncthreads();
    for (int n = 0; n < NB; n++) {
        int node = n0 + n;
        bool isp = (node % NPG) < NPROT;
        float acc;
        if (isp) {
            acc = bp[tid];
            for (int k = 0; k < PN; k++) acc = fmaf(xs[n][k], Wp[k * H + tid], acc);
        } else {
            acc = bl[tid];
            for (int k = 0; k < LN; k++) acc = fmaf(xs[n][k], Wl[k * H + tid], acc);
        }
        h[(size_t)node * H + tid] = acc;
    }
}

// ---------------- batchnorm ----------------
__global__ __launch_bounds__(128) void bn_stats_kernel(const float* __restrict__ h, float* __restrict__ bnS)
{
    int tid = threadIdx.x;
    size_t base = (size_t)blockIdx.x * NPG * H;
    float s1 = 0.f, s2 = 0.f;
    for (int i = 0; i < NPG; i++) {
        float v = h[base + (size_t)i * H + tid];
        s1 += v; s2 += v * v;
    }
    atomicAdd(&bnS[tid], s1);
    atomicAdd(&bnS[H + tid], s2);
}

__global__ void bn_final_kernel(const float* __restrict__ bnS, const float* __restrict__ gamma,
                                const float* __restrict__ beta, float* __restrict__ bnP)
{
    int j = threadIdx.x;
    float mu = bnS[j] / (float)N_NODES;
    float var = bnS[H + j] / (float)N_NODES - mu * mu;
    float inv = rsqrtf(var + EPSV);
    float sc = gamma[j] * inv;
    bnP[j] = sc;
    bnP[H + j] = beta[j] - mu * sc;
}

__global__ __launch_bounds__(256) void bn_apply_kernel(float* __restrict__ h, const float* __restrict__ bnP)
{
    int idx = blockIdx.x * 256 + threadIdx.x;
    float4 v = ((float4*)h)[idx];
    int j4 = (idx & 31) * 4;
    v.x = fmaf(v.x, bnP[j4 + 0], bnP[H + j4 + 0]);
    v.y = fmaf(v.y, bnP[j4 + 1], bnP[H + j4 + 1]);
    v.z = fmaf(v.z, bnP[j4 + 2], bnP[H + j4 + 2]);
    v.w = fmaf(v.w, bnP[j4 + 3], bnP[H + j4 + 3]);
    ((float4*)h)[idx] = v;
}

// ---------------- degree ----------------
__global__ void deg_kernel(const int* __restrict__ ei, float* __restrict__ deg)
{
    int e = blockIdx.x * 256 + threadIdx.x;
    if (e < N_EDGES) atomicAdd(&deg[ei[e]], 1.0f);
}

// ---------------- MFMA edge kernel (hi/lo split bf16, fp32-equivalent) ----------------
// One 16x16x32 product tile per wave: m0 = (wv&1)*16, n half = (wv>>1)*64.
__device__ __forceinline__ void mm_stage(
    float* featA, short* slabH, short* slabL,
    const short* __restrict__ Wh, const short* __restrict__ Wl,
    int nkb, int kt, int tid, int m0, int wn0, int ln, int quad, f4_t acc[4])
{
    #pragma unroll
    for (int ni = 0; ni < 4; ni++) acc[ni] = (f4_t)(0.0f);
    for (int kb = 0; kb < nkb; kb++) {
        __syncthreads();
        // stage hi+lo 128x32 slabs: 2 planes x 512 16B-chunks = 1024 over 256 thr
        for (int c2 = tid; c2 < 1024; c2 += 256) {
            int pl = c2 >> 9;
            int r = (c2 >> 2) & 127, q = c2 & 3;
            const short* W = pl ? Wl : Wh;
            short* s = pl ? slabL : slabH;
            *(bf8_t*)&s[r * WSTR + q * 8] = *(const bf8_t*)&W[r * kt + kb * 32 + q * 8];
        }
        __syncthreads();
        const float* ar = &featA[(m0 + ln) * FST + kb * 32 + quad * 8];
        f4_t f0 = *(const f4_t*)ar;
        f4_t f1 = *(const f4_t*)(ar + 4);
        bf8_t ah, al;
        #pragma unroll
        for (int j = 0; j < 4; j++) {
            ah[j] = f2b(f0[j]);     al[j] = f2b(f0[j] - b2f(ah[j]));
            ah[4 + j] = f2b(f1[j]); al[4 + j] = f2b(f1[j] - b2f(ah[4 + j]));
        }
        #pragma unroll
        for (int ni = 0; ni < 4; ni++) {
            int rr = (wn0 + ni * 16 + ln) * WSTR + quad * 8;
            bf8_t bh = *(const bf8_t*)&slabH[rr];
            bf8_t bl = *(const bf8_t*)&slabL[rr];
            acc[ni] = __builtin_amdgcn_mfma_f32_16x16x32_bf16(ah, bh, acc[ni], 0, 0, 0);
            acc[ni] = __builtin_amdgcn_mfma_f32_16x16x32_bf16(al, bh, acc[ni], 0, 0, 0);
            acc[ni] = __builtin_amdgcn_mfma_f32_16x16x32_bf16(ah, bl, acc[ni], 0, 0, 0);
        }
    }
    __syncthreads();   // all reads of featA/slab done before caller overwrites featA
}

__global__ __launch_bounds__(256, 2) void edge_mfma_kernel(
    const float* __restrict__ h, const float* __restrict__ pos,
    const int* __restrict__ ei, const float* __restrict__ eattr,
    const short* __restrict__ W1h, const short* __restrict__ W1l,
    const short* __restrict__ W2h, const short* __restrict__ W2l,
    const short* __restrict__ W3h, const short* __restrict__ W3l,
    const float* __restrict__ eb1, const float* __restrict__ eb2,
    const float* __restrict__ cb1, const float* __restrict__ cw2,
    float* __restrict__ magg, float* __restrict__ pagg)
{
    __shared__ __align__(16) float featA[EB2 * FST];   // 37376 B (fp32 feats, then t1/t2)
    __shared__ __align__(16) short slabH[H * WSTR];    // 10240 B
    __shared__ __align__(16) short slabL[H * WSTR];    // 10240 B
    __shared__ float relS[EB2][3];
    __shared__ float wpart[EB2][2];
    __shared__ int rowS[EB2];
    __shared__ int colS[EB2];

    int tid = threadIdx.x;
    int e0 = blockIdx.x * EB2;

    // --- edge meta: rel, d2, attr, zero-pad (fp32) ---
    if (tid < EB2) {
        int e = e0 + tid;
        int ec = (e < N_EDGES) ? e : (N_EDGES - 1);
        int r = ei[ec], c = ei[N_EDGES + ec];
        rowS[tid] = r; colS[tid] = c;
        float rx = pos[r * 3 + 0] - pos[c * 3 + 0];
        float ry = pos[r * 3 + 1] - pos[c * 3 + 1];
        float rz = pos[r * 3 + 2] - pos[c * 3 + 2];
        relS[tid][0] = rx; relS[tid][1] = ry; relS[tid][2] = rz;
        float* fr = &featA[tid * FST + 2 * H];
        fr[0] = rx * rx + ry * ry + rz * rz;
        fr[1] = eattr[(size_t)ec * 4 + 0];
        fr[2] = eattr[(size_t)ec * 4 + 1];
        fr[3] = eattr[(size_t)ec * 4 + 2];
        fr[4] = eattr[(size_t)ec * 4 + 3];
        for (int k2 = 5; k2 < KP1 - 2 * H; k2++) fr[k2] = 0.0f;   // cols 261..287
    }
    __syncthreads();

    // --- gather h[row], h[col] fp32 into featA cols 0..255 ---
    for (int i = tid; i < 2 * EB2 * (H / 4); i += 256) {   // 2048 float4 chunks
        int rrow = i >> 5, chunk = i & 31;
        int eidx = rrow & (EB2 - 1);
        int node = (rrow < EB2) ? rowS[eidx] : colS[eidx];
        f4_t v = *(const f4_t*)&h[(size_t)node * H + chunk * 4];
        *(f4_t*)&featA[eidx * FST + ((rrow < EB2) ? 0 : H) + chunk * 4] = v;
    }

    int lane = tid & 63;
    int wv = tid >> 6;
    int ln = lane & 15, quad = lane >> 4;
    int m0 = (wv & 1) * 16;
    int wn0 = (wv >> 1) * 64;

    f4_t acc[4];

    // ===== stage 1: t1 = silu(feat @ W1 + b1), K=288 =====
    mm_stage(featA, slabH, slabL, W1h, W1l, NKB1, KP1, tid, m0, wn0, ln, quad, acc);
    #pragma unroll
    for (int ni = 0; ni < 4; ni++) {
        int n = wn0 + ni * 16 + ln;
        float bb = eb1[n];
        #pragma unroll
        for (int r = 0; r < 4; r++)
            featA[(m0 + quad * 4 + r) * FST + n] = silu_f(acc[ni][r] + bb);
    }

    // ===== stage 2: t2 = silu(t1 @ W2 + b2), K=128 =====
    mm_stage(featA, slabH, slabL, W2h, W2l, 4, H, tid, m0, wn0, ln, quad, acc);
    #pragma unroll
    for (int ni = 0; ni < 4; ni++) {
        int n = wn0 + ni * 16 + ln;
        float bb = eb2[n];
        #pragma unroll
        for (int r = 0; r < 4; r++)
            featA[(m0 + quad * 4 + r) * FST + n] = silu_f(acc[ni][r] + bb);
    }

    // ===== stage 3: w = silu(t2 @ Wc1 + cb1) @ cw2, K=128 =====
    mm_stage(featA, slabH, slabL, W3h, W3l, 4, H, tid, m0, wn0, ln, quad, acc);
    {
        float part[4] = {0.f, 0.f, 0.f, 0.f};
        #pragma unroll
        for (int ni = 0; ni < 4; ni++) {
            int n = wn0 + ni * 16 + ln;
            float cb = cb1[n], cwv = cw2[n];
            #pragma unroll
            for (int r = 0; r < 4; r++)
                part[r] += silu_f(acc[ni][r] + cb) * cwv;
        }
        #pragma unroll
        for (int r = 0; r < 4; r++) {
            float v = part[r];
            v += __shfl_xor(v, 1, 64);
            v += __shfl_xor(v, 2, 64);
            v += __shfl_xor(v, 4, 64);
            v += __shfl_xor(v, 8, 64);
            part[r] = v;
        }
        if (ln == 0) {
            #pragma unroll
            for (int r = 0; r < 4; r++)
                wpart[m0 + quad * 4 + r][wv >> 1] = part[r];
        }
    }
    __syncthreads();

    // --- scatter pos aggregation ---
    if (tid < EB2 * 3) {
        int e = tid / 3, ax = tid - e * 3;
        if (e0 + e < N_EDGES) {
            float w = wpart[e][0] + wpart[e][1];
            atomicAdd(&pagg[(size_t)rowS[e] * 3 + ax], relS[e][ax] * w);
        }
    }
    // --- scatter message aggregation (t2 fp32 in featA cols 0..127) ---
    for (int i = tid; i < EB2 * H; i += 256) {
        int e = i >> 7, ch = i & (H - 1);
        if (e0 + e < N_EDGES)
            atomicAdd(&magg[(size_t)rowS[e] * H + ch], featA[e * FST + ch]);
    }
}

// ---------------- node update (fp32) ----------------
__global__ __launch_bounds__(128) void node_kernel(
    float* __restrict__ h, const float* __restrict__ magg,
    const float* __restrict__ posagg, const float* __restrict__ deg,
    float* __restrict__ pos,
    const float* __restrict__ nw1, const float* __restrict__ nb1,
    const float* __restrict__ nw2, const float* __restrict__ nb2)
{
    __shared__ float cat[NB][256];
    __shared__ float4 wt[8 * H];
    __shared__ float u1[NB][H];
    int tid = threadIdx.x;
    int n0 = blockIdx.x * NB;

    if (tid < NB * 3) {
        int n = tid / 3, ax = tid % 3;
        int node = n0 + n;
        float d = fmaxf(deg[node], 1.0f);
        pos[node * 3 + ax] += posagg[node * 3 + ax] / d;
    }
    for (int n = 0; n < NB; n++) {
        cat[n][tid]     = h[(size_t)(n0 + n) * H + tid];
        cat[n][H + tid] = magg[(size_t)(n0 + n) * H + tid];
    }

    int c = tid & 63;
    int half = tid >> 6;
    float acc0[8], acc1[8];

    #pragma unroll
    for (int e = 0; e < 8; e++) { acc0[e] = 0.f; acc1[e] = 0.f; }
    for (int kb = 0; kb < 8; kb++) {
        __syncthreads();
        #pragma unroll
        for (int q = 0; q < 8; q++) {
            int k0 = kb * 32 + q * 4;
            float4 w4;
            w4.x = nw1[(k0 + 0) * H + tid];
            w4.y = nw1[(k0 + 1) * H + tid];
            w4.z = nw1[(k0 + 2) * H + tid];
            w4.w = nw1[(k0 + 3) * H + tid];
            wt[q * H + tid] = w4;
        }
        __syncthreads();
        #pragma unroll
        for (int q = 0; q < 8; q++) {
            float4 wa = wt[q * H + c];
            float4 wb = wt[q * H + c + 64];
            int k0 = kb * 32 + q * 4;
            #pragma unroll
            for (int e = 0; e < 8; e++) {
                const float4 f = *(const float4*)&cat[half * 8 + e][k0];
                acc0[e] = fmaf(f.x, wa.x, fmaf(f.y, wa.y, fmaf(f.z, wa.z, fmaf(f.w, wa.w, acc0[e]))));
                acc1[e] = fmaf(f.x, wb.x, fmaf(f.y, wb.y, fmaf(f.z, wb.z, fmaf(f.w, wb.w, acc1[e]))));
            }
        }
    }
    {
        float bb0 = nb1[c], bb1 = nb1[c + 64];
        #pragma unroll
        for (int e = 0; e < 8; e++) {
            u1[half * 8 + e][c]      = silu_f(acc0[e] + bb0);
            u1[half * 8 + e][c + 64] = silu_f(acc1[e] + bb1);
        }
    }

    #pragma unroll
    for (int e = 0; e < 8; e++) { acc0[e] = 0.f; acc1[e] = 0.f; }
    for (int kb = 0; kb < 4; kb++) {
        __syncthreads();
        #pragma unroll
        for (int q = 0; q < 8; q++) {
            int k0 = kb * 32 + q * 4;
            float4 w4;
            w4.x = nw2[(k0 + 0) * H + tid];
            w4.y = nw2[(k0 + 1) * H + tid];
            w4.z = nw2[(k0 + 2) * H + tid];
            w4.w = nw2[(k0 + 3) * H + tid];
            wt[q * H + tid] = w4;
        }
        __syncthreads();
        #pragma unroll
        for (int q = 0; q < 8; q++) {
            float4 wa = wt[q * H + c];
            float4 wb = wt[q * H + c + 64];
            int k0 = kb * 32 + q * 4;
            #pragma unroll
            for (int e = 0; e < 8; e++) {
                const float4 f = *(const float4*)&u1[half * 8 + e][k0];
                acc0[e] = fmaf(f.x, wa.x, fmaf(f.y, wa.y, fmaf(f.z, wa.z, fmaf(f.w, wa.w, acc0[e]))));
                acc1[e] = fmaf(f.x, wb.x, fmaf(f.y, wb.y, fmaf(f.z, wb.z, fmaf(f.w, wb.w, acc1[e]))));
            }
        }
    }
    {
        float bb0 = nb2[c], bb1 = nb2[c + 64];
        #pragma unroll
        for (int e = 0; e < 8; e++) {
            int node = n0 + half * 8 + e;
            h[(size_t)node * H + c]      += acc0[e] + bb0;
            h[(size_t)node * H + c + 64] += acc1[e] + bb1;
        }
    }
}

// ---------------- pooling + head ----------------
__global__ __launch_bounds__(128) void head_kernel(
    const float* __restrict__ h,
    const float* __restrict__ h1w, const float* __restrict__ h1b,
    const float* __restrict__ h2w, const float* __restrict__ h2b,
    const float* __restrict__ h3w, const float* __restrict__ h3b,
    float* __restrict__ out)
{
    __shared__ float gfeat[256];
    __shared__ float z1[128];
    __shared__ float z2[64];
    int tid = threadIdx.x;
    int g = blockIdx.x;
    size_t base = (size_t)g * NPG * H;
    float s = 0.f;
    for (int i = 0; i < NPG; i++) s += h[base + (size_t)i * H + tid];
    gfeat[tid] = s;
    gfeat[H + tid] = s / (float)NPG;
    __syncthreads();
    float a = h1b[tid];
    for (int k = 0; k < 256; k++) a = fmaf(gfeat[k], h1w[k * H + tid], a);
    z1[tid] = fmaxf(a, 0.0f);
    __syncthreads();
    if (tid < 64) {
        float a2 = h2b[tid];
        for (int k = 0; k < 128; k++) a2 = fmaf(z1[k], h2w[k * 64 + tid], a2);
        z2[tid] = fmaxf(a2, 0.0f);
    }
    __syncthreads();
    if (tid < 64) {
        float v = z2[tid] * h3w[tid];
        #pragma unroll
        for (int off = 32; off > 0; off >>= 1) v += __shfl_xor(v, off, 64);
        if (tid == 0) out[g] = v + h3b[0];
    }
}

extern "C" void kernel_launch(void* const* d_in, const int* in_sizes, int n_in,
                              void* d_out, int out_size, void* d_ws, size_t ws_size,
                              hipStream_t stream) {
    const float* x      = (const float*)d_in[0];
    const float* pos_in = (const float*)d_in[1];
    const int*   ei     = (const int*)d_in[2];
    const float* eattr  = (const float*)d_in[3];
    const float* Wp    = (const float*)d_in[6];
    const float* bp    = (const float*)d_in[7];
    const float* Wl    = (const float*)d_in[8];
    const float* bl    = (const float*)d_in[9];
    const float* gamma = (const float*)d_in[10];
    const float* beta  = (const float*)d_in[11];
    const float* ew1   = (const float*)d_in[12];
    const float* eb1   = (const float*)d_in[13];
    const float* ew2   = (const float*)d_in[14];
    const float* eb2   = (const float*)d_in[15];
    const float* cw1   = (const float*)d_in[16];
    const float* cb1   = (const float*)d_in[17];
    const float* cw2   = (const float*)d_in[18];
    const float* nw1   = (const float*)d_in[19];
    const float* nb1   = (const float*)d_in[20];
    const float* nw2   = (const float*)d_in[21];
    const float* nb2   = (const float*)d_in[22];
    const float* h1w   = (const float*)d_in[23];
    const float* h1b   = (const float*)d_in[24];
    const float* h2w   = (const float*)d_in[25];
    const float* h2b   = (const float*)d_in[26];
    const float* h3w   = (const float*)d_in[27];
    const float* h3b   = (const float*)d_in[28];
    float* out = (float*)d_out;

    float* ws   = (float*)d_ws;
    float* hbuf = ws;                                  // N*H f32
    float* magg = hbuf + (size_t)N_NODES * H;          // N*H f32
    float* posb = magg + (size_t)N_NODES * H;          // N*3
    float* pagg = posb + (size_t)N_NODES * 3;          // N*3
    float* deg  = pagg + (size_t)N_NODES * 3;          // N
    float* bnS  = deg + N_NODES;                       // 256
    float* bnP  = bnS + 256;                           // 256
    short* W1h  = (short*)(bnP + 256);                 // 4*128*288
    short* W1l  = W1h + 4 * H * KP1;
    short* W2h  = W1l + 4 * H * KP1;                   // 4*128*128
    short* W2l  = W2h + 4 * H * H;
    short* W3h  = W2l + 4 * H * H;
    short* W3l  = W3h + 4 * H * H;

    hipMemcpyAsync(posb, pos_in, (size_t)N_NODES * 3 * sizeof(float),
                   hipMemcpyDeviceToDevice, stream);
    hipMemsetAsync(deg, 0, N_NODES * sizeof(float), stream);
    hipMemsetAsync(bnS, 0, 256 * sizeof(float), stream);

    wprep_kernel<<<(4 * H * KP1 + 255) / 256, 256, 0, stream>>>(ew1, W1h, W1l, DIN, KP1);
    wprep_kernel<<<(4 * H * H + 255) / 256, 256, 0, stream>>>(ew2, W2h, W2l, H, H);
    wprep_kernel<<<(4 * H * H + 255) / 256, 256, 0, stream>>>(cw1, W3h, W3l, H, H);

    proj_kernel<<<N_NODES / NB, 128, 0, stream>>>(x, Wp, bp, Wl, bl, hbuf);
    bn_stats_kernel<<<N_NODES / NPG, 128, 0, stream>>>(hbuf, bnS);
    bn_final_kernel<<<1, 128, 0, stream>>>(bnS, gamma, beta, bnP);
    bn_apply_kernel<<<(N_NODES * H / 4) / 256, 256, 0, stream>>>(hbuf, bnP);
    deg_kernel<<<(N_EDGES + 255) / 256, 256, 0, stream>>>(ei, deg);

    int eblocks = (N_EDGES + EB2 - 1) / EB2;
    for (int l = 0; l < 4; l++) {
        hipMemsetAsync(magg, 0, (size_t)N_NODES * H * sizeof(float), stream);
        hipMemsetAsync(pagg, 0, (size_t)N_NODES * 3 * sizeof(float), stream);
        edge_mfma_kernel<<<eblocks, 256, 0, stream>>>(
            hbuf, posb, ei, eattr,
            W1h + (size_t)l * H * KP1, W1l + (size_t)l * H * KP1,
            W2h + (size_t)l * H * H,   W2l + (size_t)l * H * H,
            W3h + (size_t)l * H * H,   W3l + (size_t)l * H * H,
            eb1 + (size_t)l * H, eb2 + (size_t)l * H,
            cb1 + (size_t)l * H, cw2 + (size_t)l * H,
            magg, pagg);
        node_kernel<<<N_NODES / NB, 128, 0, stream>>>(
            hbuf, magg, pagg, deg, posb,
            nw1 + (size_t)l * 2 * H * H, nb1 + (size_t)l * H,
            nw2 + (size_t)l * H * H,     nb2 + (size_t)l * H);
    }

    head_kernel<<<G_GRAPHS, 128, 0, stream>>>(hbuf, h1w, h1b, h2w, h2b, h3w, h3b, out);
}

// Round 5
// 3963.739 us; speedup vs baseline: 2.4213x; 1.0622x over previous
//
#include <hip/hip_runtime.h>
#include <math.h>

#define N_NODES 50000
#define N_EDGES 500000
#define G_GRAPHS 100
#define NPG 500
#define NPROT 400
#define H 128
#define PN 35
#define LN 11
#define DIN 261      // 2H + 1 + 4
#define KP1 288      // stage-1 K padded to 9 slabs of 32
#define EB2 32       // edges per block (MFMA edge kernel)
#define FSB 296      // feat plane row stride in bf16 (592B = 148 dw, %32=20 -> 2-way, free)
#define NB 16        // nodes per workgroup (fp32 node kernel)
#define EPSV 1e-5f

typedef __attribute__((ext_vector_type(8))) short bf8_t;   // 8 bf16 (4 VGPRs)
typedef __attribute__((ext_vector_type(4))) short bf4_t;
typedef __attribute__((ext_vector_type(4))) float f4_t;

__device__ __forceinline__ float silu_f(float x) {
    return x / (1.0f + __expf(-x));
}
__device__ __forceinline__ short f2b(float f) {
    __bf16 b = (__bf16)f;                 // RNE hardware cvt
    return __builtin_bit_cast(short, b);
}
__device__ __forceinline__ float b2f(short s) {
    unsigned u = ((unsigned)(unsigned short)s) << 16;
    return __builtin_bit_cast(float, u);
}

// ---------------- weight prep: transpose + split fp32 -> bf16 hi/lo ----------------
// src: [L=4][K][H], dstH/dstL: [L=4][H][Kpad]
__global__ void wprep_kernel(const float* __restrict__ src, short* __restrict__ dstH,
                             short* __restrict__ dstL, int K, int Kpad) {
    int idx = blockIdx.x * 256 + threadIdx.x;
    int total = 4 * H * Kpad;
    if (idx >= total) return;
    int l = idx / (H * Kpad);
    int rem = idx - l * (H * Kpad);
    int n = rem / Kpad;
    int k = rem - n * Kpad;
    float v = (k < K) ? src[((size_t)l * K + k) * H + n] : 0.0f;
    short hi = f2b(v);
    dstH[idx] = hi;
    dstL[idx] = f2b(v - b2f(hi));
}

// ---------------- projection ----------------
__global__ __launch_bounds__(128) void proj_kernel(
    const float* __restrict__ x, const float* __restrict__ Wp, const float* __restrict__ bp,
    const float* __restrict__ Wl, const float* __restrict__ bl, float* __restrict__ h)
{
    __shared__ float xs[NB][36];
    int tid = threadIdx.x;
    int n0 = blockIdx.x * NB;
    for (int idx = tid; idx < NB * PN; idx += 128) {
        int n = idx / PN, k = idx % PN;
        xs[n][k] = x[(size_t)(n0 + n) * PN + k];
    }
    __syncthreads();
    for (int n = 0; n < NB; n++) {
        int node = n0 + n;
        bool isp = (node % NPG) < NPROT;
        float acc;
        if (isp) {
            acc = bp[tid];
            for (int k = 0; k < PN; k++) acc = fmaf(xs[n][k], Wp[k * H + tid], acc);
        } else {
            acc = bl[tid];
            for (int k = 0; k < LN; k++) acc = fmaf(xs[n][k], Wl[k * H + tid], acc);
        }
        h[(size_t)node * H + tid] = acc;
    }
}

// ---------------- batchnorm ----------------
__global__ __launch_bounds__(128) void bn_stats_kernel(const float* __restrict__ h, float* __restrict__ bnS)
{
    int tid = threadIdx.x;
    size_t base = (size_t)blockIdx.x * NPG * H;
    float s1 = 0.f, s2 = 0.f;
    for (int i = 0; i < NPG; i++) {
        float v = h[base + (size_t)i * H + tid];
        s1 += v; s2 += v * v;
    }
    atomicAdd(&bnS[tid], s1);
    atomicAdd(&bnS[H + tid], s2);
}

__global__ void bn_final_kernel(const float* __restrict__ bnS, const float* __restrict__ gamma,
                                const float* __restrict__ beta, float* __restrict__ bnP)
{
    int j = threadIdx.x;
    float mu = bnS[j] / (float)N_NODES;
    float var = bnS[H + j] / (float)N_NODES - mu * mu;
    float inv = rsqrtf(var + EPSV);
    float sc = gamma[j] * inv;
    bnP[j] = sc;
    bnP[H + j] = beta[j] - mu * sc;
}

__global__ __launch_bounds__(256) void bn_apply_kernel(float* __restrict__ h, const float* __restrict__ bnP)
{
    int idx = blockIdx.x * 256 + threadIdx.x;
    float4 v = ((float4*)h)[idx];
    int j4 = (idx & 31) * 4;
    v.x = fmaf(v.x, bnP[j4 + 0], bnP[H + j4 + 0]);
    v.y = fmaf(v.y, bnP[j4 + 1], bnP[H + j4 + 1]);
    v.z = fmaf(v.z, bnP[j4 + 2], bnP[H + j4 + 2]);
    v.w = fmaf(v.w, bnP[j4 + 3], bnP[H + j4 + 3]);
    ((float4*)h)[idx] = v;
}

// ---------------- degree ----------------
__global__ void deg_kernel(const int* __restrict__ ei, float* __restrict__ deg)
{
    int e = blockIdx.x * 256 + threadIdx.x;
    if (e < N_EDGES) atomicAdd(&deg[ei[e]], 1.0f);
}

// ---------------- hi/lo bf16 MFMA k-loop (fp32-equivalent, 3-term) ----------------
// C[32 x 128]: wave m0=(wv&1)*16 (one 16-row m-tile), wn0=(wv>>1)*64 (4 n-tiles).
// A hi/lo planes in LDS; B hi/lo read per-fragment from global (L1/L2-cached).
__device__ __forceinline__ void mm_hl(
    const short* fH, const short* fL, int aoff,
    const short* __restrict__ WH, const short* __restrict__ WL,
    int kt, int nkb, int m0, int wn0, int ln, int quad, f4_t acc[4])
{
    #pragma unroll
    for (int ni = 0; ni < 4; ni++) acc[ni] = (f4_t)(0.0f);
    for (int kb = 0; kb < nkb; kb++) {
        int k0 = kb * 32 + quad * 8;
        bf8_t ah = *(const bf8_t*)&fH[(m0 + ln) * FSB + aoff + k0];
        bf8_t al = *(const bf8_t*)&fL[(m0 + ln) * FSB + aoff + k0];
        #pragma unroll
        for (int ni = 0; ni < 4; ni++) {
            int roff = (wn0 + ni * 16 + ln) * kt + k0;
            bf8_t bh = *(const bf8_t*)&WH[roff];
            bf8_t bl = *(const bf8_t*)&WL[roff];
            acc[ni] = __builtin_amdgcn_mfma_f32_16x16x32_bf16(ah, bh, acc[ni], 0, 0, 0);
            acc[ni] = __builtin_amdgcn_mfma_f32_16x16x32_bf16(al, bh, acc[ni], 0, 0, 0);
            acc[ni] = __builtin_amdgcn_mfma_f32_16x16x32_bf16(ah, bl, acc[ni], 0, 0, 0);
        }
    }
}

// ---------------- MFMA edge kernel ----------------
__global__ __launch_bounds__(256, 2) void edge_mfma_kernel(
    const float* __restrict__ h, const float* __restrict__ pos,
    const int* __restrict__ ei, const float* __restrict__ eattr,
    const short* __restrict__ W1h, const short* __restrict__ W1l,
    const short* __restrict__ W2h, const short* __restrict__ W2l,
    const short* __restrict__ W3h, const short* __restrict__ W3l,
    const float* __restrict__ eb1, const float* __restrict__ eb2,
    const float* __restrict__ cb1, const float* __restrict__ cw2,
    float* __restrict__ magg, float* __restrict__ pagg)
{
    __shared__ __align__(16) short fH[EB2 * FSB];   // 18944 B
    __shared__ __align__(16) short fL[EB2 * FSB];   // 18944 B
    __shared__ float relS[EB2][3];
    __shared__ float wpart[EB2][2];
    __shared__ int rowS[EB2];
    __shared__ int colS[EB2];

    int tid = threadIdx.x;
    int e0 = blockIdx.x * EB2;

    // --- edge meta: rel, d2, attr (hi/lo), zero-pad cols 261..287 both planes ---
    if (tid < EB2) {
        int e = e0 + tid;
        int ec = (e < N_EDGES) ? e : (N_EDGES - 1);
        int r = ei[ec], c = ei[N_EDGES + ec];
        rowS[tid] = r; colS[tid] = c;
        float rx = pos[r * 3 + 0] - pos[c * 3 + 0];
        float ry = pos[r * 3 + 1] - pos[c * 3 + 1];
        float rz = pos[r * 3 + 2] - pos[c * 3 + 2];
        relS[tid][0] = rx; relS[tid][1] = ry; relS[tid][2] = rz;
        float mv[5];
        mv[0] = rx * rx + ry * ry + rz * rz;
        mv[1] = eattr[(size_t)ec * 4 + 0];
        mv[2] = eattr[(size_t)ec * 4 + 1];
        mv[3] = eattr[(size_t)ec * 4 + 2];
        mv[4] = eattr[(size_t)ec * 4 + 3];
        #pragma unroll
        for (int j = 0; j < 5; j++) {
            short hi = f2b(mv[j]);
            fH[tid * FSB + 256 + j] = hi;
            fL[tid * FSB + 256 + j] = f2b(mv[j] - b2f(hi));
        }
        for (int k2 = 261; k2 < KP1; k2++) {
            fH[tid * FSB + k2] = 0;
            fL[tid * FSB + k2] = 0;
        }
    }
    __syncthreads();

    // --- gather h[row] -> cols 0..127, h[col] -> cols 128..255 (fp32 -> hi/lo bf16) ---
    for (int i = tid; i < 2 * EB2 * (H / 4); i += 256) {   // 2048 chunks
        int rrow = i >> 5, chunk = i & 31;
        int eidx = rrow & (EB2 - 1);
        int node = (rrow < EB2) ? rowS[eidx] : colS[eidx];
        f4_t v = *(const f4_t*)&h[(size_t)node * H + chunk * 4];
        bf4_t hi, lo;
        #pragma unroll
        for (int j = 0; j < 4; j++) {
            hi[j] = f2b(v[j]);
            lo[j] = f2b(v[j] - b2f(hi[j]));
        }
        int dcol = ((rrow < EB2) ? 0 : H) + chunk * 4;
        *(bf4_t*)&fH[eidx * FSB + dcol] = hi;
        *(bf4_t*)&fL[eidx * FSB + dcol] = lo;
    }
    __syncthreads();

    int lane = tid & 63;
    int wv = tid >> 6;
    int ln = lane & 15, quad = lane >> 4;
    int m0 = (wv & 1) * 16;
    int wn0 = (wv >> 1) * 64;

    f4_t acc[4];

    // ===== stage 1: t1 = silu(feat @ W1 + b1), K=288; t1 -> cols 128..255 =====
    mm_hl(fH, fL, 0, W1h, W1l, KP1, 9, m0, wn0, ln, quad, acc);
    __syncthreads();                      // all stage-1 reads done before overwrite
    #pragma unroll
    for (int ni = 0; ni < 4; ni++) {
        int n = wn0 + ni * 16 + ln;
        float bb = eb1[n];
        #pragma unroll
        for (int r = 0; r < 4; r++) {
            int m = m0 + quad * 4 + r;
            float v = silu_f(acc[ni][r] + bb);
            short hi = f2b(v);
            fH[m * FSB + H + n] = hi;
            fL[m * FSB + H + n] = f2b(v - b2f(hi));
        }
    }
    __syncthreads();

    // ===== stage 2: t2 = silu(t1 @ W2 + b2), K=128; t2 -> cols 0..127 + magg scatter =====
    mm_hl(fH, fL, H, W2h, W2l, H, 4, m0, wn0, ln, quad, acc);
    // epilogue writes cols 0..127, loop reads cols 128..255 -> disjoint, no barrier needed
    #pragma unroll
    for (int ni = 0; ni < 4; ni++) {
        int n = wn0 + ni * 16 + ln;
        float bb = eb2[n];
        #pragma unroll
        for (int r = 0; r < 4; r++) {
            int m = m0 + quad * 4 + r;
            float v = silu_f(acc[ni][r] + bb);
            short hi = f2b(v);
            fH[m * FSB + n] = hi;
            fL[m * FSB + n] = f2b(v - b2f(hi));
            if (e0 + m < N_EDGES)
                atomicAdd(&magg[(size_t)rowS[m] * H + n], v);   // fp32 message
        }
    }
    __syncthreads();

    // ===== stage 3: w = silu(t2 @ Wc1 + cb1) @ cw2, K=128 =====
    mm_hl(fH, fL, 0, W3h, W3l, H, 4, m0, wn0, ln, quad, acc);
    {
        float part[4] = {0.f, 0.f, 0.f, 0.f};
        #pragma unroll
        for (int ni = 0; ni < 4; ni++) {
            int n = wn0 + ni * 16 + ln;
            float cb = cb1[n], cwv = cw2[n];
            #pragma unroll
            for (int r = 0; r < 4; r++)
                part[r] += silu_f(acc[ni][r] + cb) * cwv;
        }
        #pragma unroll
        for (int r = 0; r < 4; r++) {
            float v = part[r];
            v += __shfl_xor(v, 1, 64);
            v += __shfl_xor(v, 2, 64);
            v += __shfl_xor(v, 4, 64);
            v += __shfl_xor(v, 8, 64);
            part[r] = v;
        }
        if (ln == 0) {
            #pragma unroll
            for (int r = 0; r < 4; r++)
                wpart[m0 + quad * 4 + r][wv >> 1] = part[r];
        }
    }
    __syncthreads();

    // --- scatter pos aggregation ---
    if (tid < EB2 * 3) {
        int e = tid / 3, ax = tid - e * 3;
        if (e0 + e < N_EDGES) {
            float w = wpart[e][0] + wpart[e][1];
            atomicAdd(&pagg[(size_t)rowS[e] * 3 + ax], relS[e][ax] * w);
        }
    }
}

// ---------------- node update (fp32, known-good) ----------------
__global__ __launch_bounds__(128) void node_kernel(
    float* __restrict__ h, const float* __restrict__ magg,
    const float* __restrict__ posagg, const float* __restrict__ deg,
    float* __restrict__ pos,
    const float* __restrict__ nw1, const float* __restrict__ nb1,
    const float* __restrict__ nw2, const float* __restrict__ nb2)
{
    __shared__ float cat[NB][256];
    __shared__ float4 wt[8 * H];
    __shared__ float u1[NB][H];
    int tid = threadIdx.x;
    int n0 = blockIdx.x * NB;

    if (tid < NB * 3) {
        int n = tid / 3, ax = tid % 3;
        int node = n0 + n;
        float d = fmaxf(deg[node], 1.0f);
        pos[node * 3 + ax] += posagg[node * 3 + ax] / d;
    }
    for (int n = 0; n < NB; n++) {
        cat[n][tid]     = h[(size_t)(n0 + n) * H + tid];
        cat[n][H + tid] = magg[(size_t)(n0 + n) * H + tid];
    }

    int c = tid & 63;
    int half = tid >> 6;
    float acc0[8], acc1[8];

    #pragma unroll
    for (int e = 0; e < 8; e++) { acc0[e] = 0.f; acc1[e] = 0.f; }
    for (int kb = 0; kb < 8; kb++) {
        __syncthreads();
        #pragma unroll
        for (int q = 0; q < 8; q++) {
            int k0 = kb * 32 + q * 4;
            float4 w4;
            w4.x = nw1[(k0 + 0) * H + tid];
            w4.y = nw1[(k0 + 1) * H + tid];
            w4.z = nw1[(k0 + 2) * H + tid];
            w4.w = nw1[(k0 + 3) * H + tid];
            wt[q * H + tid] = w4;
        }
        __syncthreads();
        #pragma unroll
        for (int q = 0; q < 8; q++) {
            float4 wa = wt[q * H + c];
            float4 wb = wt[q * H + c + 64];
            int k0 = kb * 32 + q * 4;
            #pragma unroll
            for (int e = 0; e < 8; e++) {
                const float4 f = *(const float4*)&cat[half * 8 + e][k0];
                acc0[e] = fmaf(f.x, wa.x, fmaf(f.y, wa.y, fmaf(f.z, wa.z, fmaf(f.w, wa.w, acc0[e]))));
                acc1[e] = fmaf(f.x, wb.x, fmaf(f.y, wb.y, fmaf(f.z, wb.z, fmaf(f.w, wb.w, acc1[e]))));
            }
        }
    }
    {
        float bb0 = nb1[c], bb1 = nb1[c + 64];
        #pragma unroll
        for (int e = 0; e < 8; e++) {
            u1[half * 8 + e][c]      = silu_f(acc0[e] + bb0);
            u1[half * 8 + e][c + 64] = silu_f(acc1[e] + bb1);
        }
    }

    #pragma unroll
    for (int e = 0; e < 8; e++) { acc0[e] = 0.f; acc1[e] = 0.f; }
    for (int kb = 0; kb < 4; kb++) {
        __syncthreads();
        #pragma unroll
        for (int q = 0; q < 8; q++) {
            int k0 = kb * 32 + q * 4;
            float4 w4;
            w4.x = nw2[(k0 + 0) * H + tid];
            w4.y = nw2[(k0 + 1) * H + tid];
            w4.z = nw2[(k0 + 2) * H + tid];
            w4.w = nw2[(k0 + 3) * H + tid];
            wt[q * H + tid] = w4;
        }
        __syncthreads();
        #pragma unroll
        for (int q = 0; q < 8; q++) {
            float4 wa = wt[q * H + c];
            float4 wb = wt[q * H + c + 64];
            int k0 = kb * 32 + q * 4;
            #pragma unroll
            for (int e = 0; e < 8; e++) {
                const float4 f = *(const float4*)&u1[half * 8 + e][k0];
                acc0[e] = fmaf(f.x, wa.x, fmaf(f.y, wa.y, fmaf(f.z, wa.z, fmaf(f.w, wa.w, acc0[e]))));
                acc1[e] = fmaf(f.x, wb.x, fmaf(f.y, wb.y, fmaf(f.z, wb.z, fmaf(f.w, wb.w, acc1[e]))));
            }
        }
    }
    {
        float bb0 = nb2[c], bb1 = nb2[c + 64];
        #pragma unroll
        for (int e = 0; e < 8; e++) {
            int node = n0 + half * 8 + e;
            h[(size_t)node * H + c]      += acc0[e] + bb0;
            h[(size_t)node * H + c + 64] += acc1[e] + bb1;
        }
    }
}

// ---------------- pooling + head ----------------
__global__ __launch_bounds__(128) void head_kernel(
    const float* __restrict__ h,
    const float* __restrict__ h1w, const float* __restrict__ h1b,
    const float* __restrict__ h2w, const float* __restrict__ h2b,
    const float* __restrict__ h3w, const float* __restrict__ h3b,
    float* __restrict__ out)
{
    __shared__ float gfeat[256];
    __shared__ float z1[128];
    __shared__ float z2[64];
    int tid = threadIdx.x;
    int g = blockIdx.x;
    size_t base = (size_t)g * NPG * H;
    float s = 0.f;
    for (int i = 0; i < NPG; i++) s += h[base + (size_t)i * H + tid];
    gfeat[tid] = s;
    gfeat[H + tid] = s / (float)NPG;
    __syncthreads();
    float a = h1b[tid];
    for (int k = 0; k < 256; k++) a = fmaf(gfeat[k], h1w[k * H + tid], a);
    z1[tid] = fmaxf(a, 0.0f);
    __syncthreads();
    if (tid < 64) {
        float a2 = h2b[tid];
        for (int k = 0; k < 128; k++) a2 = fmaf(z1[k], h2w[k * 64 + tid], a2);
        z2[tid] = fmaxf(a2, 0.0f);
    }
    __syncthreads();
    if (tid < 64) {
        float v = z2[tid] * h3w[tid];
        #pragma unroll
        for (int off = 32; off > 0; off >>= 1) v += __shfl_xor(v, off, 64);
        if (tid == 0) out[g] = v + h3b[0];
    }
}

extern "C" void kernel_launch(void* const* d_in, const int* in_sizes, int n_in,
                              void* d_out, int out_size, void* d_ws, size_t ws_size,
                              hipStream_t stream) {
    const float* x      = (const float*)d_in[0];
    const float* pos_in = (const float*)d_in[1];
    const int*   ei     = (const int*)d_in[2];
    const float* eattr  = (const float*)d_in[3];
    const float* Wp    = (const float*)d_in[6];
    const float* bp    = (const float*)d_in[7];
    const float* Wl    = (const float*)d_in[8];
    const float* bl    = (const float*)d_in[9];
    const float* gamma = (const float*)d_in[10];
    const float* beta  = (const float*)d_in[11];
    const float* ew1   = (const float*)d_in[12];
    const float* eb1   = (const float*)d_in[13];
    const float* ew2   = (const float*)d_in[14];
    const float* eb2   = (const float*)d_in[15];
    const float* cw1   = (const float*)d_in[16];
    const float* cb1   = (const float*)d_in[17];
    const float* cw2   = (const float*)d_in[18];
    const float* nw1   = (const float*)d_in[19];
    const float* nb1   = (const float*)d_in[20];
    const float* nw2   = (const float*)d_in[21];
    const float* nb2   = (const float*)d_in[22];
    const float* h1w   = (const float*)d_in[23];
    const float* h1b   = (const float*)d_in[24];
    const float* h2w   = (const float*)d_in[25];
    const float* h2b   = (const float*)d_in[26];
    const float* h3w   = (const float*)d_in[27];
    const float* h3b   = (const float*)d_in[28];
    float* out = (float*)d_out;

    float* ws   = (float*)d_ws;
    float* hbuf = ws;                                  // N*H f32
    float* magg = hbuf + (size_t)N_NODES * H;          // N*H f32
    float* posb = magg + (size_t)N_NODES * H;          // N*3
    float* pagg = posb + (size_t)N_NODES * 3;          // N*3
    float* deg  = pagg + (size_t)N_NODES * 3;          // N
    float* bnS  = deg + N_NODES;                       // 256
    float* bnP  = bnS + 256;                           // 256
    short* W1h  = (short*)(bnP + 256);                 // 4*128*288
    short* W1l  = W1h + 4 * H * KP1;
    short* W2h  = W1l + 4 * H * KP1;                   // 4*128*128
    short* W2l  = W2h + 4 * H * H;
    short* W3h  = W2l + 4 * H * H;
    short* W3l  = W3h + 4 * H * H;

    hipMemcpyAsync(posb, pos_in, (size_t)N_NODES * 3 * sizeof(float),
                   hipMemcpyDeviceToDevice, stream);
    hipMemsetAsync(deg, 0, N_NODES * sizeof(float), stream);
    hipMemsetAsync(bnS, 0, 256 * sizeof(float), stream);

    wprep_kernel<<<(4 * H * KP1 + 255) / 256, 256, 0, stream>>>(ew1, W1h, W1l, DIN, KP1);
    wprep_kernel<<<(4 * H * H + 255) / 256, 256, 0, stream>>>(ew2, W2h, W2l, H, H);
    wprep_kernel<<<(4 * H * H + 255) / 256, 256, 0, stream>>>(cw1, W3h, W3l, H, H);

    proj_kernel<<<N_NODES / NB, 128, 0, stream>>>(x, Wp, bp, Wl, bl, hbuf);
    bn_stats_kernel<<<N_NODES / NPG, 128, 0, stream>>>(hbuf, bnS);
    bn_final_kernel<<<1, 128, 0, stream>>>(bnS, gamma, beta, bnP);
    bn_apply_kernel<<<(N_NODES * H / 4) / 256, 256, 0, stream>>>(hbuf, bnP);
    deg_kernel<<<(N_EDGES + 255) / 256, 256, 0, stream>>>(ei, deg);

    int eblocks = (N_EDGES + EB2 - 1) / EB2;
    for (int l = 0; l < 4; l++) {
        hipMemsetAsync(magg, 0, (size_t)N_NODES * H * sizeof(float), stream);
        hipMemsetAsync(pagg, 0, (size_t)N_NODES * 3 * sizeof(float), stream);
        edge_mfma_kernel<<<eblocks, 256, 0, stream>>>(
            hbuf, posb, ei, eattr,
            W1h + (size_t)l * H * KP1, W1l + (size_t)l * H * KP1,
            W2h + (size_t)l * H * H,   W2l + (size_t)l * H * H,
            W3h + (size_t)l * H * H,   W3l + (size_t)l * H * H,
            eb1 + (size_t)l * H, eb2 + (size_t)l * H,
            cb1 + (size_t)l * H, cw2 + (size_t)l * H,
            magg, pagg);
        node_kernel<<<N_NODES / NB, 128, 0, stream>>>(
            hbuf, magg, pagg, deg, posb,
            nw1 + (size_t)l * 2 * H * H, nb1 + (size_t)l * H,
            nw2 + (size_t)l * H * H,     nb2 + (size_t)l * H);
    }

    head_kernel<<<G_GRAPHS, 128, 0, stream>>>(hbuf, h1w, h1b, h2w, h2b, h3w, h3b, out);
}

// Round 6
// 2826.050 us; speedup vs baseline: 3.3961x; 1.4026x over previous
//
#include <hip/hip_runtime.h>
#include <math.h>

#define N_NODES 50000
#define N_EDGES 500000
#define G_GRAPHS 100
#define NPG 500
#define NPROT 400
#define H 128
#define PN 35
#define LN 11
#define DIN 261      // 2H + 1 + 4
#define KP1 288      // stage-1 K padded to 9 slabs of 32
#define NKB1 9
#define EB2 64       // edges per block (MFMA edge kernel)
#define FSB 296      // feat plane row stride in bf16 (592B = 148 dw, %32=20 -> 2-way, free)
#define NB 16        // nodes per workgroup (fp32 node kernel)
#define EPSV 1e-5f

typedef __attribute__((ext_vector_type(8))) short bf8_t;   // 8 bf16 (4 VGPRs)
typedef __attribute__((ext_vector_type(4))) short bf4_t;
typedef __attribute__((ext_vector_type(4))) float f4_t;

__device__ __forceinline__ float silu_f(float x) {
    return x / (1.0f + __expf(-x));
}
__device__ __forceinline__ short f2b(float f) {
    __bf16 b = (__bf16)f;                 // RNE hardware cvt
    return __builtin_bit_cast(short, b);
}
__device__ __forceinline__ float b2f(short s) {
    unsigned u = ((unsigned)(unsigned short)s) << 16;
    return __builtin_bit_cast(float, u);
}

// ---------------- weight prep: fp32 [4][K][H] -> MFMA-fragment-ordered bf16 hi/lo ----------
// dst layout: [l][kb][nt][lane][8]  (nt = n-tile of 16 rows, lane = ln + 16*quad)
// so a wave's B-fragment load is lane-consecutive 16B chunks -> fully coalesced 1KB.
__global__ void wprep_frag_kernel(const float* __restrict__ src, short* __restrict__ dstH,
                                  short* __restrict__ dstL, int K, int nkb) {
    int idx = blockIdx.x * 256 + threadIdx.x;
    int per_l = nkb * 8 * 64 * 8;
    int total = 4 * per_l;
    if (idx >= total) return;
    int l = idx / per_l;
    int rem = idx - l * per_l;
    int j = rem & 7;
    int lane = (rem >> 3) & 63;
    int nt = (rem >> 9) & 7;
    int kb = rem >> 12;
    int ln = lane & 15, quad = lane >> 4;
    int n = nt * 16 + ln;
    int k = kb * 32 + quad * 8 + j;
    float v = (k < K) ? src[((size_t)l * K + k) * H + n] : 0.0f;
    short hi = f2b(v);
    dstH[idx] = hi;
    dstL[idx] = f2b(v - b2f(hi));
}

// ---------------- projection ----------------
__global__ __launch_bounds__(128) void proj_kernel(
    const float* __restrict__ x, const float* __restrict__ Wp, const float* __restrict__ bp,
    const float* __restrict__ Wl, const float* __restrict__ bl, float* __restrict__ h)
{
    __shared__ float xs[NB][36];
    int tid = threadIdx.x;
    int n0 = blockIdx.x * NB;
    for (int idx = tid; idx < NB * PN; idx += 128) {
        int n = idx / PN, k = idx % PN;
        xs[n][k] = x[(size_t)(n0 + n) * PN + k];
    }
    __syncthreads();
    for (int n = 0; n < NB; n++) {
        int node = n0 + n;
        bool isp = (node % NPG) < NPROT;
        float acc;
        if (isp) {
            acc = bp[tid];
            for (int k = 0; k < PN; k++) acc = fmaf(xs[n][k], Wp[k * H + tid], acc);
        } else {
            acc = bl[tid];
            for (int k = 0; k < LN; k++) acc = fmaf(xs[n][k], Wl[k * H + tid], acc);
        }
        h[(size_t)node * H + tid] = acc;
    }
}

// ---------------- batchnorm ----------------
__global__ __launch_bounds__(128) void bn_stats_kernel(const float* __restrict__ h, float* __restrict__ bnS)
{
    int tid = threadIdx.x;
    size_t base = (size_t)blockIdx.x * NPG * H;
    float s1 = 0.f, s2 = 0.f;
    for (int i = 0; i < NPG; i++) {
        float v = h[base + (size_t)i * H + tid];
        s1 += v; s2 += v * v;
    }
    atomicAdd(&bnS[tid], s1);
    atomicAdd(&bnS[H + tid], s2);
}

__global__ void bn_final_kernel(const float* __restrict__ bnS, const float* __restrict__ gamma,
                                const float* __restrict__ beta, float* __restrict__ bnP)
{
    int j = threadIdx.x;
    float mu = bnS[j] / (float)N_NODES;
    float var = bnS[H + j] / (float)N_NODES - mu * mu;
    float inv = rsqrtf(var + EPSV);
    float sc = gamma[j] * inv;
    bnP[j] = sc;
    bnP[H + j] = beta[j] - mu * sc;
}

__global__ __launch_bounds__(256) void bn_apply_kernel(float* __restrict__ h, const float* __restrict__ bnP)
{
    int idx = blockIdx.x * 256 + threadIdx.x;
    float4 v = ((float4*)h)[idx];
    int j4 = (idx & 31) * 4;
    v.x = fmaf(v.x, bnP[j4 + 0], bnP[H + j4 + 0]);
    v.y = fmaf(v.y, bnP[j4 + 1], bnP[H + j4 + 1]);
    v.z = fmaf(v.z, bnP[j4 + 2], bnP[H + j4 + 2]);
    v.w = fmaf(v.w, bnP[j4 + 3], bnP[H + j4 + 3]);
    ((float4*)h)[idx] = v;
}

// ---------------- degree ----------------
__global__ void deg_kernel(const int* __restrict__ ei, float* __restrict__ deg)
{
    int e = blockIdx.x * 256 + threadIdx.x;
    if (e < N_EDGES) atomicAdd(&deg[ei[e]], 1.0f);
}

// ---------------- hi/lo bf16 MFMA k-loop (fp32-equivalent, 3-term) ----------------
// C[64 x 128] per block. 8 waves: m0=(wv&3)*16 (4 m-tiles), ntb=(wv>>2)*4 (2 n-halves).
// A hi/lo planes in LDS; B hi/lo fragment-ordered in global -> coalesced 1KB loads.
__device__ __forceinline__ void mm_hl(
    const short* fH, const short* fL, int aoff,
    const short* __restrict__ WH, const short* __restrict__ WL,
    int nkb, int m0, int ntb, int lane, int ln, int quad, f4_t acc[4])
{
    #pragma unroll
    for (int ni = 0; ni < 4; ni++) acc[ni] = (f4_t)(0.0f);
    for (int kb = 0; kb < nkb; kb++) {
        int k0 = kb * 32 + quad * 8;
        bf8_t ah = *(const bf8_t*)&fH[(m0 + ln) * FSB + aoff + k0];
        bf8_t al = *(const bf8_t*)&fL[(m0 + ln) * FSB + aoff + k0];
        #pragma unroll
        for (int ni = 0; ni < 4; ni++) {
            int off = ((kb * 8 + ntb + ni) * 64 + lane) * 8;
            bf8_t bh = *(const bf8_t*)&WH[off];
            bf8_t bl = *(const bf8_t*)&WL[off];
            acc[ni] = __builtin_amdgcn_mfma_f32_16x16x32_bf16(ah, bh, acc[ni], 0, 0, 0);
            acc[ni] = __builtin_amdgcn_mfma_f32_16x16x32_bf16(al, bh, acc[ni], 0, 0, 0);
            acc[ni] = __builtin_amdgcn_mfma_f32_16x16x32_bf16(ah, bl, acc[ni], 0, 0, 0);
        }
    }
}

// ---------------- MFMA edge kernel ----------------
__global__ __launch_bounds__(512, 4) void edge_mfma_kernel(
    const float* __restrict__ h, const float* __restrict__ pos,
    const int* __restrict__ ei, const float* __restrict__ eattr,
    const short* __restrict__ W1h, const short* __restrict__ W1l,
    const short* __restrict__ W2h, const short* __restrict__ W2l,
    const short* __restrict__ W3h, const short* __restrict__ W3l,
    const float* __restrict__ eb1, const float* __restrict__ eb2,
    const float* __restrict__ cb1, const float* __restrict__ cw2,
    float* __restrict__ magg, float* __restrict__ pagg)
{
    __shared__ __align__(16) short fH[EB2 * FSB];   // 37888 B
    __shared__ __align__(16) short fL[EB2 * FSB];   // 37888 B
    __shared__ float relS[EB2][3];
    __shared__ float wpart[EB2][2];
    __shared__ int rowS[EB2];
    __shared__ int colS[EB2];

    int tid = threadIdx.x;
    int e0 = blockIdx.x * EB2;

    // --- edge meta: rel, d2, attr (hi/lo), zero-pad cols 261..287 both planes ---
    if (tid < EB2) {
        int e = e0 + tid;
        int ec = (e < N_EDGES) ? e : (N_EDGES - 1);
        int r = ei[ec], c = ei[N_EDGES + ec];
        rowS[tid] = r; colS[tid] = c;
        float rx = pos[r * 3 + 0] - pos[c * 3 + 0];
        float ry = pos[r * 3 + 1] - pos[c * 3 + 1];
        float rz = pos[r * 3 + 2] - pos[c * 3 + 2];
        relS[tid][0] = rx; relS[tid][1] = ry; relS[tid][2] = rz;
        float mv[5];
        mv[0] = rx * rx + ry * ry + rz * rz;
        mv[1] = eattr[(size_t)ec * 4 + 0];
        mv[2] = eattr[(size_t)ec * 4 + 1];
        mv[3] = eattr[(size_t)ec * 4 + 2];
        mv[4] = eattr[(size_t)ec * 4 + 3];
        #pragma unroll
        for (int j = 0; j < 5; j++) {
            short hi = f2b(mv[j]);
            fH[tid * FSB + 256 + j] = hi;
            fL[tid * FSB + 256 + j] = f2b(mv[j] - b2f(hi));
        }
        for (int k2 = 261; k2 < KP1; k2++) {
            fH[tid * FSB + k2] = 0;
            fL[tid * FSB + k2] = 0;
        }
    }
    __syncthreads();

    // --- gather h[row] -> cols 0..127, h[col] -> cols 128..255 (fp32 -> hi/lo bf16) ---
    for (int i = tid; i < 2 * EB2 * (H / 4); i += 512) {   // 4096 chunks
        int rrow = i >> 5, chunk = i & 31;
        int eidx = rrow & (EB2 - 1);
        int node = (rrow < EB2) ? rowS[eidx] : colS[eidx];
        f4_t v = *(const f4_t*)&h[(size_t)node * H + chunk * 4];
        bf4_t hi, lo;
        #pragma unroll
        for (int j = 0; j < 4; j++) {
            hi[j] = f2b(v[j]);
            lo[j] = f2b(v[j] - b2f(hi[j]));
        }
        int dcol = ((rrow < EB2) ? 0 : H) + chunk * 4;
        *(bf4_t*)&fH[eidx * FSB + dcol] = hi;
        *(bf4_t*)&fL[eidx * FSB + dcol] = lo;
    }
    __syncthreads();

    int lane = tid & 63;
    int wv = tid >> 6;
    int ln = lane & 15, quad = lane >> 4;
    int m0 = (wv & 3) * 16;        // 4 m-tiles -> 64 edges
    int ntb = (wv >> 2) * 4;       // 2 n-halves (n-tile base)

    f4_t acc[4];

    // ===== stage 1: t1 = silu(feat @ W1 + b1), K=288; t1 -> cols 128..255 =====
    mm_hl(fH, fL, 0, W1h, W1l, NKB1, m0, ntb, lane, ln, quad, acc);
    __syncthreads();                      // all stage-1 reads done before overwrite
    #pragma unroll
    for (int ni = 0; ni < 4; ni++) {
        int n = (ntb + ni) * 16 + ln;
        float bb = eb1[n];
        #pragma unroll
        for (int r = 0; r < 4; r++) {
            int m = m0 + quad * 4 + r;
            float v = silu_f(acc[ni][r] + bb);
            short hi = f2b(v);
            fH[m * FSB + H + n] = hi;
            fL[m * FSB + H + n] = f2b(v - b2f(hi));
        }
    }
    __syncthreads();

    // ===== stage 2: t2 = silu(t1 @ W2 + b2), K=128; t2 -> cols 0..127 + magg scatter =====
    mm_hl(fH, fL, H, W2h, W2l, 4, m0, ntb, lane, ln, quad, acc);
    // epilogue writes cols 0..127, loop reads cols 128..255 -> disjoint, no barrier needed
    #pragma unroll
    for (int ni = 0; ni < 4; ni++) {
        int n = (ntb + ni) * 16 + ln;
        float bb = eb2[n];
        #pragma unroll
        for (int r = 0; r < 4; r++) {
            int m = m0 + quad * 4 + r;
            float v = silu_f(acc[ni][r] + bb);
            short hi = f2b(v);
            fH[m * FSB + n] = hi;
            fL[m * FSB + n] = f2b(v - b2f(hi));
            if (e0 + m < N_EDGES)
                atomicAdd(&magg[(size_t)rowS[m] * H + n], v);   // fp32 message
        }
    }
    __syncthreads();

    // ===== stage 3: w = silu(t2 @ Wc1 + cb1) @ cw2, K=128 =====
    mm_hl(fH, fL, 0, W3h, W3l, 4, m0, ntb, lane, ln, quad, acc);
    {
        float part[4] = {0.f, 0.f, 0.f, 0.f};
        #pragma unroll
        for (int ni = 0; ni < 4; ni++) {
            int n = (ntb + ni) * 16 + ln;
            float cb = cb1[n], cwv = cw2[n];
            #pragma unroll
            for (int r = 0; r < 4; r++)
                part[r] += silu_f(acc[ni][r] + cb) * cwv;
        }
        #pragma unroll
        for (int r = 0; r < 4; r++) {
            float v = part[r];
            v += __shfl_xor(v, 1, 64);
            v += __shfl_xor(v, 2, 64);
            v += __shfl_xor(v, 4, 64);
            v += __shfl_xor(v, 8, 64);
            part[r] = v;
        }
        if (ln == 0) {
            #pragma unroll
            for (int r = 0; r < 4; r++)
                wpart[m0 + quad * 4 + r][wv >> 2] = part[r];
        }
    }
    __syncthreads();

    // --- scatter pos aggregation ---
    if (tid < EB2 * 3) {
        int e = tid / 3, ax = tid - e * 3;
        if (e0 + e < N_EDGES) {
            float w = wpart[e][0] + wpart[e][1];
            atomicAdd(&pagg[(size_t)rowS[e] * 3 + ax], relS[e][ax] * w);
        }
    }
}

// ---------------- node update (fp32, known-good) ----------------
__global__ __launch_bounds__(128) void node_kernel(
    float* __restrict__ h, const float* __restrict__ magg,
    const float* __restrict__ posagg, const float* __restrict__ deg,
    float* __restrict__ pos,
    const float* __restrict__ nw1, const float* __restrict__ nb1,
    const float* __restrict__ nw2, const float* __restrict__ nb2)
{
    __shared__ float cat[NB][256];
    __shared__ float4 wt[8 * H];
    __shared__ float u1[NB][H];
    int tid = threadIdx.x;
    int n0 = blockIdx.x * NB;

    if (tid < NB * 3) {
        int n = tid / 3, ax = tid % 3;
        int node = n0 + n;
        float d = fmaxf(deg[node], 1.0f);
        pos[node * 3 + ax] += posagg[node * 3 + ax] / d;
    }
    for (int n = 0; n < NB; n++) {
        cat[n][tid]     = h[(size_t)(n0 + n) * H + tid];
        cat[n][H + tid] = magg[(size_t)(n0 + n) * H + tid];
    }

    int c = tid & 63;
    int half = tid >> 6;
    float acc0[8], acc1[8];

    #pragma unroll
    for (int e = 0; e < 8; e++) { acc0[e] = 0.f; acc1[e] = 0.f; }
    for (int kb = 0; kb < 8; kb++) {
        __syncthreads();
        #pragma unroll
        for (int q = 0; q < 8; q++) {
            int k0 = kb * 32 + q * 4;
            float4 w4;
            w4.x = nw1[(k0 + 0) * H + tid];
            w4.y = nw1[(k0 + 1) * H + tid];
            w4.z = nw1[(k0 + 2) * H + tid];
            w4.w = nw1[(k0 + 3) * H + tid];
            wt[q * H + tid] = w4;
        }
        __syncthreads();
        #pragma unroll
        for (int q = 0; q < 8; q++) {
            float4 wa = wt[q * H + c];
            float4 wb = wt[q * H + c + 64];
            int k0 = kb * 32 + q * 4;
            #pragma unroll
            for (int e = 0; e < 8; e++) {
                const float4 f = *(const float4*)&cat[half * 8 + e][k0];
                acc0[e] = fmaf(f.x, wa.x, fmaf(f.y, wa.y, fmaf(f.z, wa.z, fmaf(f.w, wa.w, acc0[e]))));
                acc1[e] = fmaf(f.x, wb.x, fmaf(f.y, wb.y, fmaf(f.z, wb.z, fmaf(f.w, wb.w, acc1[e]))));
            }
        }
    }
    {
        float bb0 = nb1[c], bb1 = nb1[c + 64];
        #pragma unroll
        for (int e = 0; e < 8; e++) {
            u1[half * 8 + e][c]      = silu_f(acc0[e] + bb0);
            u1[half * 8 + e][c + 64] = silu_f(acc1[e] + bb1);
        }
    }

    #pragma unroll
    for (int e = 0; e < 8; e++) { acc0[e] = 0.f; acc1[e] = 0.f; }
    for (int kb = 0; kb < 4; kb++) {
        __syncthreads();
        #pragma unroll
        for (int q = 0; q < 8; q++) {
            int k0 = kb * 32 + q * 4;
            float4 w4;
            w4.x = nw2[(k0 + 0) * H + tid];
            w4.y = nw2[(k0 + 1) * H + tid];
            w4.z = nw2[(k0 + 2) * H + tid];
            w4.w = nw2[(k0 + 3) * H + tid];
            wt[q * H + tid] = w4;
        }
        __syncthreads();
        #pragma unroll
        for (int q = 0; q < 8; q++) {
            float4 wa = wt[q * H + c];
            float4 wb = wt[q * H + c + 64];
            int k0 = kb * 32 + q * 4;
            #pragma unroll
            for (int e = 0; e < 8; e++) {
                const float4 f = *(const float4*)&u1[half * 8 + e][k0];
                acc0[e] = fmaf(f.x, wa.x, fmaf(f.y, wa.y, fmaf(f.z, wa.z, fmaf(f.w, wa.w, acc0[e]))));
                acc1[e] = fmaf(f.x, wb.x, fmaf(f.y, wb.y, fmaf(f.z, wb.z, fmaf(f.w, wb.w, acc1[e]))));
            }
        }
    }
    {
        float bb0 = nb2[c], bb1 = nb2[c + 64];
        #pragma unroll
        for (int e = 0; e < 8; e++) {
            int node = n0 + half * 8 + e;
            h[(size_t)node * H + c]      += acc0[e] + bb0;
            h[(size_t)node * H + c + 64] += acc1[e] + bb1;
        }
    }
}

// ---------------- pooling + head ----------------
__global__ __launch_bounds__(128) void head_kernel(
    const float* __restrict__ h,
    const float* __restrict__ h1w, const float* __restrict__ h1b,
    const float* __restrict__ h2w, const float* __restrict__ h2b,
    const float* __restrict__ h3w, const float* __restrict__ h3b,
    float* __restrict__ out)
{
    __shared__ float gfeat[256];
    __shared__ float z1[128];
    __shared__ float z2[64];
    int tid = threadIdx.x;
    int g = blockIdx.x;
    size_t base = (size_t)g * NPG * H;
    float s = 0.f;
    for (int i = 0; i < NPG; i++) s += h[base + (size_t)i * H + tid];
    gfeat[tid] = s;
    gfeat[H + tid] = s / (float)NPG;
    __syncthreads();
    float a = h1b[tid];
    for (int k = 0; k < 256; k++) a = fmaf(gfeat[k], h1w[k * H + tid], a);
    z1[tid] = fmaxf(a, 0.0f);
    __syncthreads();
    if (tid < 64) {
        float a2 = h2b[tid];
        for (int k = 0; k < 128; k++) a2 = fmaf(z1[k], h2w[k * 64 + tid], a2);
        z2[tid] = fmaxf(a2, 0.0f);
    }
    __syncthreads();
    if (tid < 64) {
        float v = z2[tid] * h3w[tid];
        #pragma unroll
        for (int off = 32; off > 0; off >>= 1) v += __shfl_xor(v, off, 64);
        if (tid == 0) out[g] = v + h3b[0];
    }
}

extern "C" void kernel_launch(void* const* d_in, const int* in_sizes, int n_in,
                              void* d_out, int out_size, void* d_ws, size_t ws_size,
                              hipStream_t stream) {
    const float* x      = (const float*)d_in[0];
    const float* pos_in = (const float*)d_in[1];
    const int*   ei     = (const int*)d_in[2];
    const float* eattr  = (const float*)d_in[3];
    const float* Wp    = (const float*)d_in[6];
    const float* bp    = (const float*)d_in[7];
    const float* Wl    = (const float*)d_in[8];
    const float* bl    = (const float*)d_in[9];
    const float* gamma = (const float*)d_in[10];
    const float* beta  = (const float*)d_in[11];
    const float* ew1   = (const float*)d_in[12];
    const float* eb1   = (const float*)d_in[13];
    const float* ew2   = (const float*)d_in[14];
    const float* eb2   = (const float*)d_in[15];
    const float* cw1   = (const float*)d_in[16];
    const float* cb1   = (const float*)d_in[17];
    const float* cw2   = (const float*)d_in[18];
    const float* nw1   = (const float*)d_in[19];
    const float* nb1   = (const float*)d_in[20];
    const float* nw2   = (const float*)d_in[21];
    const float* nb2   = (const float*)d_in[22];
    const float* h1w   = (const float*)d_in[23];
    const float* h1b   = (const float*)d_in[24];
    const float* h2w   = (const float*)d_in[25];
    const float* h2b   = (const float*)d_in[26];
    const float* h3w   = (const float*)d_in[27];
    const float* h3b   = (const float*)d_in[28];
    float* out = (float*)d_out;

    float* ws   = (float*)d_ws;
    float* hbuf = ws;                                  // N*H f32
    float* magg = hbuf + (size_t)N_NODES * H;          // N*H f32
    float* posb = magg + (size_t)N_NODES * H;          // N*3
    float* pagg = posb + (size_t)N_NODES * 3;          // N*3
    float* deg  = pagg + (size_t)N_NODES * 3;          // N
    float* bnS  = deg + N_NODES;                       // 256
    float* bnP  = bnS + 256;                           // 256
    // fragment-ordered weights: per layer nkb*8*64*8 shorts
    int szW1 = 4 * NKB1 * 4096;                        // 147456
    int szW2 = 4 * 4 * 4096;                           // 65536
    short* W1h  = (short*)(bnP + 256);
    short* W1l  = W1h + szW1;
    short* W2h  = W1l + szW1;
    short* W2l  = W2h + szW2;
    short* W3h  = W2l + szW2;
    short* W3l  = W3h + szW2;

    hipMemcpyAsync(posb, pos_in, (size_t)N_NODES * 3 * sizeof(float),
                   hipMemcpyDeviceToDevice, stream);
    hipMemsetAsync(deg, 0, N_NODES * sizeof(float), stream);
    hipMemsetAsync(bnS, 0, 256 * sizeof(float), stream);

    wprep_frag_kernel<<<(szW1 + 255) / 256, 256, 0, stream>>>(ew1, W1h, W1l, DIN, NKB1);
    wprep_frag_kernel<<<(szW2 + 255) / 256, 256, 0, stream>>>(ew2, W2h, W2l, H, 4);
    wprep_frag_kernel<<<(szW2 + 255) / 256, 256, 0, stream>>>(cw1, W3h, W3l, H, 4);

    proj_kernel<<<N_NODES / NB, 128, 0, stream>>>(x, Wp, bp, Wl, bl, hbuf);
    bn_stats_kernel<<<N_NODES / NPG, 128, 0, stream>>>(hbuf, bnS);
    bn_final_kernel<<<1, 128, 0, stream>>>(bnS, gamma, beta, bnP);
    bn_apply_kernel<<<(N_NODES * H / 4) / 256, 256, 0, stream>>>(hbuf, bnP);
    deg_kernel<<<(N_EDGES + 255) / 256, 256, 0, stream>>>(ei, deg);

    int eblocks = (N_EDGES + EB2 - 1) / EB2;
    for (int l = 0; l < 4; l++) {
        hipMemsetAsync(magg, 0, (size_t)N_NODES * H * sizeof(float), stream);
        hipMemsetAsync(pagg, 0, (size_t)N_NODES * 3 * sizeof(float), stream);
        edge_mfma_kernel<<<eblocks, 512, 0, stream>>>(
            hbuf, posb, ei, eattr,
            W1h + (size_t)l * NKB1 * 4096, W1l + (size_t)l * NKB1 * 4096,
            W2h + (size_t)l * 4 * 4096,    W2l + (size_t)l * 4 * 4096,
            W3h + (size_t)l * 4 * 4096,    W3l + (size_t)l * 4 * 4096,
            eb1 + (size_t)l * H, eb2 + (size_t)l * H,
            cb1 + (size_t)l * H, cw2 + (size_t)l * H,
            magg, pagg);
        node_kernel<<<N_NODES / NB, 128, 0, stream>>>(
            hbuf, magg, pagg, deg, posb,
            nw1 + (size_t)l * 2 * H * H, nb1 + (size_t)l * H,
            nw2 + (size_t)l * H * H,     nb2 + (size_t)l * H);
    }

    head_kernel<<<G_GRAPHS, 128, 0, stream>>>(hbuf, h1w, h1b, h2w, h2b, h3w, h3b, out);
}

// Round 7
// 2696.622 us; speedup vs baseline: 3.5591x; 1.0480x over previous
//
#include <hip/hip_runtime.h>
#include <math.h>

#define N_NODES 50000
#define N_EDGES 500000
#define G_GRAPHS 100
#define NPG 500
#define NPROT 400
#define H 128
#define PN 35
#define LN 11
#define DIN 261      // 2H + 1 + 4
#define KP1 288      // stage-1 K padded to 9 slabs of 32
#define NKB1 9
#define EB2 64       // edges per block (MFMA edge kernel)
#define FSB 296      // feat plane row stride in bf16 (2-way bank alias, free)
#define T2S 132      // t2 fp32 staging stride (dwords; %32=4 -> 2-way, free)
#define NBN 64       // nodes per block (MFMA node kernel)
#define CST 264      // node cat plane stride in bf16 (528B=132dw -> 2-way, free)
#define NB 16        // nodes per workgroup (proj kernel)
#define EPSV 1e-5f

typedef __attribute__((ext_vector_type(8))) short bf8_t;   // 8 bf16 (4 VGPRs)
typedef __attribute__((ext_vector_type(4))) short bf4_t;
typedef __attribute__((ext_vector_type(4))) float f4_t;

__device__ __forceinline__ float silu_f(float x) {
    return x / (1.0f + __expf(-x));
}
__device__ __forceinline__ short f2b(float f) {
    __bf16 b = (__bf16)f;                 // RNE hardware cvt
    return __builtin_bit_cast(short, b);
}
__device__ __forceinline__ float b2f(short s) {
    unsigned u = ((unsigned)(unsigned short)s) << 16;
    return __builtin_bit_cast(float, u);
}

// ---------------- weight prep: fp32 [4][K][H] -> MFMA-fragment-ordered bf16 hi/lo ----------
// dst layout: [l][kb][nt][lane][8]  -> a wave's B-fragment load is one coalesced 1KB chunk.
__global__ void wprep_frag_kernel(const float* __restrict__ src, short* __restrict__ dstH,
                                  short* __restrict__ dstL, int K, int nkb) {
    int idx = blockIdx.x * 256 + threadIdx.x;
    int per_l = nkb * 8 * 64 * 8;
    int total = 4 * per_l;
    if (idx >= total) return;
    int l = idx / per_l;
    int rem = idx - l * per_l;
    int j = rem & 7;
    int lane = (rem >> 3) & 63;
    int nt = (rem >> 9) & 7;
    int kb = rem >> 12;
    int ln = lane & 15, quad = lane >> 4;
    int n = nt * 16 + ln;
    int k = kb * 32 + quad * 8 + j;
    float v = (k < K) ? src[((size_t)l * K + k) * H + n] : 0.0f;
    short hi = f2b(v);
    dstH[idx] = hi;
    dstL[idx] = f2b(v - b2f(hi));
}

// ---------------- edge sort: counting sort by target row ----------------
__global__ void hist_kernel(const int* __restrict__ ei, int* __restrict__ cnt)
{
    int e = blockIdx.x * 256 + threadIdx.x;
    if (e < N_EDGES) atomicAdd(&cnt[ei[e]], 1);
}

__global__ __launch_bounds__(1024) void scan_kernel(const int* __restrict__ cnt, int* __restrict__ base)
{
    __shared__ int buf[1024];
    __shared__ int carry;
    int tid = threadIdx.x;
    if (tid == 0) carry = 0;
    __syncthreads();
    for (int c0 = 0; c0 < N_NODES; c0 += 1024) {
        int i = c0 + tid;
        int v = (i < N_NODES) ? cnt[i] : 0;
        buf[tid] = v;
        __syncthreads();
        for (int off = 1; off < 1024; off <<= 1) {
            int t = (tid >= off) ? buf[tid - off] : 0;
            __syncthreads();
            buf[tid] += t;
            __syncthreads();
        }
        if (i < N_NODES) base[i] = carry + buf[tid] - v;   // exclusive
        __syncthreads();
        if (tid == 1023) carry += buf[1023];
        __syncthreads();
    }
}

__global__ void scatter_kernel(const int* __restrict__ ei, const int* __restrict__ base,
                               int* __restrict__ cursor, int* __restrict__ perm,
                               int* __restrict__ rowsS)
{
    int e = blockIdx.x * 256 + threadIdx.x;
    if (e < N_EDGES) {
        int r = ei[e];
        int p = atomicAdd(&cursor[r], 1);
        int d = base[r] + p;
        perm[d] = e;
        rowsS[d] = r;
    }
}

__global__ void deg_from_cnt_kernel(const int* __restrict__ cnt, float* __restrict__ deg)
{
    int i = blockIdx.x * 256 + threadIdx.x;
    if (i < N_NODES) deg[i] = (float)cnt[i];
}

// ---------------- projection ----------------
__global__ __launch_bounds__(128) void proj_kernel(
    const float* __restrict__ x, const float* __restrict__ Wp, const float* __restrict__ bp,
    const float* __restrict__ Wl, const float* __restrict__ bl, float* __restrict__ h)
{
    __shared__ float xs[NB][36];
    int tid = threadIdx.x;
    int n0 = blockIdx.x * NB;
    for (int idx = tid; idx < NB * PN; idx += 128) {
        int n = idx / PN, k = idx % PN;
        xs[n][k] = x[(size_t)(n0 + n) * PN + k];
    }
    __syncthreads();
    for (int n = 0; n < NB; n++) {
        int node = n0 + n;
        bool isp = (node % NPG) < NPROT;
        float acc;
        if (isp) {
            acc = bp[tid];
            for (int k = 0; k < PN; k++) acc = fmaf(xs[n][k], Wp[k * H + tid], acc);
        } else {
            acc = bl[tid];
            for (int k = 0; k < LN; k++) acc = fmaf(xs[n][k], Wl[k * H + tid], acc);
        }
        h[(size_t)node * H + tid] = acc;
    }
}

// ---------------- batchnorm ----------------
__global__ __launch_bounds__(128) void bn_stats_kernel(const float* __restrict__ h, float* __restrict__ bnS)
{
    int tid = threadIdx.x;
    size_t base = (size_t)blockIdx.x * NPG * H;
    float s1 = 0.f, s2 = 0.f;
    for (int i = 0; i < NPG; i++) {
        float v = h[base + (size_t)i * H + tid];
        s1 += v; s2 += v * v;
    }
    atomicAdd(&bnS[tid], s1);
    atomicAdd(&bnS[H + tid], s2);
}

__global__ void bn_final_kernel(const float* __restrict__ bnS, const float* __restrict__ gamma,
                                const float* __restrict__ beta, float* __restrict__ bnP)
{
    int j = threadIdx.x;
    float mu = bnS[j] / (float)N_NODES;
    float var = bnS[H + j] / (float)N_NODES - mu * mu;
    float inv = rsqrtf(var + EPSV);
    float sc = gamma[j] * inv;
    bnP[j] = sc;
    bnP[H + j] = beta[j] - mu * sc;
}

__global__ __launch_bounds__(256) void bn_apply_kernel(float* __restrict__ h, const float* __restrict__ bnP)
{
    int idx = blockIdx.x * 256 + threadIdx.x;
    float4 v = ((float4*)h)[idx];
    int j4 = (idx & 31) * 4;
    v.x = fmaf(v.x, bnP[j4 + 0], bnP[H + j4 + 0]);
    v.y = fmaf(v.y, bnP[j4 + 1], bnP[H + j4 + 1]);
    v.z = fmaf(v.z, bnP[j4 + 2], bnP[H + j4 + 2]);
    v.w = fmaf(v.w, bnP[j4 + 3], bnP[H + j4 + 3]);
    ((float4*)h)[idx] = v;
}

// ---------------- hi/lo bf16 MFMA k-loop (fp32-equivalent, 3-term) ----------------
// 8 waves: m0=(wv&3)*16 (4 m-tiles), ntb=(wv>>2)*4 (2 n-halves of 4 n-tiles).
__device__ __forceinline__ void mm_hl(
    const short* fHp, const short* fLp, int stride, int aoff,
    const short* __restrict__ WH, const short* __restrict__ WL,
    int nkb, int m0, int ntb, int lane, int ln, int quad, f4_t acc[4])
{
    #pragma unroll
    for (int ni = 0; ni < 4; ni++) acc[ni] = (f4_t)(0.0f);
    for (int kb = 0; kb < nkb; kb++) {
        int k0 = kb * 32 + quad * 8;
        bf8_t ah = *(const bf8_t*)&fHp[(m0 + ln) * stride + aoff + k0];
        bf8_t al = *(const bf8_t*)&fLp[(m0 + ln) * stride + aoff + k0];
        #pragma unroll
        for (int ni = 0; ni < 4; ni++) {
            int off = ((kb * 8 + ntb + ni) * 64 + lane) * 8;
            bf8_t bh = *(const bf8_t*)&WH[off];
            bf8_t bl = *(const bf8_t*)&WL[off];
            acc[ni] = __builtin_amdgcn_mfma_f32_16x16x32_bf16(ah, bh, acc[ni], 0, 0, 0);
            acc[ni] = __builtin_amdgcn_mfma_f32_16x16x32_bf16(al, bh, acc[ni], 0, 0, 0);
            acc[ni] = __builtin_amdgcn_mfma_f32_16x16x32_bf16(ah, bl, acc[ni], 0, 0, 0);
        }
    }
}

// ---------------- MFMA edge kernel (sorted edges + segmented reduce) ----------------
__global__ __launch_bounds__(512, 4) void edge_mfma_kernel(
    const float* __restrict__ h, const float* __restrict__ pos,
    const int* __restrict__ ei, const float* __restrict__ eattr,
    const int* __restrict__ perm, const int* __restrict__ rowsS,
    const short* __restrict__ W1h, const short* __restrict__ W1l,
    const short* __restrict__ W2h, const short* __restrict__ W2l,
    const short* __restrict__ W3h, const short* __restrict__ W3l,
    const float* __restrict__ eb1, const float* __restrict__ eb2,
    const float* __restrict__ cb1, const float* __restrict__ cw2,
    float* __restrict__ magg, float* __restrict__ pagg)
{
    __shared__ __align__(16) short fH[EB2 * FSB];   // 37888 B (t2f fp32 overlays later)
    __shared__ __align__(16) short fL[EB2 * FSB];   // 37888 B
    __shared__ float relS[EB2][3];
    __shared__ float wpart[EB2][2];
    __shared__ int rowS[EB2];    // -1 sentinel for padded edges
    __shared__ int rowG[EB2];    // clamped (valid) row for gather
    __shared__ int colS[EB2];

    int tid = threadIdx.x;
    int e0 = blockIdx.x * EB2;

    // --- edge meta (sorted order): rel, d2, attr (hi/lo), zero-pad cols 261..287 ---
    if (tid < EB2) {
        int e = e0 + tid;
        int eidx = (e < N_EDGES) ? e : (N_EDGES - 1);
        int ec = perm[eidx];
        int r = rowsS[eidx];
        int c = ei[N_EDGES + ec];
        rowG[tid] = r;
        rowS[tid] = (e < N_EDGES) ? r : -1;
        colS[tid] = c;
        float rx = pos[r * 3 + 0] - pos[c * 3 + 0];
        float ry = pos[r * 3 + 1] - pos[c * 3 + 1];
        float rz = pos[r * 3 + 2] - pos[c * 3 + 2];
        relS[tid][0] = rx; relS[tid][1] = ry; relS[tid][2] = rz;
        float mv[5];
        mv[0] = rx * rx + ry * ry + rz * rz;
        mv[1] = eattr[(size_t)ec * 4 + 0];
        mv[2] = eattr[(size_t)ec * 4 + 1];
        mv[3] = eattr[(size_t)ec * 4 + 2];
        mv[4] = eattr[(size_t)ec * 4 + 3];
        #pragma unroll
        for (int j = 0; j < 5; j++) {
            short hi = f2b(mv[j]);
            fH[tid * FSB + 256 + j] = hi;
            fL[tid * FSB + 256 + j] = f2b(mv[j] - b2f(hi));
        }
        for (int k2 = 261; k2 < KP1; k2++) {
            fH[tid * FSB + k2] = 0;
            fL[tid * FSB + k2] = 0;
        }
    }
    __syncthreads();

    // --- gather h[row] -> cols 0..127, h[col] -> cols 128..255 (fp32 -> hi/lo bf16) ---
    for (int i = tid; i < 2 * EB2 * (H / 4); i += 512) {
        int rrow = i >> 5, chunk = i & 31;
        int eidx = rrow & (EB2 - 1);
        int node = (rrow < EB2) ? rowG[eidx] : colS[eidx];
        f4_t v = *(const f4_t*)&h[(size_t)node * H + chunk * 4];
        bf4_t hi, lo;
        #pragma unroll
        for (int j = 0; j < 4; j++) {
            hi[j] = f2b(v[j]);
            lo[j] = f2b(v[j] - b2f(hi[j]));
        }
        int dcol = ((rrow < EB2) ? 0 : H) + chunk * 4;
        *(bf4_t*)&fH[eidx * FSB + dcol] = hi;
        *(bf4_t*)&fL[eidx * FSB + dcol] = lo;
    }
    __syncthreads();

    int lane = tid & 63;
    int wv = tid >> 6;
    int ln = lane & 15, quad = lane >> 4;
    int m0 = (wv & 3) * 16;
    int ntb = (wv >> 2) * 4;

    f4_t acc[4];
    float t2s[4][4];

    // ===== stage 1: t1 = silu(feat @ W1 + b1), K=288; t1 -> cols 128..255 =====
    mm_hl(fH, fL, FSB, 0, W1h, W1l, NKB1, m0, ntb, lane, ln, quad, acc);
    __syncthreads();
    #pragma unroll
    for (int ni = 0; ni < 4; ni++) {
        int n = (ntb + ni) * 16 + ln;
        float bb = eb1[n];
        #pragma unroll
        for (int r = 0; r < 4; r++) {
            int m = m0 + quad * 4 + r;
            float v = silu_f(acc[ni][r] + bb);
            short hi = f2b(v);
            fH[m * FSB + H + n] = hi;
            fL[m * FSB + H + n] = f2b(v - b2f(hi));
        }
    }
    __syncthreads();

    // ===== stage 2: t2 = silu(t1 @ W2 + b2), K=128; t2 hi/lo -> cols 0..127, fp32 -> regs =====
    mm_hl(fH, fL, FSB, H, W2h, W2l, 4, m0, ntb, lane, ln, quad, acc);
    #pragma unroll
    for (int ni = 0; ni < 4; ni++) {
        int n = (ntb + ni) * 16 + ln;
        float bb = eb2[n];
        #pragma unroll
        for (int r = 0; r < 4; r++) {
            int m = m0 + quad * 4 + r;
            float v = silu_f(acc[ni][r] + bb);
            t2s[ni][r] = v;
            short hi = f2b(v);
            fH[m * FSB + n] = hi;
            fL[m * FSB + n] = f2b(v - b2f(hi));
        }
    }
    __syncthreads();

    // ===== stage 3: w = silu(t2 @ Wc1 + cb1) @ cw2, K=128 =====
    mm_hl(fH, fL, FSB, 0, W3h, W3l, 4, m0, ntb, lane, ln, quad, acc);
    __syncthreads();   // stage-3 LDS reads done -> safe to overlay t2f on fH

    // --- stage-3 epilogue: per-edge w, and stage t2 fp32 into LDS ---
    float* t2f = (float*)fH;   // 64 x T2S fp32 = 33792 B <= 37888 B
    #pragma unroll
    for (int ni = 0; ni < 4; ni++) {
        int n = (ntb + ni) * 16 + ln;
        #pragma unroll
        for (int r = 0; r < 4; r++)
            t2f[(m0 + quad * 4 + r) * T2S + n] = t2s[ni][r];
    }
    {
        float part[4] = {0.f, 0.f, 0.f, 0.f};
        #pragma unroll
        for (int ni = 0; ni < 4; ni++) {
            int n = (ntb + ni) * 16 + ln;
            float cb = cb1[n], cwv = cw2[n];
            #pragma unroll
            for (int r = 0; r < 4; r++)
                part[r] += silu_f(acc[ni][r] + cb) * cwv;
        }
        #pragma unroll
        for (int r = 0; r < 4; r++) {
            float v = part[r];
            v += __shfl_xor(v, 1, 64);
            v += __shfl_xor(v, 2, 64);
            v += __shfl_xor(v, 4, 64);
            v += __shfl_xor(v, 8, 64);
            part[r] = v;
        }
        if (ln == 0) {
            #pragma unroll
            for (int r = 0; r < 4; r++)
                wpart[m0 + quad * 4 + r][wv >> 2] = part[r];
        }
    }
    __syncthreads();

    // --- segmented reduction over sorted rows: one atomic per (run, channel) ---
    if (tid < H) {
        int ch = tid;
        float a2 = 0.f; int cur = -1;
        for (int e2 = 0; e2 < EB2; e2++) {
            int r2 = rowS[e2];
            float v2 = t2f[e2 * T2S + ch];
            if (r2 != cur) {
                if (cur >= 0) atomicAdd(&magg[(size_t)cur * H + ch], a2);
                cur = r2; a2 = v2;
            } else a2 += v2;
        }
        if (cur >= 0) atomicAdd(&magg[(size_t)cur * H + ch], a2);
    } else if (tid < H + 3) {
        int ax = tid - H;
        float a2 = 0.f; int cur = -1;
        for (int e2 = 0; e2 < EB2; e2++) {
            int r2 = rowS[e2];
            float w2 = (wpart[e2][0] + wpart[e2][1]) * relS[e2][ax];
            if (r2 != cur) {
                if (cur >= 0) atomicAdd(&pagg[(size_t)cur * 3 + ax], a2);
                cur = r2; a2 = w2;
            } else a2 += w2;
        }
        if (cur >= 0) atomicAdd(&pagg[(size_t)cur * 3 + ax], a2);
    }
}

// ---------------- MFMA node kernel (hi/lo bf16, fp32-equivalent) ----------------
__global__ __launch_bounds__(512, 4) void node_mfma_kernel(
    float* __restrict__ h, const float* __restrict__ magg,
    const float* __restrict__ pagg, const float* __restrict__ deg,
    float* __restrict__ pos,
    const short* __restrict__ N1h, const short* __restrict__ N1l,
    const short* __restrict__ N2h, const short* __restrict__ N2l,
    const float* __restrict__ nb1, const float* __restrict__ nb2)
{
    __shared__ __align__(16) short fH[NBN * CST];   // 33792 B
    __shared__ __align__(16) short fL[NBN * CST];   // 33792 B

    int tid = threadIdx.x;
    int n0 = blockIdx.x * NBN;

    // --- pos update ---
    if (tid < NBN * 3) {
        int n = tid / 3, ax = tid - n * 3;
        int node = n0 + n;
        if (node < N_NODES) {
            float d = fmaxf(deg[node], 1.0f);
            pos[node * 3 + ax] += pagg[node * 3 + ax] / d;
        }
    }

    // --- gather h -> cols 0..127, magg -> cols 128..255 (fp32 -> hi/lo) ---
    for (int i = tid; i < 2 * NBN * (H / 4); i += 512) {
        int rrow = i >> 5, chunk = i & 31;
        int nidx = rrow & (NBN - 1);
        int node = n0 + nidx;
        if (node >= N_NODES) node = N_NODES - 1;
        const float* src = (rrow < NBN) ? h : magg;
        f4_t v = *(const f4_t*)&src[(size_t)node * H + chunk * 4];
        bf4_t hi, lo;
        #pragma unroll
        for (int j = 0; j < 4; j++) {
            hi[j] = f2b(v[j]);
            lo[j] = f2b(v[j] - b2f(hi[j]));
        }
        int dcol = ((rrow < NBN) ? 0 : H) + chunk * 4;
        *(bf4_t*)&fH[nidx * CST + dcol] = hi;
        *(bf4_t*)&fL[nidx * CST + dcol] = lo;
    }
    __syncthreads();

    int lane = tid & 63;
    int wv = tid >> 6;
    int ln = lane & 15, quad = lane >> 4;
    int m0 = (wv & 3) * 16;
    int ntb = (wv >> 2) * 4;

    f4_t acc[4];

    // ===== stage A: u1 = silu(cat @ N1 + nb1), K=256; u1 hi/lo -> cols 0..127 =====
    mm_hl(fH, fL, CST, 0, N1h, N1l, 8, m0, ntb, lane, ln, quad, acc);
    __syncthreads();
    #pragma unroll
    for (int ni = 0; ni < 4; ni++) {
        int n = (ntb + ni) * 16 + ln;
        float bb = nb1[n];
        #pragma unroll
        for (int r = 0; r < 4; r++) {
            int m = m0 + quad * 4 + r;
            float v = silu_f(acc[ni][r] + bb);
            short hi = f2b(v);
            fH[m * CST + n] = hi;
            fL[m * CST + n] = f2b(v - b2f(hi));
        }
    }
    __syncthreads();

    // ===== stage B: h += u1 @ N2 + nb2, K=128 =====
    mm_hl(fH, fL, CST, 0, N2h, N2l, 4, m0, ntb, lane, ln, quad, acc);
    #pragma unroll
    for (int ni = 0; ni < 4; ni++) {
        int n = (ntb + ni) * 16 + ln;
        float bb = nb2[n];
        #pragma unroll
        for (int r = 0; r < 4; r++) {
            int m = m0 + quad * 4 + r;
            int node = n0 + m;
            if (node < N_NODES)
                h[(size_t)node * H + n] += acc[ni][r] + bb;
        }
    }
}

// ---------------- pooling + head ----------------
__global__ __launch_bounds__(128) void head_kernel(
    const float* __restrict__ h,
    const float* __restrict__ h1w, const float* __restrict__ h1b,
    const float* __restrict__ h2w, const float* __restrict__ h2b,
    const float* __restrict__ h3w, const float* __restrict__ h3b,
    float* __restrict__ out)
{
    __shared__ float gfeat[256];
    __shared__ float z1[128];
    __shared__ float z2[64];
    int tid = threadIdx.x;
    int g = blockIdx.x;
    size_t base = (size_t)g * NPG * H;
    float s = 0.f;
    for (int i = 0; i < NPG; i++) s += h[base + (size_t)i * H + tid];
    gfeat[tid] = s;
    gfeat[H + tid] = s / (float)NPG;
    __syncthreads();
    float a = h1b[tid];
    for (int k = 0; k < 256; k++) a = fmaf(gfeat[k], h1w[k * H + tid], a);
    z1[tid] = fmaxf(a, 0.0f);
    __syncthreads();
    if (tid < 64) {
        float a2 = h2b[tid];
        for (int k = 0; k < 128; k++) a2 = fmaf(z1[k], h2w[k * 64 + tid], a2);
        z2[tid] = fmaxf(a2, 0.0f);
    }
    __syncthreads();
    if (tid < 64) {
        float v = z2[tid] * h3w[tid];
        #pragma unroll
        for (int off = 32; off > 0; off >>= 1) v += __shfl_xor(v, off, 64);
        if (tid == 0) out[g] = v + h3b[0];
    }
}

extern "C" void kernel_launch(void* const* d_in, const int* in_sizes, int n_in,
                              void* d_out, int out_size, void* d_ws, size_t ws_size,
                              hipStream_t stream) {
    const float* x      = (const float*)d_in[0];
    const float* pos_in = (const float*)d_in[1];
    const int*   ei     = (const int*)d_in[2];
    const float* eattr  = (const float*)d_in[3];
    const float* Wp    = (const float*)d_in[6];
    const float* bp    = (const float*)d_in[7];
    const float* Wl    = (const float*)d_in[8];
    const float* bl    = (const float*)d_in[9];
    const float* gamma = (const float*)d_in[10];
    const float* beta  = (const float*)d_in[11];
    const float* ew1   = (const float*)d_in[12];
    const float* eb1   = (const float*)d_in[13];
    const float* ew2   = (const float*)d_in[14];
    const float* eb2   = (const float*)d_in[15];
    const float* cw1   = (const float*)d_in[16];
    const float* cb1   = (const float*)d_in[17];
    const float* cw2   = (const float*)d_in[18];
    const float* nw1   = (const float*)d_in[19];
    const float* nb1   = (const float*)d_in[20];
    const float* nw2   = (const float*)d_in[21];
    const float* nb2   = (const float*)d_in[22];
    const float* h1w   = (const float*)d_in[23];
    const float* h1b   = (const float*)d_in[24];
    const float* h2w   = (const float*)d_in[25];
    const float* h2b   = (const float*)d_in[26];
    const float* h3w   = (const float*)d_in[27];
    const float* h3b   = (const float*)d_in[28];
    float* out = (float*)d_out;

    float* ws   = (float*)d_ws;
    float* hbuf = ws;                                  // N*H f32
    float* magg = hbuf + (size_t)N_NODES * H;          // N*H f32
    float* posb = magg + (size_t)N_NODES * H;          // N*3
    float* pagg = posb + (size_t)N_NODES * 3;          // N*3
    float* deg  = pagg + (size_t)N_NODES * 3;          // N
    float* bnS  = deg + N_NODES;                       // 256
    float* bnP  = bnS + 256;                           // 256
    int* cnt    = (int*)(bnP + 256);                   // N
    int* basep  = cnt + N_NODES;                       // N
    int* cursor = basep + N_NODES;                     // N
    int* perm   = cursor + N_NODES;                    // E
    int* rowsS  = perm + N_EDGES;                      // E
    // fragment-ordered bf16 hi/lo weights
    int szW1 = 4 * NKB1 * 4096;                        // 147456 shorts per plane
    int szW2 = 4 * 4 * 4096;                           // 65536
    int szN1 = 4 * 8 * 4096;                           // 131072
    short* W1h = (short*)(rowsS + N_EDGES);
    short* W1l = W1h + szW1;
    short* W2h = W1l + szW1;
    short* W2l = W2h + szW2;
    short* W3h = W2l + szW2;
    short* W3l = W3h + szW2;
    short* N1h = W3l + szW2;
    short* N1l = N1h + szN1;
    short* N2h = N1l + szN1;
    short* N2l = N2h + szW2;

    hipMemcpyAsync(posb, pos_in, (size_t)N_NODES * 3 * sizeof(float),
                   hipMemcpyDeviceToDevice, stream);
    hipMemsetAsync(cnt, 0, N_NODES * sizeof(int), stream);
    hipMemsetAsync(cursor, 0, N_NODES * sizeof(int), stream);
    hipMemsetAsync(bnS, 0, 256 * sizeof(float), stream);

    // --- edge sort by target row ---
    hist_kernel<<<(N_EDGES + 255) / 256, 256, 0, stream>>>(ei, cnt);
    scan_kernel<<<1, 1024, 0, stream>>>(cnt, basep);
    scatter_kernel<<<(N_EDGES + 255) / 256, 256, 0, stream>>>(ei, basep, cursor, perm, rowsS);
    deg_from_cnt_kernel<<<(N_NODES + 255) / 256, 256, 0, stream>>>(cnt, deg);

    // --- weight prep ---
    wprep_frag_kernel<<<(szW1 + 255) / 256, 256, 0, stream>>>(ew1, W1h, W1l, DIN, NKB1);
    wprep_frag_kernel<<<(szW2 + 255) / 256, 256, 0, stream>>>(ew2, W2h, W2l, H, 4);
    wprep_frag_kernel<<<(szW2 + 255) / 256, 256, 0, stream>>>(cw1, W3h, W3l, H, 4);
    wprep_frag_kernel<<<(szN1 + 255) / 256, 256, 0, stream>>>(nw1, N1h, N1l, 256, 8);
    wprep_frag_kernel<<<(szW2 + 255) / 256, 256, 0, stream>>>(nw2, N2h, N2l, H, 4);

    proj_kernel<<<N_NODES / NB, 128, 0, stream>>>(x, Wp, bp, Wl, bl, hbuf);
    bn_stats_kernel<<<N_NODES / NPG, 128, 0, stream>>>(hbuf, bnS);
    bn_final_kernel<<<1, 128, 0, stream>>>(bnS, gamma, beta, bnP);
    bn_apply_kernel<<<(N_NODES * H / 4) / 256, 256, 0, stream>>>(hbuf, bnP);

    int eblocks = (N_EDGES + EB2 - 1) / EB2;
    int nblocks = (N_NODES + NBN - 1) / NBN;
    for (int l = 0; l < 4; l++) {
        hipMemsetAsync(magg, 0, (size_t)N_NODES * H * sizeof(float), stream);
        hipMemsetAsync(pagg, 0, (size_t)N_NODES * 3 * sizeof(float), stream);
        edge_mfma_kernel<<<eblocks, 512, 0, stream>>>(
            hbuf, posb, ei, eattr, perm, rowsS,
            W1h + (size_t)l * NKB1 * 4096, W1l + (size_t)l * NKB1 * 4096,
            W2h + (size_t)l * 4 * 4096,    W2l + (size_t)l * 4 * 4096,
            W3h + (size_t)l * 4 * 4096,    W3l + (size_t)l * 4 * 4096,
            eb1 + (size_t)l * H, eb2 + (size_t)l * H,
            cb1 + (size_t)l * H, cw2 + (size_t)l * H,
            magg, pagg);
        node_mfma_kernel<<<nblocks, 512, 0, stream>>>(
            hbuf, magg, pagg, deg, posb,
            N1h + (size_t)l * 8 * 4096, N1l + (size_t)l * 8 * 4096,
            N2h + (size_t)l * 4 * 4096, N2l + (size_t)l * 4 * 4096,
            nb1 + (size_t)l * H, nb2 + (size_t)l * H);
    }

    head_kernel<<<G_GRAPHS, 128, 0, stream>>>(hbuf, h1w, h1b, h2w, h2b, h3w, h3b, out);
}

// Round 8
// 1697.840 us; speedup vs baseline: 5.6528x; 1.5883x over previous
//
#include <hip/hip_runtime.h>
#include <math.h>

#define N_NODES 50000
#define N_EDGES 500000
#define G_GRAPHS 100
#define NPG 500
#define NPROT 400
#define H 128
#define PN 35
#define LN 11
#define DIN 261      // 2H + 1 + 4
#define EB2 64       // edges per block (MFMA edge kernel)
#define FS2 136      // bf16 plane row stride (272B = 68 dw, %32=4 -> 2-way, free)
#define T2S 132      // t2 fp32 staging stride (dw, %32=4 -> 2-way, free)
#define NBN 64       // nodes per block (MFMA node kernel)
#define CST 264      // node cat plane stride in bf16 (2-way, free)
#define NB 16        // nodes per workgroup (proj kernel)
#define EPSV 1e-5f

typedef __attribute__((ext_vector_type(8))) short bf8_t;   // 8 bf16 (4 VGPRs)
typedef __attribute__((ext_vector_type(4))) short bf4_t;
typedef __attribute__((ext_vector_type(4))) float f4_t;

__device__ __forceinline__ float silu_f(float x) {
    return x / (1.0f + __expf(-x));
}
__device__ __forceinline__ short f2b(float f) {
    __bf16 b = (__bf16)f;
    return __builtin_bit_cast(short, b);
}
__device__ __forceinline__ float b2f(short s) {
    unsigned u = ((unsigned)(unsigned short)s) << 16;
    return __builtin_bit_cast(float, u);
}

// ---- weight prep: fp32 [4][Ksrc][H] (+row offset) -> fragment-ordered bf16 hi/lo ----
// dst: [l][kb][nt][lane][8] -> a wave's B-fragment load is one coalesced 1KB chunk.
__global__ void wprep_frag_kernel(const float* __restrict__ src, short* __restrict__ dstH,
                                  short* __restrict__ dstL, int Ksrc, int nkb, int koff) {
    int idx = blockIdx.x * 256 + threadIdx.x;
    int per_l = nkb * 8 * 64 * 8;
    int total = 4 * per_l;
    if (idx >= total) return;
    int l = idx / per_l;
    int rem = idx - l * per_l;
    int j = rem & 7;
    int lane = (rem >> 3) & 63;
    int nt = (rem >> 9) & 7;
    int kb = rem >> 12;
    int ln = lane & 15, quad = lane >> 4;
    int n = nt * 16 + ln;
    int k = koff + kb * 32 + quad * 8 + j;
    float v = (k < Ksrc) ? src[((size_t)l * Ksrc + k) * H + n] : 0.0f;
    short hi = f2b(v);
    dstH[idx] = hi;
    dstL[idx] = f2b(v - b2f(hi));
}

// ---------------- edge sort: counting sort by target row ----------------
__global__ void hist_kernel(const int* __restrict__ ei, int* __restrict__ cnt)
{
    int e = blockIdx.x * 256 + threadIdx.x;
    if (e < N_EDGES) atomicAdd(&cnt[ei[e]], 1);
}

__global__ __launch_bounds__(1024) void scan_kernel(const int* __restrict__ cnt, int* __restrict__ base)
{
    __shared__ int buf[1024];
    __shared__ int carry;
    int tid = threadIdx.x;
    if (tid == 0) carry = 0;
    __syncthreads();
    for (int c0 = 0; c0 < N_NODES; c0 += 1024) {
        int i = c0 + tid;
        int v = (i < N_NODES) ? cnt[i] : 0;
        buf[tid] = v;
        __syncthreads();
        for (int off = 1; off < 1024; off <<= 1) {
            int t = (tid >= off) ? buf[tid - off] : 0;
            __syncthreads();
            buf[tid] += t;
            __syncthreads();
        }
        if (i < N_NODES) base[i] = carry + buf[tid] - v;
        __syncthreads();
        if (tid == 1023) carry += buf[1023];
        __syncthreads();
    }
}

__global__ void scatter_kernel(const int* __restrict__ ei, const int* __restrict__ base,
                               int* __restrict__ cursor, int* __restrict__ perm,
                               int* __restrict__ rowsS)
{
    int e = blockIdx.x * 256 + threadIdx.x;
    if (e < N_EDGES) {
        int r = ei[e];
        int p = atomicAdd(&cursor[r], 1);
        int d = base[r] + p;
        perm[d] = e;
        rowsS[d] = r;
    }
}

__global__ void deg_from_cnt_kernel(const int* __restrict__ cnt, float* __restrict__ deg)
{
    int i = blockIdx.x * 256 + threadIdx.x;
    if (i < N_NODES) deg[i] = (float)cnt[i];
}

// ---------------- projection ----------------
__global__ __launch_bounds__(128) void proj_kernel(
    const float* __restrict__ x, const float* __restrict__ Wp, const float* __restrict__ bp,
    const float* __restrict__ Wl, const float* __restrict__ bl, float* __restrict__ h)
{
    __shared__ float xs[NB][36];
    int tid = threadIdx.x;
    int n0 = blockIdx.x * NB;
    for (int idx = tid; idx < NB * PN; idx += 128) {
        int n = idx / PN, k = idx % PN;
        xs[n][k] = x[(size_t)(n0 + n) * PN + k];
    }
    __syncthreads();
    for (int n = 0; n < NB; n++) {
        int node = n0 + n;
        bool isp = (node % NPG) < NPROT;
        float acc;
        if (isp) {
            acc = bp[tid];
            for (int k = 0; k < PN; k++) acc = fmaf(xs[n][k], Wp[k * H + tid], acc);
        } else {
            acc = bl[tid];
            for (int k = 0; k < LN; k++) acc = fmaf(xs[n][k], Wl[k * H + tid], acc);
        }
        h[(size_t)node * H + tid] = acc;
    }
}

// ---------------- batchnorm ----------------
__global__ __launch_bounds__(128) void bn_stats_kernel(const float* __restrict__ h, float* __restrict__ bnS)
{
    int tid = threadIdx.x;
    size_t base = (size_t)blockIdx.x * NPG * H;
    float s1 = 0.f, s2 = 0.f;
    for (int i = 0; i < NPG; i++) {
        float v = h[base + (size_t)i * H + tid];
        s1 += v; s2 += v * v;
    }
    atomicAdd(&bnS[tid], s1);
    atomicAdd(&bnS[H + tid], s2);
}

__global__ void bn_final_kernel(const float* __restrict__ bnS, const float* __restrict__ gamma,
                                const float* __restrict__ beta, float* __restrict__ bnP)
{
    int j = threadIdx.x;
    float mu = bnS[j] / (float)N_NODES;
    float var = bnS[H + j] / (float)N_NODES - mu * mu;
    float inv = rsqrtf(var + EPSV);
    float sc = gamma[j] * inv;
    bnP[j] = sc;
    bnP[H + j] = beta[j] - mu * sc;
}

__global__ __launch_bounds__(256) void bn_apply_kernel(float* __restrict__ h, const float* __restrict__ bnP)
{
    int idx = blockIdx.x * 256 + threadIdx.x;
    float4 v = ((float4*)h)[idx];
    int j4 = (idx & 31) * 4;
    v.x = fmaf(v.x, bnP[j4 + 0], bnP[H + j4 + 0]);
    v.y = fmaf(v.y, bnP[j4 + 1], bnP[H + j4 + 1]);
    v.z = fmaf(v.z, bnP[j4 + 2], bnP[H + j4 + 2]);
    v.w = fmaf(v.w, bnP[j4 + 3], bnP[H + j4 + 3]);
    ((float4*)h)[idx] = v;
}

// ---- hi/lo bf16 MFMA k-loop: 4 m-tiles x 1 n-tile per wave (weights read once) ----
__device__ __forceinline__ void mm_hl4(
    const short* fH, const short* fL, int stride,
    const short* __restrict__ WH, const short* __restrict__ WL,
    int nkb, int nt, int lane, int ln, int quad, f4_t acc[4])
{
    #pragma unroll
    for (int mi = 0; mi < 4; mi++) acc[mi] = (f4_t)(0.0f);
    for (int kb = 0; kb < nkb; kb++) {
        int k0 = kb * 32 + quad * 8;
        int off = ((kb * 8 + nt) * 64 + lane) * 8;
        bf8_t bh = *(const bf8_t*)&WH[off];
        bf8_t bl = *(const bf8_t*)&WL[off];
        #pragma unroll
        for (int mi = 0; mi < 4; mi++) {
            bf8_t ah = *(const bf8_t*)&fH[(mi * 16 + ln) * stride + k0];
            bf8_t al = *(const bf8_t*)&fL[(mi * 16 + ln) * stride + k0];
            acc[mi] = __builtin_amdgcn_mfma_f32_16x16x32_bf16(ah, bh, acc[mi], 0, 0, 0);
            acc[mi] = __builtin_amdgcn_mfma_f32_16x16x32_bf16(al, bh, acc[mi], 0, 0, 0);
            acc[mi] = __builtin_amdgcn_mfma_f32_16x16x32_bf16(ah, bl, acc[mi], 0, 0, 0);
        }
    }
}

// ---------------- per-layer node pre-projection: P1 = h@W1a, P2 = h@W1b ----------------
__global__ __launch_bounds__(512, 4) void p12_kernel(
    const float* __restrict__ h,
    const short* __restrict__ Ah, const short* __restrict__ Al,
    const short* __restrict__ Bh, const short* __restrict__ Bl,
    float* __restrict__ P1, float* __restrict__ P2)
{
    __shared__ __align__(16) short fH[NBN * FS2];
    __shared__ __align__(16) short fL[NBN * FS2];
    int tid = threadIdx.x;
    int n0 = blockIdx.x * NBN;

    for (int i = tid; i < NBN * (H / 4); i += 512) {
        int nidx = i >> 5, chunk = i & 31;
        int node = n0 + nidx;
        if (node >= N_NODES) node = N_NODES - 1;
        f4_t v = *(const f4_t*)&h[(size_t)node * H + chunk * 4];
        bf4_t hi, lo;
        #pragma unroll
        for (int j = 0; j < 4; j++) {
            hi[j] = f2b(v[j]);
            lo[j] = f2b(v[j] - b2f(hi[j]));
        }
        *(bf4_t*)&fH[nidx * FS2 + chunk * 4] = hi;
        *(bf4_t*)&fL[nidx * FS2 + chunk * 4] = lo;
    }
    __syncthreads();

    int lane = tid & 63;
    int nt = tid >> 6;
    int ln = lane & 15, quad = lane >> 4;

    f4_t accA[4], accB[4];
    #pragma unroll
    for (int mi = 0; mi < 4; mi++) { accA[mi] = (f4_t)(0.0f); accB[mi] = (f4_t)(0.0f); }
    for (int kb = 0; kb < 4; kb++) {
        int k0 = kb * 32 + quad * 8;
        int off = ((kb * 8 + nt) * 64 + lane) * 8;
        bf8_t bhA = *(const bf8_t*)&Ah[off];
        bf8_t blA = *(const bf8_t*)&Al[off];
        bf8_t bhB = *(const bf8_t*)&Bh[off];
        bf8_t blB = *(const bf8_t*)&Bl[off];
        #pragma unroll
        for (int mi = 0; mi < 4; mi++) {
            bf8_t ah = *(const bf8_t*)&fH[(mi * 16 + ln) * FS2 + k0];
            bf8_t al = *(const bf8_t*)&fL[(mi * 16 + ln) * FS2 + k0];
            accA[mi] = __builtin_amdgcn_mfma_f32_16x16x32_bf16(ah, bhA, accA[mi], 0, 0, 0);
            accA[mi] = __builtin_amdgcn_mfma_f32_16x16x32_bf16(al, bhA, accA[mi], 0, 0, 0);
            accA[mi] = __builtin_amdgcn_mfma_f32_16x16x32_bf16(ah, blA, accA[mi], 0, 0, 0);
            accB[mi] = __builtin_amdgcn_mfma_f32_16x16x32_bf16(ah, bhB, accB[mi], 0, 0, 0);
            accB[mi] = __builtin_amdgcn_mfma_f32_16x16x32_bf16(al, bhB, accB[mi], 0, 0, 0);
            accB[mi] = __builtin_amdgcn_mfma_f32_16x16x32_bf16(ah, blB, accB[mi], 0, 0, 0);
        }
    }
    int n = nt * 16 + ln;
    #pragma unroll
    for (int mi = 0; mi < 4; mi++) {
        #pragma unroll
        for (int r = 0; r < 4; r++) {
            int node = n0 + mi * 16 + quad * 4 + r;
            if (node < N_NODES) {
                P1[(size_t)node * H + n] = accA[mi][r];
                P2[(size_t)node * H + n] = accB[mi][r];
            }
        }
    }
}

// ---------------- MFMA edge kernel (stage-1 fused into gather) ----------------
__global__ __launch_bounds__(512, 4) void edge_mfma_kernel(
    const float* __restrict__ P1, const float* __restrict__ P2,
    const float* __restrict__ pos,
    const int* __restrict__ ei, const float* __restrict__ eattr,
    const int* __restrict__ perm, const int* __restrict__ rowsS,
    const float* __restrict__ W1c, const float* __restrict__ eb1,
    const short* __restrict__ W2h, const short* __restrict__ W2l,
    const short* __restrict__ W3h, const short* __restrict__ W3l,
    const float* __restrict__ eb2,
    const float* __restrict__ cb1, const float* __restrict__ cw2,
    float* __restrict__ magg, float* __restrict__ pagg)
{
    __shared__ __align__(16) short fHL[2 * EB2 * FS2];   // 34816 B; t2f fp32 overlays later
    __shared__ float relS[EB2][3];
    __shared__ float attrS[EB2][5];    // d2, eattr0..3
    __shared__ float wpart[EB2][8];
    __shared__ int rowS[EB2];          // -1 sentinel for padded
    __shared__ int rowG[EB2];
    __shared__ int colS[EB2];

    short* fH = fHL;
    short* fL = fHL + EB2 * FS2;
    int tid = threadIdx.x;
    int e0 = blockIdx.x * EB2;

    // --- edge meta ---
    if (tid < EB2) {
        int e = e0 + tid;
        int eidx = (e < N_EDGES) ? e : (N_EDGES - 1);
        int ec = perm[eidx];
        int r = rowsS[eidx];
        int c = ei[N_EDGES + ec];
        rowG[tid] = r;
        rowS[tid] = (e < N_EDGES) ? r : -1;
        colS[tid] = c;
        float rx = pos[r * 3 + 0] - pos[c * 3 + 0];
        float ry = pos[r * 3 + 1] - pos[c * 3 + 1];
        float rz = pos[r * 3 + 2] - pos[c * 3 + 2];
        relS[tid][0] = rx; relS[tid][1] = ry; relS[tid][2] = rz;
        attrS[tid][0] = rx * rx + ry * ry + rz * rz;
        attrS[tid][1] = eattr[(size_t)ec * 4 + 0];
        attrS[tid][2] = eattr[(size_t)ec * 4 + 1];
        attrS[tid][3] = eattr[(size_t)ec * 4 + 2];
        attrS[tid][4] = eattr[(size_t)ec * 4 + 3];
    }
    __syncthreads();

    // --- fused stage 1: t1 = silu(P1[row] + P2[col] + extra@W1c + b1) -> hi/lo LDS ---
    for (int i = tid; i < EB2 * (H / 4); i += 512) {   // 2048 chunks
        int e = i >> 5, ch4 = (i & 31) * 4;
        int r = rowG[e], c = colS[e];
        f4_t p1 = *(const f4_t*)&P1[(size_t)r * H + ch4];
        f4_t p2 = *(const f4_t*)&P2[(size_t)c * H + ch4];
        f4_t bb = *(const f4_t*)&eb1[ch4];
        float t[4];
        #pragma unroll
        for (int j = 0; j < 4; j++) t[j] = p1[j] + p2[j] + bb[j];
        #pragma unroll
        for (int k = 0; k < 5; k++) {
            f4_t w = *(const f4_t*)&W1c[k * H + ch4];
            float ex = attrS[e][k];
            #pragma unroll
            for (int j = 0; j < 4; j++) t[j] = fmaf(ex, w[j], t[j]);
        }
        bf4_t hi, lo;
        #pragma unroll
        for (int j = 0; j < 4; j++) {
            float v = silu_f(t[j]);
            hi[j] = f2b(v);
            lo[j] = f2b(v - b2f(hi[j]));
        }
        *(bf4_t*)&fH[e * FS2 + ch4] = hi;
        *(bf4_t*)&fL[e * FS2 + ch4] = lo;
    }
    __syncthreads();

    int lane = tid & 63;
    int nt = tid >> 6;            // 8 waves = 8 n-tiles
    int ln = lane & 15, quad = lane >> 4;
    int n = nt * 16 + ln;

    f4_t acc[4];
    float t2s[4][4];

    // ===== stage 2: t2 = silu(t1 @ W2 + b2), K=128 =====
    mm_hl4(fH, fL, FS2, W2h, W2l, 4, nt, lane, ln, quad, acc);
    {
        float bb = eb2[n];
        #pragma unroll
        for (int mi = 0; mi < 4; mi++)
            #pragma unroll
            for (int r = 0; r < 4; r++)
                t2s[mi][r] = silu_f(acc[mi][r] + bb);
    }
    __syncthreads();   // all stage-2 reads of t1 done
    #pragma unroll
    for (int mi = 0; mi < 4; mi++) {
        #pragma unroll
        for (int r = 0; r < 4; r++) {
            int m = mi * 16 + quad * 4 + r;
            float v = t2s[mi][r];
            short hi = f2b(v);
            fH[m * FS2 + n] = hi;
            fL[m * FS2 + n] = f2b(v - b2f(hi));
        }
    }
    __syncthreads();

    // ===== stage 3: w = silu(t2 @ Wc1 + cb1) @ cw2, K=128 =====
    mm_hl4(fH, fL, FS2, W3h, W3l, 4, nt, lane, ln, quad, acc);
    {
        float cb = cb1[n], cwv = cw2[n];
        #pragma unroll
        for (int mi = 0; mi < 4; mi++) {
            #pragma unroll
            for (int r = 0; r < 4; r++) {
                float v = silu_f(acc[mi][r] + cb) * cwv;
                v += __shfl_xor(v, 1, 64);
                v += __shfl_xor(v, 2, 64);
                v += __shfl_xor(v, 4, 64);
                v += __shfl_xor(v, 8, 64);
                if (ln == 0) wpart[mi * 16 + quad * 4 + r][nt] = v;
            }
        }
    }
    __syncthreads();   // stage-3 LDS reads done -> safe to overlay t2f

    // --- stage t2 fp32 into LDS (overlay on fHL) ---
    float* t2f = (float*)fHL;   // 64 x T2S fp32 = 33792 B <= 34816 B
    #pragma unroll
    for (int mi = 0; mi < 4; mi++)
        #pragma unroll
        for (int r = 0; r < 4; r++)
            t2f[(mi * 16 + quad * 4 + r) * T2S + n] = t2s[mi][r];
    __syncthreads();

    // --- segmented reduction over sorted rows (all 512 threads: 128 ch x 4 segs) ---
    {
        int ch = tid & 127, seg = tid >> 7;
        int ebeg = seg * 16, eend = ebeg + 16;
        float a2 = 0.f; int cur = -1;
        for (int e2 = ebeg; e2 < eend; e2++) {
            int r2 = rowS[e2];
            float v2 = t2f[e2 * T2S + ch];
            if (r2 != cur) {
                if (cur >= 0) atomicAdd(&magg[(size_t)cur * H + ch], a2);
                cur = r2; a2 = v2;
            } else a2 += v2;
        }
        if (cur >= 0) atomicAdd(&magg[(size_t)cur * H + ch], a2);
    }
    if (tid < 12) {
        int ax = tid % 3, seg = tid / 3;
        int ebeg = seg * 16, eend = ebeg + 16;
        float a2 = 0.f; int cur = -1;
        for (int e2 = ebeg; e2 < eend; e2++) {
            int r2 = rowS[e2];
            float w2 = 0.f;
            #pragma unroll
            for (int g = 0; g < 8; g++) w2 += wpart[e2][g];
            w2 *= relS[e2][ax];
            if (r2 != cur) {
                if (cur >= 0) atomicAdd(&pagg[(size_t)cur * 3 + ax], a2);
                cur = r2; a2 = w2;
            } else a2 += w2;
        }
        if (cur >= 0) atomicAdd(&pagg[(size_t)cur * 3 + ax], a2);
    }
}

// ---------------- MFMA node kernel (hi/lo bf16, fp32-equivalent) ----------------
__global__ __launch_bounds__(512, 4) void node_mfma_kernel(
    float* __restrict__ h, const float* __restrict__ magg,
    const float* __restrict__ pagg, const float* __restrict__ deg,
    float* __restrict__ pos,
    const short* __restrict__ N1h, const short* __restrict__ N1l,
    const short* __restrict__ N2h, const short* __restrict__ N2l,
    const float* __restrict__ nb1, const float* __restrict__ nb2)
{
    __shared__ __align__(16) short fH[NBN * CST];   // 33792 B
    __shared__ __align__(16) short fL[NBN * CST];   // 33792 B

    int tid = threadIdx.x;
    int n0 = blockIdx.x * NBN;

    if (tid < NBN * 3) {
        int n = tid / 3, ax = tid - n * 3;
        int node = n0 + n;
        if (node < N_NODES) {
            float d = fmaxf(deg[node], 1.0f);
            pos[node * 3 + ax] += pagg[node * 3 + ax] / d;
        }
    }

    for (int i = tid; i < 2 * NBN * (H / 4); i += 512) {
        int rrow = i >> 5, chunk = i & 31;
        int nidx = rrow & (NBN - 1);
        int node = n0 + nidx;
        if (node >= N_NODES) node = N_NODES - 1;
        const float* src = (rrow < NBN) ? h : magg;
        f4_t v = *(const f4_t*)&src[(size_t)node * H + chunk * 4];
        bf4_t hi, lo;
        #pragma unroll
        for (int j = 0; j < 4; j++) {
            hi[j] = f2b(v[j]);
            lo[j] = f2b(v[j] - b2f(hi[j]));
        }
        int dcol = ((rrow < NBN) ? 0 : H) + chunk * 4;
        *(bf4_t*)&fH[nidx * CST + dcol] = hi;
        *(bf4_t*)&fL[nidx * CST + dcol] = lo;
    }
    __syncthreads();

    int lane = tid & 63;
    int nt = tid >> 6;
    int ln = lane & 15, quad = lane >> 4;
    int n = nt * 16 + ln;

    f4_t acc[4];
    float u1s[4][4];

    // stage A: u1 = silu(cat @ N1 + nb1), K=256
    mm_hl4(fH, fL, CST, N1h, N1l, 8, nt, lane, ln, quad, acc);
    {
        float bb = nb1[n];
        #pragma unroll
        for (int mi = 0; mi < 4; mi++)
            #pragma unroll
            for (int r = 0; r < 4; r++)
                u1s[mi][r] = silu_f(acc[mi][r] + bb);
    }
    __syncthreads();
    #pragma unroll
    for (int mi = 0; mi < 4; mi++) {
        #pragma unroll
        for (int r = 0; r < 4; r++) {
            int m = mi * 16 + quad * 4 + r;
            float v = u1s[mi][r];
            short hi = f2b(v);
            fH[m * CST + n] = hi;
            fL[m * CST + n] = f2b(v - b2f(hi));
        }
    }
    __syncthreads();

    // stage B: h += u1 @ N2 + nb2, K=128
    mm_hl4(fH, fL, CST, N2h, N2l, 4, nt, lane, ln, quad, acc);
    {
        float bb = nb2[n];
        #pragma unroll
        for (int mi = 0; mi < 4; mi++) {
            #pragma unroll
            for (int r = 0; r < 4; r++) {
                int node = n0 + mi * 16 + quad * 4 + r;
                if (node < N_NODES)
                    h[(size_t)node * H + n] += acc[mi][r] + bb;
            }
        }
    }
}

// ---------------- pooling + head ----------------
__global__ __launch_bounds__(128) void head_kernel(
    const float* __restrict__ h,
    const float* __restrict__ h1w, const float* __restrict__ h1b,
    const float* __restrict__ h2w, const float* __restrict__ h2b,
    const float* __restrict__ h3w, const float* __restrict__ h3b,
    float* __restrict__ out)
{
    __shared__ float gfeat[256];
    __shared__ float z1[128];
    __shared__ float z2[64];
    int tid = threadIdx.x;
    int g = blockIdx.x;
    size_t base = (size_t)g * NPG * H;
    float s = 0.f;
    for (int i = 0; i < NPG; i++) s += h[base + (size_t)i * H + tid];
    gfeat[tid] = s;
    gfeat[H + tid] = s / (float)NPG;
    __syncthreads();
    float a = h1b[tid];
    for (int k = 0; k < 256; k++) a = fmaf(gfeat[k], h1w[k * H + tid], a);
    z1[tid] = fmaxf(a, 0.0f);
    __syncthreads();
    if (tid < 64) {
        float a2 = h2b[tid];
        for (int k = 0; k < 128; k++) a2 = fmaf(z1[k], h2w[k * 64 + tid], a2);
        z2[tid] = fmaxf(a2, 0.0f);
    }
    __syncthreads();
    if (tid < 64) {
        float v = z2[tid] * h3w[tid];
        #pragma unroll
        for (int off = 32; off > 0; off >>= 1) v += __shfl_xor(v, off, 64);
        if (tid == 0) out[g] = v + h3b[0];
    }
}

extern "C" void kernel_launch(void* const* d_in, const int* in_sizes, int n_in,
                              void* d_out, int out_size, void* d_ws, size_t ws_size,
                              hipStream_t stream) {
    const float* x      = (const float*)d_in[0];
    const float* pos_in = (const float*)d_in[1];
    const int*   ei     = (const int*)d_in[2];
    const float* eattr  = (const float*)d_in[3];
    const float* Wp    = (const float*)d_in[6];
    const float* bp    = (const float*)d_in[7];
    const float* Wl    = (const float*)d_in[8];
    const float* bl    = (const float*)d_in[9];
    const float* gamma = (const float*)d_in[10];
    const float* beta  = (const float*)d_in[11];
    const float* ew1   = (const float*)d_in[12];
    const float* eb1   = (const float*)d_in[13];
    const float* ew2   = (const float*)d_in[14];
    const float* eb2   = (const float*)d_in[15];
    const float* cw1   = (const float*)d_in[16];
    const float* cb1   = (const float*)d_in[17];
    const float* cw2   = (const float*)d_in[18];
    const float* nw1   = (const float*)d_in[19];
    const float* nb1   = (const float*)d_in[20];
    const float* nw2   = (const float*)d_in[21];
    const float* nb2   = (const float*)d_in[22];
    const float* h1w   = (const float*)d_in[23];
    const float* h1b   = (const float*)d_in[24];
    const float* h2w   = (const float*)d_in[25];
    const float* h2b   = (const float*)d_in[26];
    const float* h3w   = (const float*)d_in[27];
    const float* h3b   = (const float*)d_in[28];
    float* out = (float*)d_out;

    float* ws   = (float*)d_ws;
    float* hbuf = ws;                                  // N*H f32
    float* magg = hbuf + (size_t)N_NODES * H;          // N*H f32
    float* P1   = magg + (size_t)N_NODES * H;          // N*H f32
    float* P2   = P1 + (size_t)N_NODES * H;            // N*H f32
    float* posb = P2 + (size_t)N_NODES * H;            // N*3
    float* pagg = posb + (size_t)N_NODES * 3;          // N*3
    float* deg  = pagg + (size_t)N_NODES * 3;          // N
    float* bnS  = deg + N_NODES;                       // 256
    float* bnP  = bnS + 256;                           // 256
    int* cnt    = (int*)(bnP + 256);                   // N
    int* basep  = cnt + N_NODES;                       // N
    int* cursor = basep + N_NODES;                     // N
    int* perm   = cursor + N_NODES;                    // E
    int* rowsS  = perm + N_EDGES;                      // E
    // fragment-ordered bf16 hi/lo weights (per plane: 4 layers x nkb x 4096 shorts)
    int szK4 = 4 * 4 * 4096;                           // K=128 weights
    int szK8 = 4 * 8 * 4096;                           // K=256 weights
    short* W1aH = (short*)(rowsS + N_EDGES);
    short* W1aL = W1aH + szK4;
    short* W1bH = W1aL + szK4;
    short* W1bL = W1bH + szK4;
    short* W2h  = W1bL + szK4;
    short* W2l  = W2h + szK4;
    short* W3h  = W2l + szK4;
    short* W3l  = W3h + szK4;
    short* N1h  = W3l + szK4;
    short* N1l  = N1h + szK8;
    short* N2h  = N1l + szK8;
    short* N2l  = N2h + szK4;

    hipMemcpyAsync(posb, pos_in, (size_t)N_NODES * 3 * sizeof(float),
                   hipMemcpyDeviceToDevice, stream);
    hipMemsetAsync(cnt, 0, N_NODES * sizeof(int), stream);
    hipMemsetAsync(cursor, 0, N_NODES * sizeof(int), stream);
    hipMemsetAsync(bnS, 0, 256 * sizeof(float), stream);

    // --- edge sort by target row ---
    hist_kernel<<<(N_EDGES + 255) / 256, 256, 0, stream>>>(ei, cnt);
    scan_kernel<<<1, 1024, 0, stream>>>(cnt, basep);
    scatter_kernel<<<(N_EDGES + 255) / 256, 256, 0, stream>>>(ei, basep, cursor, perm, rowsS);
    deg_from_cnt_kernel<<<(N_NODES + 255) / 256, 256, 0, stream>>>(cnt, deg);

    // --- weight prep (fragment-ordered hi/lo) ---
    wprep_frag_kernel<<<(szK4 + 255) / 256, 256, 0, stream>>>(ew1, W1aH, W1aL, DIN, 4, 0);
    wprep_frag_kernel<<<(szK4 + 255) / 256, 256, 0, stream>>>(ew1, W1bH, W1bL, DIN, 4, H);
    wprep_frag_kernel<<<(szK4 + 255) / 256, 256, 0, stream>>>(ew2, W2h, W2l, H, 4, 0);
    wprep_frag_kernel<<<(szK4 + 255) / 256, 256, 0, stream>>>(cw1, W3h, W3l, H, 4, 0);
    wprep_frag_kernel<<<(szK8 + 255) / 256, 256, 0, stream>>>(nw1, N1h, N1l, 256, 8, 0);
    wprep_frag_kernel<<<(szK4 + 255) / 256, 256, 0, stream>>>(nw2, N2h, N2l, H, 4, 0);

    proj_kernel<<<N_NODES / NB, 128, 0, stream>>>(x, Wp, bp, Wl, bl, hbuf);
    bn_stats_kernel<<<N_NODES / NPG, 128, 0, stream>>>(hbuf, bnS);
    bn_final_kernel<<<1, 128, 0, stream>>>(bnS, gamma, beta, bnP);
    bn_apply_kernel<<<(N_NODES * H / 4) / 256, 256, 0, stream>>>(hbuf, bnP);

    int eblocks = (N_EDGES + EB2 - 1) / EB2;
    int nblocks = (N_NODES + NBN - 1) / NBN;
    for (int l = 0; l < 4; l++) {
        hipMemsetAsync(magg, 0, (size_t)N_NODES * H * sizeof(float), stream);
        hipMemsetAsync(pagg, 0, (size_t)N_NODES * 3 * sizeof(float), stream);
        p12_kernel<<<nblocks, 512, 0, stream>>>(
            hbuf,
            W1aH + (size_t)l * 4 * 4096, W1aL + (size_t)l * 4 * 4096,
            W1bH + (size_t)l * 4 * 4096, W1bL + (size_t)l * 4 * 4096,
            P1, P2);
        edge_mfma_kernel<<<eblocks, 512, 0, stream>>>(
            P1, P2, posb, ei, eattr, perm, rowsS,
            ew1 + (size_t)l * DIN * H + (size_t)2 * H * H,   // W1c rows 256..260
            eb1 + (size_t)l * H,
            W2h + (size_t)l * 4 * 4096, W2l + (size_t)l * 4 * 4096,
            W3h + (size_t)l * 4 * 4096, W3l + (size_t)l * 4 * 4096,
            eb2 + (size_t)l * H,
            cb1 + (size_t)l * H, cw2 + (size_t)l * H,
            magg, pagg);
        node_mfma_kernel<<<nblocks, 512, 0, stream>>>(
            hbuf, magg, pagg, deg, posb,
            N1h + (size_t)l * 8 * 4096, N1l + (size_t)l * 8 * 4096,
            N2h + (size_t)l * 4 * 4096, N2l + (size_t)l * 4 * 4096,
            nb1 + (size_t)l * H, nb2 + (size_t)l * H);
    }

    head_kernel<<<G_GRAPHS, 128, 0, stream>>>(hbuf, h1w, h1b, h2w, h2b, h3w, h3b, out);
}

// Round 9
// 1531.944 us; speedup vs baseline: 6.2650x; 1.1083x over previous
//
#include <hip/hip_runtime.h>
#include <math.h>

#define N_NODES 50000
#define N_EDGES 500000
#define G_GRAPHS 100
#define NPG 500
#define NPROT 400
#define H 128
#define PN 35
#define LN 11
#define DIN 261      // 2H + 1 + 4
#define EB2 32       // edges per block (MFMA edge kernel)
#define FS2 136      // bf16 plane row stride (272B = 68 dw, %32=4 -> 2-way, free)
#define T2S 132      // t2 fp32 staging stride (dw, %32=4 -> 2-way, free)
#define NBN 64       // nodes per block (MFMA node kernel)
#define CST 264      // node cat plane stride in bf16 (2-way, free)
#define NB 16        // nodes per workgroup (proj kernel)
#define EPSV 1e-5f

typedef __attribute__((ext_vector_type(8))) short bf8_t;   // 8 bf16 (4 VGPRs)
typedef __attribute__((ext_vector_type(4))) short bf4_t;
typedef __attribute__((ext_vector_type(4))) float f4_t;

__device__ __forceinline__ float silu_f(float x) {
    return x / (1.0f + __expf(-x));
}
__device__ __forceinline__ short f2b(float f) {
    __bf16 b = (__bf16)f;
    return __builtin_bit_cast(short, b);
}
__device__ __forceinline__ float b2f(short s) {
    unsigned u = ((unsigned)(unsigned short)s) << 16;
    return __builtin_bit_cast(float, u);
}

// ---- weight prep: fp32 [4][Ksrc][H] (+row offset) -> fragment-ordered bf16 hi/lo ----
__global__ void wprep_frag_kernel(const float* __restrict__ src, short* __restrict__ dstH,
                                  short* __restrict__ dstL, int Ksrc, int nkb, int koff) {
    int idx = blockIdx.x * 256 + threadIdx.x;
    int per_l = nkb * 8 * 64 * 8;
    int total = 4 * per_l;
    if (idx >= total) return;
    int l = idx / per_l;
    int rem = idx - l * per_l;
    int j = rem & 7;
    int lane = (rem >> 3) & 63;
    int nt = (rem >> 9) & 7;
    int kb = rem >> 12;
    int ln = lane & 15, quad = lane >> 4;
    int n = nt * 16 + ln;
    int k = koff + kb * 32 + quad * 8 + j;
    float v = (k < Ksrc) ? src[((size_t)l * Ksrc + k) * H + n] : 0.0f;
    short hi = f2b(v);
    dstH[idx] = hi;
    dstL[idx] = f2b(v - b2f(hi));
}

// ---------------- edge sort: counting sort by target row ----------------
__global__ void hist_kernel(const int* __restrict__ ei, int* __restrict__ cnt)
{
    int e = blockIdx.x * 256 + threadIdx.x;
    if (e < N_EDGES) atomicAdd(&cnt[ei[e]], 1);
}

__global__ __launch_bounds__(1024) void scan_kernel(const int* __restrict__ cnt, int* __restrict__ base)
{
    __shared__ int buf[1024];
    __shared__ int carry;
    int tid = threadIdx.x;
    if (tid == 0) carry = 0;
    __syncthreads();
    for (int c0 = 0; c0 < N_NODES; c0 += 1024) {
        int i = c0 + tid;
        int v = (i < N_NODES) ? cnt[i] : 0;
        buf[tid] = v;
        __syncthreads();
        for (int off = 1; off < 1024; off <<= 1) {
            int t = (tid >= off) ? buf[tid - off] : 0;
            __syncthreads();
            buf[tid] += t;
            __syncthreads();
        }
        if (i < N_NODES) base[i] = carry + buf[tid] - v;
        __syncthreads();
        if (tid == 1023) carry += buf[1023];
        __syncthreads();
    }
}

__global__ void scatter_kernel(const int* __restrict__ ei, const int* __restrict__ base,
                               int* __restrict__ cursor, int* __restrict__ perm,
                               int* __restrict__ rowsS)
{
    int e = blockIdx.x * 256 + threadIdx.x;
    if (e < N_EDGES) {
        int r = ei[e];
        int p = atomicAdd(&cursor[r], 1);
        int d = base[r] + p;
        perm[d] = e;
        rowsS[d] = r;
    }
}

__global__ void deg_from_cnt_kernel(const int* __restrict__ cnt, float* __restrict__ deg)
{
    int i = blockIdx.x * 256 + threadIdx.x;
    if (i < N_NODES) deg[i] = (float)cnt[i];
}

// ---------------- projection ----------------
__global__ __launch_bounds__(128) void proj_kernel(
    const float* __restrict__ x, const float* __restrict__ Wp, const float* __restrict__ bp,
    const float* __restrict__ Wl, const float* __restrict__ bl, float* __restrict__ h)
{
    __shared__ float xs[NB][36];
    int tid = threadIdx.x;
    int n0 = blockIdx.x * NB;
    for (int idx = tid; idx < NB * PN; idx += 128) {
        int n = idx / PN, k = idx % PN;
        xs[n][k] = x[(size_t)(n0 + n) * PN + k];
    }
    __syncthreads();
    for (int n = 0; n < NB; n++) {
        int node = n0 + n;
        bool isp = (node % NPG) < NPROT;
        float acc;
        if (isp) {
            acc = bp[tid];
            for (int k = 0; k < PN; k++) acc = fmaf(xs[n][k], Wp[k * H + tid], acc);
        } else {
            acc = bl[tid];
            for (int k = 0; k < LN; k++) acc = fmaf(xs[n][k], Wl[k * H + tid], acc);
        }
        h[(size_t)node * H + tid] = acc;
    }
}

// ---------------- batchnorm ----------------
__global__ __launch_bounds__(128) void bn_stats_kernel(const float* __restrict__ h, float* __restrict__ bnS)
{
    int tid = threadIdx.x;
    size_t base = (size_t)blockIdx.x * NPG * H;
    float s1 = 0.f, s2 = 0.f;
    for (int i = 0; i < NPG; i++) {
        float v = h[base + (size_t)i * H + tid];
        s1 += v; s2 += v * v;
    }
    atomicAdd(&bnS[tid], s1);
    atomicAdd(&bnS[H + tid], s2);
}

__global__ void bn_final_kernel(const float* __restrict__ bnS, const float* __restrict__ gamma,
                                const float* __restrict__ beta, float* __restrict__ bnP)
{
    int j = threadIdx.x;
    float mu = bnS[j] / (float)N_NODES;
    float var = bnS[H + j] / (float)N_NODES - mu * mu;
    float inv = rsqrtf(var + EPSV);
    float sc = gamma[j] * inv;
    bnP[j] = sc;
    bnP[H + j] = beta[j] - mu * sc;
}

__global__ __launch_bounds__(256) void bn_apply_kernel(float* __restrict__ h, const float* __restrict__ bnP)
{
    int idx = blockIdx.x * 256 + threadIdx.x;
    float4 v = ((float4*)h)[idx];
    int j4 = (idx & 31) * 4;
    v.x = fmaf(v.x, bnP[j4 + 0], bnP[H + j4 + 0]);
    v.y = fmaf(v.y, bnP[j4 + 1], bnP[H + j4 + 1]);
    v.z = fmaf(v.z, bnP[j4 + 2], bnP[H + j4 + 2]);
    v.w = fmaf(v.w, bnP[j4 + 3], bnP[H + j4 + 3]);
    ((float4*)h)[idx] = v;
}

// ---- hi/lo bf16 MFMA k-loop: 2 m-tiles x 2 n-tiles per wave (EB=32 edge kernel) ----
__device__ __forceinline__ void mm_hl2(
    const short* fH, const short* fL, int stride,
    const short* __restrict__ WH, const short* __restrict__ WL,
    int nkb, int nt0, int lane, int ln, int quad, f4_t acc[2][2])
{
    #pragma unroll
    for (int mi = 0; mi < 2; mi++)
        #pragma unroll
        for (int ni = 0; ni < 2; ni++) acc[mi][ni] = (f4_t)(0.0f);
    for (int kb = 0; kb < nkb; kb++) {
        int k0 = kb * 32 + quad * 8;
        bf8_t ah0 = *(const bf8_t*)&fH[(ln) * stride + k0];
        bf8_t al0 = *(const bf8_t*)&fL[(ln) * stride + k0];
        bf8_t ah1 = *(const bf8_t*)&fH[(16 + ln) * stride + k0];
        bf8_t al1 = *(const bf8_t*)&fL[(16 + ln) * stride + k0];
        #pragma unroll
        for (int ni = 0; ni < 2; ni++) {
            int off = ((kb * 8 + nt0 + ni) * 64 + lane) * 8;
            bf8_t bh = *(const bf8_t*)&WH[off];
            bf8_t bl = *(const bf8_t*)&WL[off];
            acc[0][ni] = __builtin_amdgcn_mfma_f32_16x16x32_bf16(ah0, bh, acc[0][ni], 0, 0, 0);
            acc[0][ni] = __builtin_amdgcn_mfma_f32_16x16x32_bf16(al0, bh, acc[0][ni], 0, 0, 0);
            acc[0][ni] = __builtin_amdgcn_mfma_f32_16x16x32_bf16(ah0, bl, acc[0][ni], 0, 0, 0);
            acc[1][ni] = __builtin_amdgcn_mfma_f32_16x16x32_bf16(ah1, bh, acc[1][ni], 0, 0, 0);
            acc[1][ni] = __builtin_amdgcn_mfma_f32_16x16x32_bf16(al1, bh, acc[1][ni], 0, 0, 0);
            acc[1][ni] = __builtin_amdgcn_mfma_f32_16x16x32_bf16(ah1, bl, acc[1][ni], 0, 0, 0);
        }
    }
}

// ---- hi/lo bf16 MFMA k-loop: 4 m-tiles x 1 n-tile per wave (node kernel, 512 thr) ----
__device__ __forceinline__ void mm_hl4(
    const short* fH, const short* fL, int stride,
    const short* __restrict__ WH, const short* __restrict__ WL,
    int nkb, int nt, int lane, int ln, int quad, f4_t acc[4])
{
    #pragma unroll
    for (int mi = 0; mi < 4; mi++) acc[mi] = (f4_t)(0.0f);
    for (int kb = 0; kb < nkb; kb++) {
        int k0 = kb * 32 + quad * 8;
        int off = ((kb * 8 + nt) * 64 + lane) * 8;
        bf8_t bh = *(const bf8_t*)&WH[off];
        bf8_t bl = *(const bf8_t*)&WL[off];
        #pragma unroll
        for (int mi = 0; mi < 4; mi++) {
            bf8_t ah = *(const bf8_t*)&fH[(mi * 16 + ln) * stride + k0];
            bf8_t al = *(const bf8_t*)&fL[(mi * 16 + ln) * stride + k0];
            acc[mi] = __builtin_amdgcn_mfma_f32_16x16x32_bf16(ah, bh, acc[mi], 0, 0, 0);
            acc[mi] = __builtin_amdgcn_mfma_f32_16x16x32_bf16(al, bh, acc[mi], 0, 0, 0);
            acc[mi] = __builtin_amdgcn_mfma_f32_16x16x32_bf16(ah, bl, acc[mi], 0, 0, 0);
        }
    }
}

// ---------------- initial node pre-projection (layer 0): P1 = h@W1a, P2 = h@W1b ----------------
__global__ __launch_bounds__(512, 4) void p12_kernel(
    const float* __restrict__ h,
    const short* __restrict__ Ah, const short* __restrict__ Al,
    const short* __restrict__ Bh, const short* __restrict__ Bl,
    float* __restrict__ P1, float* __restrict__ P2)
{
    __shared__ __align__(16) short fH[NBN * FS2];
    __shared__ __align__(16) short fL[NBN * FS2];
    int tid = threadIdx.x;
    int n0 = blockIdx.x * NBN;

    for (int i = tid; i < NBN * (H / 4); i += 512) {
        int nidx = i >> 5, chunk = i & 31;
        int node = n0 + nidx;
        if (node >= N_NODES) node = N_NODES - 1;
        f4_t v = *(const f4_t*)&h[(size_t)node * H + chunk * 4];
        bf4_t hi, lo;
        #pragma unroll
        for (int j = 0; j < 4; j++) {
            hi[j] = f2b(v[j]);
            lo[j] = f2b(v[j] - b2f(hi[j]));
        }
        *(bf4_t*)&fH[nidx * FS2 + chunk * 4] = hi;
        *(bf4_t*)&fL[nidx * FS2 + chunk * 4] = lo;
    }
    __syncthreads();

    int lane = tid & 63;
    int nt = tid >> 6;
    int ln = lane & 15, quad = lane >> 4;

    f4_t accA[4], accB[4];
    #pragma unroll
    for (int mi = 0; mi < 4; mi++) { accA[mi] = (f4_t)(0.0f); accB[mi] = (f4_t)(0.0f); }
    for (int kb = 0; kb < 4; kb++) {
        int k0 = kb * 32 + quad * 8;
        int off = ((kb * 8 + nt) * 64 + lane) * 8;
        bf8_t bhA = *(const bf8_t*)&Ah[off];
        bf8_t blA = *(const bf8_t*)&Al[off];
        bf8_t bhB = *(const bf8_t*)&Bh[off];
        bf8_t blB = *(const bf8_t*)&Bl[off];
        #pragma unroll
        for (int mi = 0; mi < 4; mi++) {
            bf8_t ah = *(const bf8_t*)&fH[(mi * 16 + ln) * FS2 + k0];
            bf8_t al = *(const bf8_t*)&fL[(mi * 16 + ln) * FS2 + k0];
            accA[mi] = __builtin_amdgcn_mfma_f32_16x16x32_bf16(ah, bhA, accA[mi], 0, 0, 0);
            accA[mi] = __builtin_amdgcn_mfma_f32_16x16x32_bf16(al, bhA, accA[mi], 0, 0, 0);
            accA[mi] = __builtin_amdgcn_mfma_f32_16x16x32_bf16(ah, blA, accA[mi], 0, 0, 0);
            accB[mi] = __builtin_amdgcn_mfma_f32_16x16x32_bf16(ah, bhB, accB[mi], 0, 0, 0);
            accB[mi] = __builtin_amdgcn_mfma_f32_16x16x32_bf16(al, bhB, accB[mi], 0, 0, 0);
            accB[mi] = __builtin_amdgcn_mfma_f32_16x16x32_bf16(ah, blB, accB[mi], 0, 0, 0);
        }
    }
    int n = nt * 16 + ln;
    #pragma unroll
    for (int mi = 0; mi < 4; mi++) {
        #pragma unroll
        for (int r = 0; r < 4; r++) {
            int node = n0 + mi * 16 + quad * 4 + r;
            if (node < N_NODES) {
                P1[(size_t)node * H + n] = accA[mi][r];
                P2[(size_t)node * H + n] = accB[mi][r];
            }
        }
    }
}

// ---------------- MFMA edge kernel (EB=32, 256 thr, 8 blocks/CU) ----------------
__global__ __launch_bounds__(256, 8) void edge_mfma_kernel(
    const float* __restrict__ P1, const float* __restrict__ P2,
    const float* __restrict__ pos,
    const int* __restrict__ ei, const float* __restrict__ eattr,
    const int* __restrict__ perm, const int* __restrict__ rowsS,
    const float* __restrict__ W1c, const float* __restrict__ eb1,
    const short* __restrict__ W2h, const short* __restrict__ W2l,
    const short* __restrict__ W3h, const short* __restrict__ W3l,
    const float* __restrict__ eb2,
    const float* __restrict__ cb1, const float* __restrict__ cw2,
    float* __restrict__ magg, float* __restrict__ pagg)
{
    __shared__ __align__(16) short fHL[2 * EB2 * FS2];   // 17408 B; t2f fp32 overlays later
    __shared__ float relS[EB2][3];
    __shared__ float attrS[EB2][5];
    __shared__ float wpart[EB2][4];
    __shared__ int rowS[EB2];
    __shared__ int rowG[EB2];
    __shared__ int colS[EB2];

    short* fH = fHL;
    short* fL = fHL + EB2 * FS2;
    int tid = threadIdx.x;
    int e0 = blockIdx.x * EB2;

    // --- edge meta ---
    if (tid < EB2) {
        int e = e0 + tid;
        int eidx = (e < N_EDGES) ? e : (N_EDGES - 1);
        int ec = perm[eidx];
        int r = rowsS[eidx];
        int c = ei[N_EDGES + ec];
        rowG[tid] = r;
        rowS[tid] = (e < N_EDGES) ? r : -1;
        colS[tid] = c;
        float rx = pos[r * 3 + 0] - pos[c * 3 + 0];
        float ry = pos[r * 3 + 1] - pos[c * 3 + 1];
        float rz = pos[r * 3 + 2] - pos[c * 3 + 2];
        relS[tid][0] = rx; relS[tid][1] = ry; relS[tid][2] = rz;
        attrS[tid][0] = rx * rx + ry * ry + rz * rz;
        attrS[tid][1] = eattr[(size_t)ec * 4 + 0];
        attrS[tid][2] = eattr[(size_t)ec * 4 + 1];
        attrS[tid][3] = eattr[(size_t)ec * 4 + 2];
        attrS[tid][4] = eattr[(size_t)ec * 4 + 3];
    }
    __syncthreads();

    // --- fused stage 1, pair-batched for load ILP ---
    #pragma unroll
    for (int b = 0; b < 2; b++) {
        int i0 = tid + b * 512;
        int i1 = i0 + 256;
        int ea = i0 >> 5, ca = (i0 & 31) * 4;
        int eb_ = i1 >> 5, cb_ = (i1 & 31) * 4;
        f4_t p1a = *(const f4_t*)&P1[(size_t)rowG[ea] * H + ca];
        f4_t p2a = *(const f4_t*)&P2[(size_t)colS[ea] * H + ca];
        f4_t p1b = *(const f4_t*)&P1[(size_t)rowG[eb_] * H + cb_];
        f4_t p2b = *(const f4_t*)&P2[(size_t)colS[eb_] * H + cb_];
        #pragma unroll
        for (int half = 0; half < 2; half++) {
            int e = half ? eb_ : ea;
            int ch4 = half ? cb_ : ca;
            f4_t p1 = half ? p1b : p1a;
            f4_t p2 = half ? p2b : p2a;
            f4_t bb = *(const f4_t*)&eb1[ch4];
            float t[4];
            #pragma unroll
            for (int j = 0; j < 4; j++) t[j] = p1[j] + p2[j] + bb[j];
            #pragma unroll
            for (int k = 0; k < 5; k++) {
                f4_t w = *(const f4_t*)&W1c[k * H + ch4];
                float ex = attrS[e][k];
                #pragma unroll
                for (int j = 0; j < 4; j++) t[j] = fmaf(ex, w[j], t[j]);
            }
            bf4_t hi, lo;
            #pragma unroll
            for (int j = 0; j < 4; j++) {
                float v = silu_f(t[j]);
                hi[j] = f2b(v);
                lo[j] = f2b(v - b2f(hi[j]));
            }
            *(bf4_t*)&fH[e * FS2 + ch4] = hi;
            *(bf4_t*)&fL[e * FS2 + ch4] = lo;
        }
    }
    __syncthreads();

    int lane = tid & 63;
    int wv = tid >> 6;            // 4 waves
    int ln = lane & 15, quad = lane >> 4;
    int nt0 = wv * 2;             // each wave: 2 n-tiles

    f4_t acc[2][2];
    float t2s[2][2][4];

    // ===== stage 2: t2 = silu(t1 @ W2 + b2), K=128 =====
    mm_hl2(fH, fL, FS2, W2h, W2l, 4, nt0, lane, ln, quad, acc);
    #pragma unroll
    for (int ni = 0; ni < 2; ni++) {
        int n = (nt0 + ni) * 16 + ln;
        float bb = eb2[n];
        #pragma unroll
        for (int mi = 0; mi < 2; mi++)
            #pragma unroll
            for (int r = 0; r < 4; r++)
                t2s[mi][ni][r] = silu_f(acc[mi][ni][r] + bb);
    }
    __syncthreads();   // all stage-2 reads of t1 done
    #pragma unroll
    for (int ni = 0; ni < 2; ni++) {
        int n = (nt0 + ni) * 16 + ln;
        #pragma unroll
        for (int mi = 0; mi < 2; mi++) {
            #pragma unroll
            for (int r = 0; r < 4; r++) {
                int m = mi * 16 + quad * 4 + r;
                float v = t2s[mi][ni][r];
                short hi = f2b(v);
                fH[m * FS2 + n] = hi;
                fL[m * FS2 + n] = f2b(v - b2f(hi));
            }
        }
    }
    __syncthreads();

    // ===== stage 3: w = silu(t2 @ Wc1 + cb1) @ cw2, K=128 =====
    mm_hl2(fH, fL, FS2, W3h, W3l, 4, nt0, lane, ln, quad, acc);
    {
        #pragma unroll
        for (int mi = 0; mi < 2; mi++) {
            #pragma unroll
            for (int r = 0; r < 4; r++) {
                float v = 0.f;
                #pragma unroll
                for (int ni = 0; ni < 2; ni++) {
                    int n = (nt0 + ni) * 16 + ln;
                    v += silu_f(acc[mi][ni][r] + cb1[n]) * cw2[n];
                }
                v += __shfl_xor(v, 1, 64);
                v += __shfl_xor(v, 2, 64);
                v += __shfl_xor(v, 4, 64);
                v += __shfl_xor(v, 8, 64);
                if (ln == 0) wpart[mi * 16 + quad * 4 + r][wv] = v;
            }
        }
    }
    __syncthreads();   // stage-3 LDS reads done -> safe to overlay t2f

    // --- stage t2 fp32 into LDS (overlay on fHL) ---
    float* t2f = (float*)fHL;   // 32 x T2S fp32 = 16896 B <= 17408 B
    #pragma unroll
    for (int ni = 0; ni < 2; ni++) {
        int n = (nt0 + ni) * 16 + ln;
        #pragma unroll
        for (int mi = 0; mi < 2; mi++)
            #pragma unroll
            for (int r = 0; r < 4; r++)
                t2f[(mi * 16 + quad * 4 + r) * T2S + n] = t2s[mi][ni][r];
    }
    __syncthreads();

    // --- segmented reduction over sorted rows (256 threads: 128 ch x 2 segs) ---
    {
        int ch = tid & 127, seg = tid >> 7;
        int ebeg = seg * 16, eend = ebeg + 16;
        float a2 = 0.f; int cur = -1;
        for (int e2 = ebeg; e2 < eend; e2++) {
            int r2 = rowS[e2];
            float v2 = t2f[e2 * T2S + ch];
            if (r2 != cur) {
                if (cur >= 0) atomicAdd(&magg[(size_t)cur * H + ch], a2);
                cur = r2; a2 = v2;
            } else a2 += v2;
        }
        if (cur >= 0) atomicAdd(&magg[(size_t)cur * H + ch], a2);
    }
    if (tid < 6) {
        int ax = tid % 3, seg = tid / 3;
        int ebeg = seg * 16, eend = ebeg + 16;
        float a2 = 0.f; int cur = -1;
        for (int e2 = ebeg; e2 < eend; e2++) {
            int r2 = rowS[e2];
            float w2 = (wpart[e2][0] + wpart[e2][1] + wpart[e2][2] + wpart[e2][3]) * relS[e2][ax];
            if (r2 != cur) {
                if (cur >= 0) atomicAdd(&pagg[(size_t)cur * 3 + ax], a2);
                cur = r2; a2 = w2;
            } else a2 += w2;
        }
        if (cur >= 0) atomicAdd(&pagg[(size_t)cur * 3 + ax], a2);
    }
}

// ---------------- MFMA node kernel + fused next-layer P1/P2 ----------------
__global__ __launch_bounds__(512, 4) void node_mfma_kernel(
    float* __restrict__ h, const float* __restrict__ magg,
    const float* __restrict__ pagg, const float* __restrict__ deg,
    float* __restrict__ pos,
    const short* __restrict__ N1h, const short* __restrict__ N1l,
    const short* __restrict__ N2h, const short* __restrict__ N2l,
    const float* __restrict__ nb1, const float* __restrict__ nb2,
    const short* __restrict__ Ah, const short* __restrict__ Al,
    const short* __restrict__ Bh, const short* __restrict__ Bl,
    float* __restrict__ P1, float* __restrict__ P2, int doP)
{
    __shared__ __align__(16) short fH[NBN * CST];   // 33792 B
    __shared__ __align__(16) short fL[NBN * CST];   // 33792 B

    int tid = threadIdx.x;
    int n0 = blockIdx.x * NBN;

    if (tid < NBN * 3) {
        int n = tid / 3, ax = tid - n * 3;
        int node = n0 + n;
        if (node < N_NODES) {
            float d = fmaxf(deg[node], 1.0f);
            pos[node * 3 + ax] += pagg[node * 3 + ax] / d;
        }
    }

    for (int i = tid; i < 2 * NBN * (H / 4); i += 512) {
        int rrow = i >> 5, chunk = i & 31;
        int nidx = rrow & (NBN - 1);
        int node = n0 + nidx;
        if (node >= N_NODES) node = N_NODES - 1;
        const float* src = (rrow < NBN) ? h : magg;
        f4_t v = *(const f4_t*)&src[(size_t)node * H + chunk * 4];
        bf4_t hi, lo;
        #pragma unroll
        for (int j = 0; j < 4; j++) {
            hi[j] = f2b(v[j]);
            lo[j] = f2b(v[j] - b2f(hi[j]));
        }
        int dcol = ((rrow < NBN) ? 0 : H) + chunk * 4;
        *(bf4_t*)&fH[nidx * CST + dcol] = hi;
        *(bf4_t*)&fL[nidx * CST + dcol] = lo;
    }
    __syncthreads();

    int lane = tid & 63;
    int nt = tid >> 6;
    int ln = lane & 15, quad = lane >> 4;
    int n = nt * 16 + ln;

    f4_t acc[4];
    float u1s[4][4];

    // stage A: u1 = silu(cat @ N1 + nb1), K=256
    mm_hl4(fH, fL, CST, N1h, N1l, 8, nt, lane, ln, quad, acc);
    {
        float bb = nb1[n];
        #pragma unroll
        for (int mi = 0; mi < 4; mi++)
            #pragma unroll
            for (int r = 0; r < 4; r++)
                u1s[mi][r] = silu_f(acc[mi][r] + bb);
    }
    __syncthreads();
    #pragma unroll
    for (int mi = 0; mi < 4; mi++) {
        #pragma unroll
        for (int r = 0; r < 4; r++) {
            int m = mi * 16 + quad * 4 + r;
            float v = u1s[mi][r];
            short hi = f2b(v);
            fH[m * CST + n] = hi;
            fL[m * CST + n] = f2b(v - b2f(hi));
        }
    }
    __syncthreads();

    // stage B: h_new = h + u1 @ N2 + nb2; write h, stage h_new hi/lo for P GEMMs
    mm_hl4(fH, fL, CST, N2h, N2l, 4, nt, lane, ln, quad, acc);
    __syncthreads();   // all stage-B LDS reads of u1 done before overwrite
    {
        float bb = nb2[n];
        #pragma unroll
        for (int mi = 0; mi < 4; mi++) {
            #pragma unroll
            for (int r = 0; r < 4; r++) {
                int m = mi * 16 + quad * 4 + r;
                int node = n0 + m;
                int nc = (node < N_NODES) ? node : (N_NODES - 1);
                float hn = h[(size_t)nc * H + n] + acc[mi][r] + bb;
                if (node < N_NODES) h[(size_t)node * H + n] = hn;
                short hi = f2b(hn);
                fH[m * CST + n] = hi;
                fL[m * CST + n] = f2b(hn - b2f(hi));
            }
        }
    }
    if (!doP) return;
    __syncthreads();

    // fused P GEMMs for next layer: P1 = h_new@W1a, P2 = h_new@W1b (K=128)
    f4_t accA[4], accB[4];
    #pragma unroll
    for (int mi = 0; mi < 4; mi++) { accA[mi] = (f4_t)(0.0f); accB[mi] = (f4_t)(0.0f); }
    for (int kb = 0; kb < 4; kb++) {
        int k0 = kb * 32 + quad * 8;
        int off = ((kb * 8 + nt) * 64 + lane) * 8;
        bf8_t bhA = *(const bf8_t*)&Ah[off];
        bf8_t blA = *(const bf8_t*)&Al[off];
        bf8_t bhB = *(const bf8_t*)&Bh[off];
        bf8_t blB = *(const bf8_t*)&Bl[off];
        #pragma unroll
        for (int mi = 0; mi < 4; mi++) {
            bf8_t ah = *(const bf8_t*)&fH[(mi * 16 + ln) * CST + k0];
            bf8_t al = *(const bf8_t*)&fL[(mi * 16 + ln) * CST + k0];
            accA[mi] = __builtin_amdgcn_mfma_f32_16x16x32_bf16(ah, bhA, accA[mi], 0, 0, 0);
            accA[mi] = __builtin_amdgcn_mfma_f32_16x16x32_bf16(al, bhA, accA[mi], 0, 0, 0);
            accA[mi] = __builtin_amdgcn_mfma_f32_16x16x32_bf16(ah, blA, accA[mi], 0, 0, 0);
            accB[mi] = __builtin_amdgcn_mfma_f32_16x16x32_bf16(ah, bhB, accB[mi], 0, 0, 0);
            accB[mi] = __builtin_amdgcn_mfma_f32_16x16x32_bf16(al, bhB, accB[mi], 0, 0, 0);
            accB[mi] = __builtin_amdgcn_mfma_f32_16x16x32_bf16(ah, blB, accB[mi], 0, 0, 0);
        }
    }
    #pragma unroll
    for (int mi = 0; mi < 4; mi++) {
        #pragma unroll
        for (int r = 0; r < 4; r++) {
            int node = n0 + mi * 16 + quad * 4 + r;
            if (node < N_NODES) {
                P1[(size_t)node * H + n] = accA[mi][r];
                P2[(size_t)node * H + n] = accB[mi][r];
            }
        }
    }
}

// ---------------- pooling + head ----------------
__global__ __launch_bounds__(128) void head_kernel(
    const float* __restrict__ h,
    const float* __restrict__ h1w, const float* __restrict__ h1b,
    const float* __restrict__ h2w, const float* __restrict__ h2b,
    const float* __restrict__ h3w, const float* __restrict__ h3b,
    float* __restrict__ out)
{
    __shared__ float gfeat[256];
    __shared__ float z1[128];
    __shared__ float z2[64];
    int tid = threadIdx.x;
    int g = blockIdx.x;
    size_t base = (size_t)g * NPG * H;
    float s = 0.f;
    for (int i = 0; i < NPG; i++) s += h[base + (size_t)i * H + tid];
    gfeat[tid] = s;
    gfeat[H + tid] = s / (float)NPG;
    __syncthreads();
    float a = h1b[tid];
    for (int k = 0; k < 256; k++) a = fmaf(gfeat[k], h1w[k * H + tid], a);
    z1[tid] = fmaxf(a, 0.0f);
    __syncthreads();
    if (tid < 64) {
        float a2 = h2b[tid];
        for (int k = 0; k < 128; k++) a2 = fmaf(z1[k], h2w[k * 64 + tid], a2);
        z2[tid] = fmaxf(a2, 0.0f);
    }
    __syncthreads();
    if (tid < 64) {
        float v = z2[tid] * h3w[tid];
        #pragma unroll
        for (int off = 32; off > 0; off >>= 1) v += __shfl_xor(v, off, 64);
        if (tid == 0) out[g] = v + h3b[0];
    }
}

extern "C" void kernel_launch(void* const* d_in, const int* in_sizes, int n_in,
                              void* d_out, int out_size, void* d_ws, size_t ws_size,
                              hipStream_t stream) {
    const float* x      = (const float*)d_in[0];
    const float* pos_in = (const float*)d_in[1];
    const int*   ei     = (const int*)d_in[2];
    const float* eattr  = (const float*)d_in[3];
    const float* Wp    = (const float*)d_in[6];
    const float* bp    = (const float*)d_in[7];
    const float* Wl    = (const float*)d_in[8];
    const float* bl    = (const float*)d_in[9];
    const float* gamma = (const float*)d_in[10];
    const float* beta  = (const float*)d_in[11];
    const float* ew1   = (const float*)d_in[12];
    const float* eb1   = (const float*)d_in[13];
    const float* ew2   = (const float*)d_in[14];
    const float* eb2   = (const float*)d_in[15];
    const float* cw1   = (const float*)d_in[16];
    const float* cb1   = (const float*)d_in[17];
    const float* cw2   = (const float*)d_in[18];
    const float* nw1   = (const float*)d_in[19];
    const float* nb1   = (const float*)d_in[20];
    const float* nw2   = (const float*)d_in[21];
    const float* nb2   = (const float*)d_in[22];
    const float* h1w   = (const float*)d_in[23];
    const float* h1b   = (const float*)d_in[24];
    const float* h2w   = (const float*)d_in[25];
    const float* h2b   = (const float*)d_in[26];
    const float* h3w   = (const float*)d_in[27];
    const float* h3b   = (const float*)d_in[28];
    float* out = (float*)d_out;

    float* ws   = (float*)d_ws;
    float* hbuf = ws;                                  // N*H f32
    float* magg = hbuf + (size_t)N_NODES * H;          // N*H f32
    float* P1   = magg + (size_t)N_NODES * H;          // N*H f32
    float* P2   = P1 + (size_t)N_NODES * H;            // N*H f32
    float* posb = P2 + (size_t)N_NODES * H;            // N*3
    float* pagg = posb + (size_t)N_NODES * 3;          // N*3
    float* deg  = pagg + (size_t)N_NODES * 3;          // N
    float* bnS  = deg + N_NODES;                       // 256
    float* bnP  = bnS + 256;                           // 256
    int* cnt    = (int*)(bnP + 256);                   // N
    int* basep  = cnt + N_NODES;                       // N
    int* cursor = basep + N_NODES;                     // N
    int* perm   = cursor + N_NODES;                    // E
    int* rowsS  = perm + N_EDGES;                      // E
    int szK4 = 4 * 4 * 4096;                           // K=128 weights per plane
    int szK8 = 4 * 8 * 4096;                           // K=256 weights per plane
    short* W1aH = (short*)(rowsS + N_EDGES);
    short* W1aL = W1aH + szK4;
    short* W1bH = W1aL + szK4;
    short* W1bL = W1bH + szK4;
    short* W2h  = W1bL + szK4;
    short* W2l  = W2h + szK4;
    short* W3h  = W2l + szK4;
    short* W3l  = W3h + szK4;
    short* N1h  = W3l + szK4;
    short* N1l  = N1h + szK8;
    short* N2h  = N1l + szK8;
    short* N2l  = N2h + szK4;

    hipMemcpyAsync(posb, pos_in, (size_t)N_NODES * 3 * sizeof(float),
                   hipMemcpyDeviceToDevice, stream);
    hipMemsetAsync(cnt, 0, N_NODES * sizeof(int), stream);
    hipMemsetAsync(cursor, 0, N_NODES * sizeof(int), stream);
    hipMemsetAsync(bnS, 0, 256 * sizeof(float), stream);

    hist_kernel<<<(N_EDGES + 255) / 256, 256, 0, stream>>>(ei, cnt);
    scan_kernel<<<1, 1024, 0, stream>>>(cnt, basep);
    scatter_kernel<<<(N_EDGES + 255) / 256, 256, 0, stream>>>(ei, basep, cursor, perm, rowsS);
    deg_from_cnt_kernel<<<(N_NODES + 255) / 256, 256, 0, stream>>>(cnt, deg);

    wprep_frag_kernel<<<(szK4 + 255) / 256, 256, 0, stream>>>(ew1, W1aH, W1aL, DIN, 4, 0);
    wprep_frag_kernel<<<(szK4 + 255) / 256, 256, 0, stream>>>(ew1, W1bH, W1bL, DIN, 4, H);
    wprep_frag_kernel<<<(szK4 + 255) / 256, 256, 0, stream>>>(ew2, W2h, W2l, H, 4, 0);
    wprep_frag_kernel<<<(szK4 + 255) / 256, 256, 0, stream>>>(cw1, W3h, W3l, H, 4, 0);
    wprep_frag_kernel<<<(szK8 + 255) / 256, 256, 0, stream>>>(nw1, N1h, N1l, 256, 8, 0);
    wprep_frag_kernel<<<(szK4 + 255) / 256, 256, 0, stream>>>(nw2, N2h, N2l, H, 4, 0);

    proj_kernel<<<N_NODES / NB, 128, 0, stream>>>(x, Wp, bp, Wl, bl, hbuf);
    bn_stats_kernel<<<N_NODES / NPG, 128, 0, stream>>>(hbuf, bnS);
    bn_final_kernel<<<1, 128, 0, stream>>>(bnS, gamma, beta, bnP);
    bn_apply_kernel<<<(N_NODES * H / 4) / 256, 256, 0, stream>>>(hbuf, bnP);

    int eblocks = (N_EDGES + EB2 - 1) / EB2;
    int nblocks = (N_NODES + NBN - 1) / NBN;

    // initial P1/P2 for layer 0
    p12_kernel<<<nblocks, 512, 0, stream>>>(hbuf, W1aH, W1aL, W1bH, W1bL, P1, P2);

    for (int l = 0; l < 4; l++) {
        hipMemsetAsync(magg, 0, (size_t)N_NODES * H * sizeof(float), stream);
        hipMemsetAsync(pagg, 0, (size_t)N_NODES * 3 * sizeof(float), stream);
        edge_mfma_kernel<<<eblocks, 256, 0, stream>>>(
            P1, P2, posb, ei, eattr, perm, rowsS,
            ew1 + (size_t)l * DIN * H + (size_t)2 * H * H,   // W1c rows 256..260
            eb1 + (size_t)l * H,
            W2h + (size_t)l * 4 * 4096, W2l + (size_t)l * 4 * 4096,
            W3h + (size_t)l * 4 * 4096, W3l + (size_t)l * 4 * 4096,
            eb2 + (size_t)l * H,
            cb1 + (size_t)l * H, cw2 + (size_t)l * H,
            magg, pagg);
        int lp = l + 1;
        node_mfma_kernel<<<nblocks, 512, 0, stream>>>(
            hbuf, magg, pagg, deg, posb,
            N1h + (size_t)l * 8 * 4096, N1l + (size_t)l * 8 * 4096,
            N2h + (size_t)l * 4 * 4096, N2l + (size_t)l * 4 * 4096,
            nb1 + (size_t)l * H, nb2 + (size_t)l * H,
            W1aH + (size_t)(lp & 3) * 4 * 4096, W1aL + (size_t)(lp & 3) * 4 * 4096,
            W1bH + (size_t)(lp & 3) * 4 * 4096, W1bL + (size_t)(lp & 3) * 4 * 4096,
            P1, P2, (l < 3) ? 1 : 0);
    }

    head_kernel<<<G_GRAPHS, 128, 0, stream>>>(hbuf, h1w, h1b, h2w, h2b, h3w, h3b, out);
}

// Round 10
// 1396.451 us; speedup vs baseline: 6.8728x; 1.0970x over previous
//
#include <hip/hip_runtime.h>
#include <math.h>

#define N_NODES 50000
#define N_EDGES 500000
#define G_GRAPHS 100
#define NPG 500
#define NPROT 400
#define H 128
#define PN 35
#define LN 11
#define DIN 261      // 2H + 1 + 4
#define EB2 32       // edges per block (MFMA edge kernel)
#define FS2 136      // bf16 plane row stride (272B = 68 dw, %32=4 -> 2-way, free)
#define T2S 132      // t2 fp32 staging stride (dw, %32=4 -> 2-way, free)
#define NBN 64       // nodes per block (MFMA node kernel)
#define CST 264      // node cat plane stride in bf16 (2-way, free)
#define NB 16        // nodes per workgroup (proj kernel)
#define EPSV 1e-5f

typedef __attribute__((ext_vector_type(8))) short bf8_t;   // 8 bf16 (4 VGPRs)
typedef __attribute__((ext_vector_type(4))) short bf4_t;
typedef __attribute__((ext_vector_type(4))) float f4_t;

__device__ __forceinline__ float silu_f(float x) {
    return x / (1.0f + __expf(-x));
}
__device__ __forceinline__ short f2b(float f) {
    __bf16 b = (__bf16)f;
    return __builtin_bit_cast(short, b);
}
__device__ __forceinline__ float b2f(short s) {
    unsigned u = ((unsigned)(unsigned short)s) << 16;
    return __builtin_bit_cast(float, u);
}

// ---- weight prep: fp32 [4][Ksrc][H] (+row offset) -> fragment-ordered bf16 hi/lo ----
__global__ void wprep_frag_kernel(const float* __restrict__ src, short* __restrict__ dstH,
                                  short* __restrict__ dstL, int Ksrc, int nkb, int koff) {
    int idx = blockIdx.x * 256 + threadIdx.x;
    int per_l = nkb * 8 * 64 * 8;
    int total = 4 * per_l;
    if (idx >= total) return;
    int l = idx / per_l;
    int rem = idx - l * per_l;
    int j = rem & 7;
    int lane = (rem >> 3) & 63;
    int nt = (rem >> 9) & 7;
    int kb = rem >> 12;
    int ln = lane & 15, quad = lane >> 4;
    int n = nt * 16 + ln;
    int k = koff + kb * 32 + quad * 8 + j;
    float v = (k < Ksrc) ? src[((size_t)l * Ksrc + k) * H + n] : 0.0f;
    short hi = f2b(v);
    dstH[idx] = hi;
    dstL[idx] = f2b(v - b2f(hi));
}

// ---------------- edge sort: counting sort by target row ----------------
__global__ void hist_kernel(const int* __restrict__ ei, int* __restrict__ cnt)
{
    int e = blockIdx.x * 256 + threadIdx.x;
    if (e < N_EDGES) atomicAdd(&cnt[ei[e]], 1);
}

__global__ __launch_bounds__(1024) void scan_kernel(const int* __restrict__ cnt, int* __restrict__ base)
{
    __shared__ int buf[1024];
    __shared__ int carry;
    int tid = threadIdx.x;
    if (tid == 0) carry = 0;
    __syncthreads();
    for (int c0 = 0; c0 < N_NODES; c0 += 1024) {
        int i = c0 + tid;
        int v = (i < N_NODES) ? cnt[i] : 0;
        buf[tid] = v;
        __syncthreads();
        for (int off = 1; off < 1024; off <<= 1) {
            int t = (tid >= off) ? buf[tid - off] : 0;
            __syncthreads();
            buf[tid] += t;
            __syncthreads();
        }
        if (i < N_NODES) base[i] = carry + buf[tid] - v;
        __syncthreads();
        if (tid == 1023) carry += buf[1023];
        __syncthreads();
    }
}

__global__ void scatter_kernel(const int* __restrict__ ei, const int* __restrict__ base,
                               int* __restrict__ cursor, int* __restrict__ perm,
                               int* __restrict__ rowsS)
{
    int e = blockIdx.x * 256 + threadIdx.x;
    if (e < N_EDGES) {
        int r = ei[e];
        int p = atomicAdd(&cursor[r], 1);
        int d = base[r] + p;
        perm[d] = e;
        rowsS[d] = r;
    }
}

__global__ void deg_from_cnt_kernel(const int* __restrict__ cnt, float* __restrict__ deg)
{
    int i = blockIdx.x * 256 + threadIdx.x;
    if (i < N_NODES) deg[i] = (float)cnt[i];
}

// ---------------- projection ----------------
__global__ __launch_bounds__(128) void proj_kernel(
    const float* __restrict__ x, const float* __restrict__ Wp, const float* __restrict__ bp,
    const float* __restrict__ Wl, const float* __restrict__ bl, float* __restrict__ h)
{
    __shared__ float xs[NB][36];
    int tid = threadIdx.x;
    int n0 = blockIdx.x * NB;
    for (int idx = tid; idx < NB * PN; idx += 128) {
        int n = idx / PN, k = idx % PN;
        xs[n][k] = x[(size_t)(n0 + n) * PN + k];
    }
    __syncthreads();
    for (int n = 0; n < NB; n++) {
        int node = n0 + n;
        bool isp = (node % NPG) < NPROT;
        float acc;
        if (isp) {
            acc = bp[tid];
            for (int k = 0; k < PN; k++) acc = fmaf(xs[n][k], Wp[k * H + tid], acc);
        } else {
            acc = bl[tid];
            for (int k = 0; k < LN; k++) acc = fmaf(xs[n][k], Wl[k * H + tid], acc);
        }
        h[(size_t)node * H + tid] = acc;
    }
}

// ---------------- batchnorm ----------------
__global__ __launch_bounds__(128) void bn_stats_kernel(const float* __restrict__ h, float* __restrict__ bnS)
{
    int tid = threadIdx.x;
    size_t base = (size_t)blockIdx.x * NPG * H;
    float s1 = 0.f, s2 = 0.f;
    for (int i = 0; i < NPG; i++) {
        float v = h[base + (size_t)i * H + tid];
        s1 += v; s2 += v * v;
    }
    atomicAdd(&bnS[tid], s1);
    atomicAdd(&bnS[H + tid], s2);
}

__global__ void bn_final_kernel(const float* __restrict__ bnS, const float* __restrict__ gamma,
                                const float* __restrict__ beta, float* __restrict__ bnP)
{
    int j = threadIdx.x;
    float mu = bnS[j] / (float)N_NODES;
    float var = bnS[H + j] / (float)N_NODES - mu * mu;
    float inv = rsqrtf(var + EPSV);
    float sc = gamma[j] * inv;
    bnP[j] = sc;
    bnP[H + j] = beta[j] - mu * sc;
}

__global__ __launch_bounds__(256) void bn_apply_kernel(float* __restrict__ h, const float* __restrict__ bnP)
{
    int idx = blockIdx.x * 256 + threadIdx.x;
    float4 v = ((float4*)h)[idx];
    int j4 = (idx & 31) * 4;
    v.x = fmaf(v.x, bnP[j4 + 0], bnP[H + j4 + 0]);
    v.y = fmaf(v.y, bnP[j4 + 1], bnP[H + j4 + 1]);
    v.z = fmaf(v.z, bnP[j4 + 2], bnP[H + j4 + 2]);
    v.w = fmaf(v.w, bnP[j4 + 3], bnP[H + j4 + 3]);
    ((float4*)h)[idx] = v;
}

// ---- hi/lo bf16 MFMA k-loop: 2 m-tiles x 2 n-tiles per wave (3-term, exact) ----
__device__ __forceinline__ void mm_hl2(
    const short* fH, const short* fL, int stride,
    const short* __restrict__ WH, const short* __restrict__ WL,
    int nkb, int nt0, int lane, int ln, int quad, f4_t acc[2][2])
{
    #pragma unroll
    for (int mi = 0; mi < 2; mi++)
        #pragma unroll
        for (int ni = 0; ni < 2; ni++) acc[mi][ni] = (f4_t)(0.0f);
    for (int kb = 0; kb < nkb; kb++) {
        int k0 = kb * 32 + quad * 8;
        bf8_t ah0 = *(const bf8_t*)&fH[(ln) * stride + k0];
        bf8_t al0 = *(const bf8_t*)&fL[(ln) * stride + k0];
        bf8_t ah1 = *(const bf8_t*)&fH[(16 + ln) * stride + k0];
        bf8_t al1 = *(const bf8_t*)&fL[(16 + ln) * stride + k0];
        #pragma unroll
        for (int ni = 0; ni < 2; ni++) {
            int off = ((kb * 8 + nt0 + ni) * 64 + lane) * 8;
            bf8_t bh = *(const bf8_t*)&WH[off];
            bf8_t bl = *(const bf8_t*)&WL[off];
            acc[0][ni] = __builtin_amdgcn_mfma_f32_16x16x32_bf16(ah0, bh, acc[0][ni], 0, 0, 0);
            acc[0][ni] = __builtin_amdgcn_mfma_f32_16x16x32_bf16(al0, bh, acc[0][ni], 0, 0, 0);
            acc[0][ni] = __builtin_amdgcn_mfma_f32_16x16x32_bf16(ah0, bl, acc[0][ni], 0, 0, 0);
            acc[1][ni] = __builtin_amdgcn_mfma_f32_16x16x32_bf16(ah1, bh, acc[1][ni], 0, 0, 0);
            acc[1][ni] = __builtin_amdgcn_mfma_f32_16x16x32_bf16(al1, bh, acc[1][ni], 0, 0, 0);
            acc[1][ni] = __builtin_amdgcn_mfma_f32_16x16x32_bf16(ah1, bl, acc[1][ni], 0, 0, 0);
        }
    }
}

// ---- 2-term variant: bf16 activations (hi only) x exact hi/lo weights ----
__device__ __forceinline__ void mm_h2t(
    const short* fH, int stride,
    const short* __restrict__ WH, const short* __restrict__ WL,
    int nkb, int nt0, int lane, int ln, int quad, f4_t acc[2][2])
{
    #pragma unroll
    for (int mi = 0; mi < 2; mi++)
        #pragma unroll
        for (int ni = 0; ni < 2; ni++) acc[mi][ni] = (f4_t)(0.0f);
    for (int kb = 0; kb < nkb; kb++) {
        int k0 = kb * 32 + quad * 8;
        bf8_t ah0 = *(const bf8_t*)&fH[(ln) * stride + k0];
        bf8_t ah1 = *(const bf8_t*)&fH[(16 + ln) * stride + k0];
        #pragma unroll
        for (int ni = 0; ni < 2; ni++) {
            int off = ((kb * 8 + nt0 + ni) * 64 + lane) * 8;
            bf8_t bh = *(const bf8_t*)&WH[off];
            bf8_t bl = *(const bf8_t*)&WL[off];
            acc[0][ni] = __builtin_amdgcn_mfma_f32_16x16x32_bf16(ah0, bh, acc[0][ni], 0, 0, 0);
            acc[0][ni] = __builtin_amdgcn_mfma_f32_16x16x32_bf16(ah0, bl, acc[0][ni], 0, 0, 0);
            acc[1][ni] = __builtin_amdgcn_mfma_f32_16x16x32_bf16(ah1, bh, acc[1][ni], 0, 0, 0);
            acc[1][ni] = __builtin_amdgcn_mfma_f32_16x16x32_bf16(ah1, bl, acc[1][ni], 0, 0, 0);
        }
    }
}

// ---- hi/lo bf16 MFMA k-loop: 4 m-tiles x 1 n-tile per wave (node kernel, 512 thr) ----
__device__ __forceinline__ void mm_hl4(
    const short* fH, const short* fL, int stride,
    const short* __restrict__ WH, const short* __restrict__ WL,
    int nkb, int nt, int lane, int ln, int quad, f4_t acc[4])
{
    #pragma unroll
    for (int mi = 0; mi < 4; mi++) acc[mi] = (f4_t)(0.0f);
    for (int kb = 0; kb < nkb; kb++) {
        int k0 = kb * 32 + quad * 8;
        int off = ((kb * 8 + nt) * 64 + lane) * 8;
        bf8_t bh = *(const bf8_t*)&WH[off];
        bf8_t bl = *(const bf8_t*)&WL[off];
        #pragma unroll
        for (int mi = 0; mi < 4; mi++) {
            bf8_t ah = *(const bf8_t*)&fH[(mi * 16 + ln) * stride + k0];
            bf8_t al = *(const bf8_t*)&fL[(mi * 16 + ln) * stride + k0];
            acc[mi] = __builtin_amdgcn_mfma_f32_16x16x32_bf16(ah, bh, acc[mi], 0, 0, 0);
            acc[mi] = __builtin_amdgcn_mfma_f32_16x16x32_bf16(al, bh, acc[mi], 0, 0, 0);
            acc[mi] = __builtin_amdgcn_mfma_f32_16x16x32_bf16(ah, bl, acc[mi], 0, 0, 0);
        }
    }
}

// ---------------- initial node pre-projection (layer 0): P1 = h@W1a, P2 = h@W1b ----------------
__global__ __launch_bounds__(512, 4) void p12_kernel(
    const float* __restrict__ h,
    const short* __restrict__ Ah, const short* __restrict__ Al,
    const short* __restrict__ Bh, const short* __restrict__ Bl,
    float* __restrict__ P1, float* __restrict__ P2)
{
    __shared__ __align__(16) short fH[NBN * FS2];
    __shared__ __align__(16) short fL[NBN * FS2];
    int tid = threadIdx.x;
    int n0 = blockIdx.x * NBN;

    for (int i = tid; i < NBN * (H / 4); i += 512) {
        int nidx = i >> 5, chunk = i & 31;
        int node = n0 + nidx;
        if (node >= N_NODES) node = N_NODES - 1;
        f4_t v = *(const f4_t*)&h[(size_t)node * H + chunk * 4];
        bf4_t hi, lo;
        #pragma unroll
        for (int j = 0; j < 4; j++) {
            hi[j] = f2b(v[j]);
            lo[j] = f2b(v[j] - b2f(hi[j]));
        }
        *(bf4_t*)&fH[nidx * FS2 + chunk * 4] = hi;
        *(bf4_t*)&fL[nidx * FS2 + chunk * 4] = lo;
    }
    __syncthreads();

    int lane = tid & 63;
    int nt = tid >> 6;
    int ln = lane & 15, quad = lane >> 4;

    f4_t accA[4], accB[4];
    #pragma unroll
    for (int mi = 0; mi < 4; mi++) { accA[mi] = (f4_t)(0.0f); accB[mi] = (f4_t)(0.0f); }
    for (int kb = 0; kb < 4; kb++) {
        int k0 = kb * 32 + quad * 8;
        int off = ((kb * 8 + nt) * 64 + lane) * 8;
        bf8_t bhA = *(const bf8_t*)&Ah[off];
        bf8_t blA = *(const bf8_t*)&Al[off];
        bf8_t bhB = *(const bf8_t*)&Bh[off];
        bf8_t blB = *(const bf8_t*)&Bl[off];
        #pragma unroll
        for (int mi = 0; mi < 4; mi++) {
            bf8_t ah = *(const bf8_t*)&fH[(mi * 16 + ln) * FS2 + k0];
            bf8_t al = *(const bf8_t*)&fL[(mi * 16 + ln) * FS2 + k0];
            accA[mi] = __builtin_amdgcn_mfma_f32_16x16x32_bf16(ah, bhA, accA[mi], 0, 0, 0);
            accA[mi] = __builtin_amdgcn_mfma_f32_16x16x32_bf16(al, bhA, accA[mi], 0, 0, 0);
            accA[mi] = __builtin_amdgcn_mfma_f32_16x16x32_bf16(ah, blA, accA[mi], 0, 0, 0);
            accB[mi] = __builtin_amdgcn_mfma_f32_16x16x32_bf16(ah, bhB, accB[mi], 0, 0, 0);
            accB[mi] = __builtin_amdgcn_mfma_f32_16x16x32_bf16(al, bhB, accB[mi], 0, 0, 0);
            accB[mi] = __builtin_amdgcn_mfma_f32_16x16x32_bf16(ah, blB, accB[mi], 0, 0, 0);
        }
    }
    int n = nt * 16 + ln;
    #pragma unroll
    for (int mi = 0; mi < 4; mi++) {
        #pragma unroll
        for (int r = 0; r < 4; r++) {
            int node = n0 + mi * 16 + quad * 4 + r;
            if (node < N_NODES) {
                P1[(size_t)node * H + n] = accA[mi][r];
                P2[(size_t)node * H + n] = accB[mi][r];
            }
        }
    }
}

// ---------------- MFMA edge kernel (EB=32, 256 thr, 8 blocks/CU, XCD-swizzled) ----------------
__global__ __launch_bounds__(256, 8) void edge_mfma_kernel(
    const float* __restrict__ P1, const float* __restrict__ P2,
    const float* __restrict__ pos,
    const int* __restrict__ ei, const float* __restrict__ eattr,
    const int* __restrict__ perm, const int* __restrict__ rowsS,
    const float* __restrict__ W1c, const float* __restrict__ eb1,
    const short* __restrict__ W2h, const short* __restrict__ W2l,
    const short* __restrict__ W3h, const short* __restrict__ W3l,
    const float* __restrict__ eb2,
    const float* __restrict__ cb1, const float* __restrict__ cw2,
    float* __restrict__ magg, float* __restrict__ pagg)
{
    __shared__ __align__(16) short fHL[2 * EB2 * FS2];   // 17408 B; t2f fp32 overlays later
    __shared__ float relS[EB2][3];
    __shared__ float attrS[EB2][5];
    __shared__ float wpart[EB2][4];
    __shared__ int rowS[EB2];
    __shared__ int rowG[EB2];
    __shared__ int colS[EB2];

    short* fH = fHL;
    short* fL = fHL + EB2 * FS2;
    int tid = threadIdx.x;
    // XCD swizzle: grid = 8*chunk; blocks with equal (bx&7) land on one XCD (round-robin
    // dispatch heuristic) and get a CONTIGUOUS edge range -> P1 slice + magg rows L2-local.
    int chunk = gridDim.x >> 3;
    int bx = blockIdx.x;
    int bid = (bx & 7) * chunk + (bx >> 3);
    int e0 = bid * EB2;

    // --- edge meta ---
    if (tid < EB2) {
        int e = e0 + tid;
        int eidx = (e < N_EDGES) ? e : (N_EDGES - 1);
        int ec = perm[eidx];
        int r = rowsS[eidx];
        int c = ei[N_EDGES + ec];
        rowG[tid] = r;
        rowS[tid] = (e < N_EDGES) ? r : -1;
        colS[tid] = c;
        float rx = pos[r * 3 + 0] - pos[c * 3 + 0];
        float ry = pos[r * 3 + 1] - pos[c * 3 + 1];
        float rz = pos[r * 3 + 2] - pos[c * 3 + 2];
        relS[tid][0] = rx; relS[tid][1] = ry; relS[tid][2] = rz;
        attrS[tid][0] = rx * rx + ry * ry + rz * rz;
        attrS[tid][1] = eattr[(size_t)ec * 4 + 0];
        attrS[tid][2] = eattr[(size_t)ec * 4 + 1];
        attrS[tid][3] = eattr[(size_t)ec * 4 + 2];
        attrS[tid][4] = eattr[(size_t)ec * 4 + 3];
    }
    __syncthreads();

    // --- fused stage 1, pair-batched for load ILP; ch4 is invariant per thread ---
    {
        int ch4 = (tid & 31) * 4;
        f4_t bb = *(const f4_t*)&eb1[ch4];
        f4_t w0 = *(const f4_t*)&W1c[0 * H + ch4];
        f4_t w1 = *(const f4_t*)&W1c[1 * H + ch4];
        f4_t w2 = *(const f4_t*)&W1c[2 * H + ch4];
        f4_t w3 = *(const f4_t*)&W1c[3 * H + ch4];
        f4_t w4 = *(const f4_t*)&W1c[4 * H + ch4];
        #pragma unroll
        for (int b = 0; b < 2; b++) {
            int i0 = tid + b * 512;
            int i1 = i0 + 256;
            int ea = i0 >> 5;
            int eb_ = i1 >> 5;
            f4_t p1a = *(const f4_t*)&P1[(size_t)rowG[ea] * H + ch4];
            f4_t p2a = *(const f4_t*)&P2[(size_t)colS[ea] * H + ch4];
            f4_t p1b = *(const f4_t*)&P1[(size_t)rowG[eb_] * H + ch4];
            f4_t p2b = *(const f4_t*)&P2[(size_t)colS[eb_] * H + ch4];
            #pragma unroll
            for (int half = 0; half < 2; half++) {
                int e = half ? eb_ : ea;
                f4_t p1 = half ? p1b : p1a;
                f4_t p2 = half ? p2b : p2a;
                float a0 = attrS[e][0], a1 = attrS[e][1], a2 = attrS[e][2];
                float a3 = attrS[e][3], a4 = attrS[e][4];
                bf4_t hi, lo;
                #pragma unroll
                for (int j = 0; j < 4; j++) {
                    float t = p1[j] + p2[j] + bb[j];
                    t = fmaf(a0, w0[j], t);
                    t = fmaf(a1, w1[j], t);
                    t = fmaf(a2, w2[j], t);
                    t = fmaf(a3, w3[j], t);
                    t = fmaf(a4, w4[j], t);
                    float v = silu_f(t);
                    hi[j] = f2b(v);
                    lo[j] = f2b(v - b2f(hi[j]));
                }
                *(bf4_t*)&fH[e * FS2 + ch4] = hi;
                *(bf4_t*)&fL[e * FS2 + ch4] = lo;
            }
        }
    }
    __syncthreads();

    int lane = tid & 63;
    int wv = tid >> 6;            // 4 waves
    int ln = lane & 15, quad = lane >> 4;
    int nt0 = wv * 2;             // each wave: 2 n-tiles

    f4_t acc[2][2];
    float t2s[2][2][4];

    // ===== stage 2: t2 = silu(t1 @ W2 + b2), K=128 (exact 3-term) =====
    mm_hl2(fH, fL, FS2, W2h, W2l, 4, nt0, lane, ln, quad, acc);
    #pragma unroll
    for (int ni = 0; ni < 2; ni++) {
        int n = (nt0 + ni) * 16 + ln;
        float bb = eb2[n];
        #pragma unroll
        for (int mi = 0; mi < 2; mi++)
            #pragma unroll
            for (int r = 0; r < 4; r++)
                t2s[mi][ni][r] = silu_f(acc[mi][ni][r] + bb);
    }
    __syncthreads();   // all stage-2 reads of t1 done
    // t2 stored hi-only: stage 3 (pos path) tolerates bf16 activations
    #pragma unroll
    for (int ni = 0; ni < 2; ni++) {
        int n = (nt0 + ni) * 16 + ln;
        #pragma unroll
        for (int mi = 0; mi < 2; mi++) {
            #pragma unroll
            for (int r = 0; r < 4; r++) {
                int m = mi * 16 + quad * 4 + r;
                fH[m * FS2 + n] = f2b(t2s[mi][ni][r]);
            }
        }
    }
    __syncthreads();

    // ===== stage 3: w = silu(t2 @ Wc1 + cb1) @ cw2, K=128 (2-term) =====
    mm_h2t(fH, FS2, W3h, W3l, 4, nt0, lane, ln, quad, acc);
    {
        #pragma unroll
        for (int mi = 0; mi < 2; mi++) {
            #pragma unroll
            for (int r = 0; r < 4; r++) {
                float v = 0.f;
                #pragma unroll
                for (int ni = 0; ni < 2; ni++) {
                    int n = (nt0 + ni) * 16 + ln;
                    v += silu_f(acc[mi][ni][r] + cb1[n]) * cw2[n];
                }
                v += __shfl_xor(v, 1, 64);
                v += __shfl_xor(v, 2, 64);
                v += __shfl_xor(v, 4, 64);
                v += __shfl_xor(v, 8, 64);
                if (ln == 0) wpart[mi * 16 + quad * 4 + r][wv] = v;
            }
        }
    }
    __syncthreads();   // stage-3 LDS reads done -> safe to overlay t2f

    // --- stage t2 fp32 into LDS (overlay on fHL) ---
    float* t2f = (float*)fHL;   // 32 x T2S fp32 = 16896 B <= 17408 B
    #pragma unroll
    for (int ni = 0; ni < 2; ni++) {
        int n = (nt0 + ni) * 16 + ln;
        #pragma unroll
        for (int mi = 0; mi < 2; mi++)
            #pragma unroll
            for (int r = 0; r < 4; r++)
                t2f[(mi * 16 + quad * 4 + r) * T2S + n] = t2s[mi][ni][r];
    }
    __syncthreads();

    // --- segmented reduction over sorted rows (256 threads: 128 ch x 2 segs) ---
    {
        int ch = tid & 127, seg = tid >> 7;
        int ebeg = seg * 16, eend = ebeg + 16;
        float a2 = 0.f; int cur = -1;
        for (int e2 = ebeg; e2 < eend; e2++) {
            int r2 = rowS[e2];
            float v2 = t2f[e2 * T2S + ch];
            if (r2 != cur) {
                if (cur >= 0) atomicAdd(&magg[(size_t)cur * H + ch], a2);
                cur = r2; a2 = v2;
            } else a2 += v2;
        }
        if (cur >= 0) atomicAdd(&magg[(size_t)cur * H + ch], a2);
    }
    if (tid < 6) {
        int ax = tid % 3, seg = tid / 3;
        int ebeg = seg * 16, eend = ebeg + 16;
        float a2 = 0.f; int cur = -1;
        for (int e2 = ebeg; e2 < eend; e2++) {
            int r2 = rowS[e2];
            float w2 = (wpart[e2][0] + wpart[e2][1] + wpart[e2][2] + wpart[e2][3]) * relS[e2][ax];
            if (r2 != cur) {
                if (cur >= 0) atomicAdd(&pagg[(size_t)cur * 3 + ax], a2);
                cur = r2; a2 = w2;
            } else a2 += w2;
        }
        if (cur >= 0) atomicAdd(&pagg[(size_t)cur * 3 + ax], a2);
    }
}

// ---------------- MFMA node kernel + fused next-layer P1/P2 ----------------
__global__ __launch_bounds__(512, 4) void node_mfma_kernel(
    float* __restrict__ h, const float* __restrict__ magg,
    const float* __restrict__ pagg, const float* __restrict__ deg,
    float* __restrict__ pos,
    const short* __restrict__ N1h, const short* __restrict__ N1l,
    const short* __restrict__ N2h, const short* __restrict__ N2l,
    const float* __restrict__ nb1, const float* __restrict__ nb2,
    const short* __restrict__ Ah, const short* __restrict__ Al,
    const short* __restrict__ Bh, const short* __restrict__ Bl,
    float* __restrict__ P1, float* __restrict__ P2, int doP)
{
    __shared__ __align__(16) short fH[NBN * CST];   // 33792 B
    __shared__ __align__(16) short fL[NBN * CST];   // 33792 B

    int tid = threadIdx.x;
    int n0 = blockIdx.x * NBN;

    if (tid < NBN * 3) {
        int n = tid / 3, ax = tid - n * 3;
        int node = n0 + n;
        if (node < N_NODES) {
            float d = fmaxf(deg[node], 1.0f);
            pos[node * 3 + ax] += pagg[node * 3 + ax] / d;
        }
    }

    for (int i = tid; i < 2 * NBN * (H / 4); i += 512) {
        int rrow = i >> 5, chunk = i & 31;
        int nidx = rrow & (NBN - 1);
        int node = n0 + nidx;
        if (node >= N_NODES) node = N_NODES - 1;
        const float* src = (rrow < NBN) ? h : magg;
        f4_t v = *(const f4_t*)&src[(size_t)node * H + chunk * 4];
        bf4_t hi, lo;
        #pragma unroll
        for (int j = 0; j < 4; j++) {
            hi[j] = f2b(v[j]);
            lo[j] = f2b(v[j] - b2f(hi[j]));
        }
        int dcol = ((rrow < NBN) ? 0 : H) + chunk * 4;
        *(bf4_t*)&fH[nidx * CST + dcol] = hi;
        *(bf4_t*)&fL[nidx * CST + dcol] = lo;
    }
    __syncthreads();

    int lane = tid & 63;
    int nt = tid >> 6;
    int ln = lane & 15, quad = lane >> 4;
    int n = nt * 16 + ln;

    f4_t acc[4];
    float u1s[4][4];

    // stage A: u1 = silu(cat @ N1 + nb1), K=256
    mm_hl4(fH, fL, CST, N1h, N1l, 8, nt, lane, ln, quad, acc);
    {
        float bb = nb1[n];
        #pragma unroll
        for (int mi = 0; mi < 4; mi++)
            #pragma unroll
            for (int r = 0; r < 4; r++)
                u1s[mi][r] = silu_f(acc[mi][r] + bb);
    }
    __syncthreads();
    #pragma unroll
    for (int mi = 0; mi < 4; mi++) {
        #pragma unroll
        for (int r = 0; r < 4; r++) {
            int m = mi * 16 + quad * 4 + r;
            float v = u1s[mi][r];
            short hi = f2b(v);
            fH[m * CST + n] = hi;
            fL[m * CST + n] = f2b(v - b2f(hi));
        }
    }
    __syncthreads();

    // stage B: h_new = h + u1 @ N2 + nb2; write h, stage h_new hi/lo for P GEMMs
    mm_hl4(fH, fL, CST, N2h, N2l, 4, nt, lane, ln, quad, acc);
    __syncthreads();   // all stage-B LDS reads of u1 done before overwrite
    {
        float bb = nb2[n];
        #pragma unroll
        for (int mi = 0; mi < 4; mi++) {
            #pragma unroll
            for (int r = 0; r < 4; r++) {
                int m = mi * 16 + quad * 4 + r;
                int node = n0 + m;
                int nc = (node < N_NODES) ? node : (N_NODES - 1);
                float hn = h[(size_t)nc * H + n] + acc[mi][r] + bb;
                if (node < N_NODES) h[(size_t)node * H + n] = hn;
                short hi = f2b(hn);
                fH[m * CST + n] = hi;
                fL[m * CST + n] = f2b(hn - b2f(hi));
            }
        }
    }
    if (!doP) return;
    __syncthreads();

    // fused P GEMMs for next layer: P1 = h_new@W1a, P2 = h_new@W1b (K=128)
    f4_t accA[4], accB[4];
    #pragma unroll
    for (int mi = 0; mi < 4; mi++) { accA[mi] = (f4_t)(0.0f); accB[mi] = (f4_t)(0.0f); }
    for (int kb = 0; kb < 4; kb++) {
        int k0 = kb * 32 + quad * 8;
        int off = ((kb * 8 + nt) * 64 + lane) * 8;
        bf8_t bhA = *(const bf8_t*)&Ah[off];
        bf8_t blA = *(const bf8_t*)&Al[off];
        bf8_t bhB = *(const bf8_t*)&Bh[off];
        bf8_t blB = *(const bf8_t*)&Bl[off];
        #pragma unroll
        for (int mi = 0; mi < 4; mi++) {
            bf8_t ah = *(const bf8_t*)&fH[(mi * 16 + ln) * CST + k0];
            bf8_t al = *(const bf8_t*)&fL[(mi * 16 + ln) * CST + k0];
            accA[mi] = __builtin_amdgcn_mfma_f32_16x16x32_bf16(ah, bhA, accA[mi], 0, 0, 0);
            accA[mi] = __builtin_amdgcn_mfma_f32_16x16x32_bf16(al, bhA, accA[mi], 0, 0, 0);
            accA[mi] = __builtin_amdgcn_mfma_f32_16x16x32_bf16(ah, blA, accA[mi], 0, 0, 0);
            accB[mi] = __builtin_amdgcn_mfma_f32_16x16x32_bf16(ah, bhB, accB[mi], 0, 0, 0);
            accB[mi] = __builtin_amdgcn_mfma_f32_16x16x32_bf16(al, bhB, accB[mi], 0, 0, 0);
            accB[mi] = __builtin_amdgcn_mfma_f32_16x16x32_bf16(ah, blB, accB[mi], 0, 0, 0);
        }
    }
    #pragma unroll
    for (int mi = 0; mi < 4; mi++) {
        #pragma unroll
        for (int r = 0; r < 4; r++) {
            int node = n0 + mi * 16 + quad * 4 + r;
            if (node < N_NODES) {
                P1[(size_t)node * H + n] = accA[mi][r];
                P2[(size_t)node * H + n] = accB[mi][r];
            }
        }
    }
}

// ---------------- pooling + head ----------------
__global__ __launch_bounds__(128) void head_kernel(
    const float* __restrict__ h,
    const float* __restrict__ h1w, const float* __restrict__ h1b,
    const float* __restrict__ h2w, const float* __restrict__ h2b,
    const float* __restrict__ h3w, const float* __restrict__ h3b,
    float* __restrict__ out)
{
    __shared__ float gfeat[256];
    __shared__ float z1[128];
    __shared__ float z2[64];
    int tid = threadIdx.x;
    int g = blockIdx.x;
    size_t base = (size_t)g * NPG * H;
    float s = 0.f;
    for (int i = 0; i < NPG; i++) s += h[base + (size_t)i * H + tid];
    gfeat[tid] = s;
    gfeat[H + tid] = s / (float)NPG;
    __syncthreads();
    float a = h1b[tid];
    for (int k = 0; k < 256; k++) a = fmaf(gfeat[k], h1w[k * H + tid], a);
    z1[tid] = fmaxf(a, 0.0f);
    __syncthreads();
    if (tid < 64) {
        float a2 = h2b[tid];
        for (int k = 0; k < 128; k++) a2 = fmaf(z1[k], h2w[k * 64 + tid], a2);
        z2[tid] = fmaxf(a2, 0.0f);
    }
    __syncthreads();
    if (tid < 64) {
        float v = z2[tid] * h3w[tid];
        #pragma unroll
        for (int off = 32; off > 0; off >>= 1) v += __shfl_xor(v, off, 64);
        if (tid == 0) out[g] = v + h3b[0];
    }
}

extern "C" void kernel_launch(void* const* d_in, const int* in_sizes, int n_in,
                              void* d_out, int out_size, void* d_ws, size_t ws_size,
                              hipStream_t stream) {
    const float* x      = (const float*)d_in[0];
    const float* pos_in = (const float*)d_in[1];
    const int*   ei     = (const int*)d_in[2];
    const float* eattr  = (const float*)d_in[3];
    const float* Wp    = (const float*)d_in[6];
    const float* bp    = (const float*)d_in[7];
    const float* Wl    = (const float*)d_in[8];
    const float* bl    = (const float*)d_in[9];
    const float* gamma = (const float*)d_in[10];
    const float* beta  = (const float*)d_in[11];
    const float* ew1   = (const float*)d_in[12];
    const float* eb1   = (const float*)d_in[13];
    const float* ew2   = (const float*)d_in[14];
    const float* eb2   = (const float*)d_in[15];
    const float* cw1   = (const float*)d_in[16];
    const float* cb1   = (const float*)d_in[17];
    const float* cw2   = (const float*)d_in[18];
    const float* nw1   = (const float*)d_in[19];
    const float* nb1   = (const float*)d_in[20];
    const float* nw2   = (const float*)d_in[21];
    const float* nb2   = (const float*)d_in[22];
    const float* h1w   = (const float*)d_in[23];
    const float* h1b   = (const float*)d_in[24];
    const float* h2w   = (const float*)d_in[25];
    const float* h2b   = (const float*)d_in[26];
    const float* h3w   = (const float*)d_in[27];
    const float* h3b   = (const float*)d_in[28];
    float* out = (float*)d_out;

    float* ws   = (float*)d_ws;
    float* hbuf = ws;                                  // N*H f32
    float* magg = hbuf + (size_t)N_NODES * H;          // N*H f32
    float* P1   = magg + (size_t)N_NODES * H;          // N*H f32
    float* P2   = P1 + (size_t)N_NODES * H;            // N*H f32
    float* posb = P2 + (size_t)N_NODES * H;            // N*3
    float* pagg = posb + (size_t)N_NODES * 3;          // N*3
    float* deg  = pagg + (size_t)N_NODES * 3;          // N
    float* bnS  = deg + N_NODES;                       // 256
    float* bnP  = bnS + 256;                           // 256
    int* cnt    = (int*)(bnP + 256);                   // N
    int* basep  = cnt + N_NODES;                       // N
    int* cursor = basep + N_NODES;                     // N
    int* perm   = cursor + N_NODES;                    // E
    int* rowsS  = perm + N_EDGES;                      // E
    int szK4 = 4 * 4 * 4096;                           // K=128 weights per plane
    int szK8 = 4 * 8 * 4096;                           // K=256 weights per plane
    short* W1aH = (short*)(rowsS + N_EDGES);
    short* W1aL = W1aH + szK4;
    short* W1bH = W1aL + szK4;
    short* W1bL = W1bH + szK4;
    short* W2h  = W1bL + szK4;
    short* W2l  = W2h + szK4;
    short* W3h  = W2l + szK4;
    short* W3l  = W3h + szK4;
    short* N1h  = W3l + szK4;
    short* N1l  = N1h + szK8;
    short* N2h  = N1l + szK8;
    short* N2l  = N2h + szK4;

    hipMemcpyAsync(posb, pos_in, (size_t)N_NODES * 3 * sizeof(float),
                   hipMemcpyDeviceToDevice, stream);
    hipMemsetAsync(cnt, 0, N_NODES * sizeof(int), stream);
    hipMemsetAsync(cursor, 0, N_NODES * sizeof(int), stream);
    hipMemsetAsync(bnS, 0, 256 * sizeof(float), stream);

    hist_kernel<<<(N_EDGES + 255) / 256, 256, 0, stream>>>(ei, cnt);
    scan_kernel<<<1, 1024, 0, stream>>>(cnt, basep);
    scatter_kernel<<<(N_EDGES + 255) / 256, 256, 0, stream>>>(ei, basep, cursor, perm, rowsS);
    deg_from_cnt_kernel<<<(N_NODES + 255) / 256, 256, 0, stream>>>(cnt, deg);

    wprep_frag_kernel<<<(szK4 + 255) / 256, 256, 0, stream>>>(ew1, W1aH, W1aL, DIN, 4, 0);
    wprep_frag_kernel<<<(szK4 + 255) / 256, 256, 0, stream>>>(ew1, W1bH, W1bL, DIN, 4, H);
    wprep_frag_kernel<<<(szK4 + 255) / 256, 256, 0, stream>>>(ew2, W2h, W2l, H, 4, 0);
    wprep_frag_kernel<<<(szK4 + 255) / 256, 256, 0, stream>>>(cw1, W3h, W3l, H, 4, 0);
    wprep_frag_kernel<<<(szK8 + 255) / 256, 256, 0, stream>>>(nw1, N1h, N1l, 256, 8, 0);
    wprep_frag_kernel<<<(szK4 + 255) / 256, 256, 0, stream>>>(nw2, N2h, N2l, H, 4, 0);

    proj_kernel<<<N_NODES / NB, 128, 0, stream>>>(x, Wp, bp, Wl, bl, hbuf);
    bn_stats_kernel<<<N_NODES / NPG, 128, 0, stream>>>(hbuf, bnS);
    bn_final_kernel<<<1, 128, 0, stream>>>(bnS, gamma, beta, bnP);
    bn_apply_kernel<<<(N_NODES * H / 4) / 256, 256, 0, stream>>>(hbuf, bnP);

    int eblocks = (N_EDGES + EB2 - 1) / EB2;
    int echunk = (eblocks + 7) / 8;
    int eblocks_pad = echunk * 8;          // swizzled grid; padded blocks are no-ops
    int nblocks = (N_NODES + NBN - 1) / NBN;

    // initial P1/P2 for layer 0
    p12_kernel<<<nblocks, 512, 0, stream>>>(hbuf, W1aH, W1aL, W1bH, W1bL, P1, P2);

    for (int l = 0; l < 4; l++) {
        hipMemsetAsync(magg, 0, (size_t)N_NODES * H * sizeof(float), stream);
        hipMemsetAsync(pagg, 0, (size_t)N_NODES * 3 * sizeof(float), stream);
        edge_mfma_kernel<<<eblocks_pad, 256, 0, stream>>>(
            P1, P2, posb, ei, eattr, perm, rowsS,
            ew1 + (size_t)l * DIN * H + (size_t)2 * H * H,   // W1c rows 256..260
            eb1 + (size_t)l * H,
            W2h + (size_t)l * 4 * 4096, W2l + (size_t)l * 4 * 4096,
            W3h + (size_t)l * 4 * 4096, W3l + (size_t)l * 4 * 4096,
            eb2 + (size_t)l * H,
            cb1 + (size_t)l * H, cw2 + (size_t)l * H,
            magg, pagg);
        int lp = l + 1;
        node_mfma_kernel<<<nblocks, 512, 0, stream>>>(
            hbuf, magg, pagg, deg, posb,
            N1h + (size_t)l * 8 * 4096, N1l + (size_t)l * 8 * 4096,
            N2h + (size_t)l * 4 * 4096, N2l + (size_t)l * 4 * 4096,
            nb1 + (size_t)l * H, nb2 + (size_t)l * H,
            W1aH + (size_t)(lp & 3) * 4 * 4096, W1aL + (size_t)(lp & 3) * 4 * 4096,
            W1bH + (size_t)(lp & 3) * 4 * 4096, W1bL + (size_t)(lp & 3) * 4 * 4096,
            P1, P2, (l < 3) ? 1 : 0);
    }

    head_kernel<<<G_GRAPHS, 128, 0, stream>>>(hbuf, h1w, h1b, h2w, h2b, h3w, h3b, out);
}

// Round 11
// 1265.610 us; speedup vs baseline: 7.5834x; 1.1034x over previous
//
#include <hip/hip_runtime.h>
#include <math.h>

#define N_NODES 50000
#define N_EDGES 500000
#define G_GRAPHS 100
#define NPG 500
#define NPROT 400
#define H 128
#define PN 35
#define LN 11
#define DIN 261      // 2H + 1 + 4
#define EB2 32       // edges per block (MFMA edge kernel)
#define FS2 136      // bf16 plane row stride (272B = 68 dw, %32=4 -> 2-way, free)
#define T2S 132      // t2 fp32 staging stride (dw, %32=4 -> 2-way, free)
#define NBN 64       // nodes per block (p12 kernel)
#define NB2 32       // nodes per block (MFMA node kernel)
#define CST 264      // node cat plane stride in bf16 (2-way, free)
#define NB 16        // nodes per workgroup (proj kernel)
#define NCHUNK 49    // ceil(N_NODES / 1024) for the scan
#define EPSV 1e-5f

typedef __attribute__((ext_vector_type(8))) short bf8_t;   // 8 bf16 (4 VGPRs)
typedef __attribute__((ext_vector_type(4))) short bf4_t;
typedef __attribute__((ext_vector_type(4))) float f4_t;

__device__ __forceinline__ float silu_f(float x) {
    return x / (1.0f + __expf(-x));
}
__device__ __forceinline__ short f2b(float f) {
    __bf16 b = (__bf16)f;
    return __builtin_bit_cast(short, b);
}
__device__ __forceinline__ float b2f(short s) {
    unsigned u = ((unsigned)(unsigned short)s) << 16;
    return __builtin_bit_cast(float, u);
}

// ---- weight prep: fp32 [4][Ksrc][H] (+row offset) -> fragment-ordered bf16 hi/lo ----
__global__ void wprep_frag_kernel(const float* __restrict__ src, short* __restrict__ dstH,
                                  short* __restrict__ dstL, int Ksrc, int nkb, int koff) {
    int idx = blockIdx.x * 256 + threadIdx.x;
    int per_l = nkb * 8 * 64 * 8;
    int total = 4 * per_l;
    if (idx >= total) return;
    int l = idx / per_l;
    int rem = idx - l * per_l;
    int j = rem & 7;
    int lane = (rem >> 3) & 63;
    int nt = (rem >> 9) & 7;
    int kb = rem >> 12;
    int ln = lane & 15, quad = lane >> 4;
    int n = nt * 16 + ln;
    int k = koff + kb * 32 + quad * 8 + j;
    float v = (k < Ksrc) ? src[((size_t)l * Ksrc + k) * H + n] : 0.0f;
    short hi = f2b(v);
    dstH[idx] = hi;
    dstL[idx] = f2b(v - b2f(hi));
}

// ---------------- edge sort: counting sort by target row ----------------
__global__ void hist_kernel(const int* __restrict__ ei, int* __restrict__ cnt)
{
    int e = blockIdx.x * 256 + threadIdx.x;
    if (e < N_EDGES) atomicAdd(&cnt[ei[e]], 1);
}

// pass A: per-1024-chunk sums
__global__ __launch_bounds__(256) void bsum_kernel(const int* __restrict__ cnt, int* __restrict__ bsum)
{
    __shared__ int red[4];
    int tid = threadIdx.x;
    int i0 = blockIdx.x * 1024 + tid * 4;
    int s = 0;
    #pragma unroll
    for (int j = 0; j < 4; j++) {
        int i = i0 + j;
        if (i < N_NODES) s += cnt[i];
    }
    #pragma unroll
    for (int off = 32; off > 0; off >>= 1) s += __shfl_down(s, off, 64);
    if ((tid & 63) == 0) red[tid >> 6] = s;
    __syncthreads();
    if (tid == 0) bsum[blockIdx.x] = red[0] + red[1] + red[2] + red[3];
}

// pass B: tiny serial exclusive scan of chunk sums
__global__ void scanb_kernel(const int* __restrict__ bsum, int* __restrict__ boff)
{
    if (threadIdx.x == 0) {
        int acc = 0;
        for (int i = 0; i < NCHUNK; i++) { boff[i] = acc; acc += bsum[i]; }
    }
}

// pass C: per-chunk local exclusive scan + chunk offset
__global__ __launch_bounds__(256) void scanc_kernel(const int* __restrict__ cnt,
                                                    const int* __restrict__ boff,
                                                    int* __restrict__ base)
{
    __shared__ int ts[256];
    int tid = threadIdx.x;
    int b = blockIdx.x;
    int i0 = b * 1024 + tid * 4;
    int v0 = (i0 + 0 < N_NODES) ? cnt[i0 + 0] : 0;
    int v1 = (i0 + 1 < N_NODES) ? cnt[i0 + 1] : 0;
    int v2 = (i0 + 2 < N_NODES) ? cnt[i0 + 2] : 0;
    int v3 = (i0 + 3 < N_NODES) ? cnt[i0 + 3] : 0;
    int s0 = v0, s1 = s0 + v1, s2 = s1 + v2, s3 = s2 + v3;
    ts[tid] = s3;
    __syncthreads();
    for (int off = 1; off < 256; off <<= 1) {
        int t = (tid >= off) ? ts[tid - off] : 0;
        __syncthreads();
        ts[tid] += t;
        __syncthreads();
    }
    int excl = ((tid > 0) ? ts[tid - 1] : 0) + boff[b];
    if (i0 + 0 < N_NODES) base[i0 + 0] = excl;
    if (i0 + 1 < N_NODES) base[i0 + 1] = excl + s0;
    if (i0 + 2 < N_NODES) base[i0 + 2] = excl + s1;
    if (i0 + 3 < N_NODES) base[i0 + 3] = excl + s2;
}

__global__ void scatter_kernel(const int* __restrict__ ei, const int* __restrict__ base,
                               int* __restrict__ cursor, int* __restrict__ perm,
                               int* __restrict__ rowsS)
{
    int e = blockIdx.x * 256 + threadIdx.x;
    if (e < N_EDGES) {
        int r = ei[e];
        int p = atomicAdd(&cursor[r], 1);
        int d = base[r] + p;
        perm[d] = e;
        rowsS[d] = r;
    }
}

__global__ void deg_from_cnt_kernel(const int* __restrict__ cnt, float* __restrict__ deg)
{
    int i = blockIdx.x * 256 + threadIdx.x;
    if (i < N_NODES) deg[i] = (float)cnt[i];
}

// ---------------- projection ----------------
__global__ __launch_bounds__(128) void proj_kernel(
    const float* __restrict__ x, const float* __restrict__ Wp, const float* __restrict__ bp,
    const float* __restrict__ Wl, const float* __restrict__ bl, float* __restrict__ h)
{
    __shared__ float xs[NB][36];
    int tid = threadIdx.x;
    int n0 = blockIdx.x * NB;
    for (int idx = tid; idx < NB * PN; idx += 128) {
        int n = idx / PN, k = idx % PN;
        xs[n][k] = x[(size_t)(n0 + n) * PN + k];
    }
    __syncthreads();
    for (int n = 0; n < NB; n++) {
        int node = n0 + n;
        bool isp = (node % NPG) < NPROT;
        float acc;
        if (isp) {
            acc = bp[tid];
            for (int k = 0; k < PN; k++) acc = fmaf(xs[n][k], Wp[k * H + tid], acc);
        } else {
            acc = bl[tid];
            for (int k = 0; k < LN; k++) acc = fmaf(xs[n][k], Wl[k * H + tid], acc);
        }
        h[(size_t)node * H + tid] = acc;
    }
}

// ---------------- batchnorm ----------------
__global__ __launch_bounds__(128) void bn_stats_kernel(const float* __restrict__ h, float* __restrict__ bnS)
{
    int tid = threadIdx.x;
    size_t base = (size_t)blockIdx.x * NPG * H;
    float s1 = 0.f, s2 = 0.f;
    for (int i = 0; i < NPG; i++) {
        float v = h[base + (size_t)i * H + tid];
        s1 += v; s2 += v * v;
    }
    atomicAdd(&bnS[tid], s1);
    atomicAdd(&bnS[H + tid], s2);
}

__global__ void bn_final_kernel(const float* __restrict__ bnS, const float* __restrict__ gamma,
                                const float* __restrict__ beta, float* __restrict__ bnP)
{
    int j = threadIdx.x;
    float mu = bnS[j] / (float)N_NODES;
    float var = bnS[H + j] / (float)N_NODES - mu * mu;
    float inv = rsqrtf(var + EPSV);
    float sc = gamma[j] * inv;
    bnP[j] = sc;
    bnP[H + j] = beta[j] - mu * sc;
}

__global__ __launch_bounds__(256) void bn_apply_kernel(float* __restrict__ h, const float* __restrict__ bnP)
{
    int idx = blockIdx.x * 256 + threadIdx.x;
    float4 v = ((float4*)h)[idx];
    int j4 = (idx & 31) * 4;
    v.x = fmaf(v.x, bnP[j4 + 0], bnP[H + j4 + 0]);
    v.y = fmaf(v.y, bnP[j4 + 1], bnP[H + j4 + 1]);
    v.z = fmaf(v.z, bnP[j4 + 2], bnP[H + j4 + 2]);
    v.w = fmaf(v.w, bnP[j4 + 3], bnP[H + j4 + 3]);
    ((float4*)h)[idx] = v;
}

// ---- hi/lo bf16 MFMA k-loop: 2 m-tiles x 2 n-tiles per wave (3-term, exact) ----
__device__ __forceinline__ void mm_hl2(
    const short* fH, const short* fL, int stride,
    const short* __restrict__ WH, const short* __restrict__ WL,
    int nkb, int nt0, int lane, int ln, int quad, f4_t acc[2][2])
{
    #pragma unroll
    for (int mi = 0; mi < 2; mi++)
        #pragma unroll
        for (int ni = 0; ni < 2; ni++) acc[mi][ni] = (f4_t)(0.0f);
    for (int kb = 0; kb < nkb; kb++) {
        int k0 = kb * 32 + quad * 8;
        bf8_t ah0 = *(const bf8_t*)&fH[(ln) * stride + k0];
        bf8_t al0 = *(const bf8_t*)&fL[(ln) * stride + k0];
        bf8_t ah1 = *(const bf8_t*)&fH[(16 + ln) * stride + k0];
        bf8_t al1 = *(const bf8_t*)&fL[(16 + ln) * stride + k0];
        #pragma unroll
        for (int ni = 0; ni < 2; ni++) {
            int off = ((kb * 8 + nt0 + ni) * 64 + lane) * 8;
            bf8_t bh = *(const bf8_t*)&WH[off];
            bf8_t bl = *(const bf8_t*)&WL[off];
            acc[0][ni] = __builtin_amdgcn_mfma_f32_16x16x32_bf16(ah0, bh, acc[0][ni], 0, 0, 0);
            acc[0][ni] = __builtin_amdgcn_mfma_f32_16x16x32_bf16(al0, bh, acc[0][ni], 0, 0, 0);
            acc[0][ni] = __builtin_amdgcn_mfma_f32_16x16x32_bf16(ah0, bl, acc[0][ni], 0, 0, 0);
            acc[1][ni] = __builtin_amdgcn_mfma_f32_16x16x32_bf16(ah1, bh, acc[1][ni], 0, 0, 0);
            acc[1][ni] = __builtin_amdgcn_mfma_f32_16x16x32_bf16(al1, bh, acc[1][ni], 0, 0, 0);
            acc[1][ni] = __builtin_amdgcn_mfma_f32_16x16x32_bf16(ah1, bl, acc[1][ni], 0, 0, 0);
        }
    }
}

// ---- 2-term variant: bf16 activations (hi only) x exact hi/lo weights ----
__device__ __forceinline__ void mm_h2t(
    const short* fH, int stride,
    const short* __restrict__ WH, const short* __restrict__ WL,
    int nkb, int nt0, int lane, int ln, int quad, f4_t acc[2][2])
{
    #pragma unroll
    for (int mi = 0; mi < 2; mi++)
        #pragma unroll
        for (int ni = 0; ni < 2; ni++) acc[mi][ni] = (f4_t)(0.0f);
    for (int kb = 0; kb < nkb; kb++) {
        int k0 = kb * 32 + quad * 8;
        bf8_t ah0 = *(const bf8_t*)&fH[(ln) * stride + k0];
        bf8_t ah1 = *(const bf8_t*)&fH[(16 + ln) * stride + k0];
        #pragma unroll
        for (int ni = 0; ni < 2; ni++) {
            int off = ((kb * 8 + nt0 + ni) * 64 + lane) * 8;
            bf8_t bh = *(const bf8_t*)&WH[off];
            bf8_t bl = *(const bf8_t*)&WL[off];
            acc[0][ni] = __builtin_amdgcn_mfma_f32_16x16x32_bf16(ah0, bh, acc[0][ni], 0, 0, 0);
            acc[0][ni] = __builtin_amdgcn_mfma_f32_16x16x32_bf16(ah0, bl, acc[0][ni], 0, 0, 0);
            acc[1][ni] = __builtin_amdgcn_mfma_f32_16x16x32_bf16(ah1, bh, acc[1][ni], 0, 0, 0);
            acc[1][ni] = __builtin_amdgcn_mfma_f32_16x16x32_bf16(ah1, bl, acc[1][ni], 0, 0, 0);
        }
    }
}

// ---- hi/lo bf16 MFMA k-loop: 4 m-tiles x 1 n-tile per wave (p12 kernel, 512 thr) ----
__device__ __forceinline__ void mm_hl4(
    const short* fH, const short* fL, int stride,
    const short* __restrict__ WH, const short* __restrict__ WL,
    int nkb, int nt, int lane, int ln, int quad, f4_t acc[4])
{
    #pragma unroll
    for (int mi = 0; mi < 4; mi++) acc[mi] = (f4_t)(0.0f);
    for (int kb = 0; kb < nkb; kb++) {
        int k0 = kb * 32 + quad * 8;
        int off = ((kb * 8 + nt) * 64 + lane) * 8;
        bf8_t bh = *(const bf8_t*)&WH[off];
        bf8_t bl = *(const bf8_t*)&WL[off];
        #pragma unroll
        for (int mi = 0; mi < 4; mi++) {
            bf8_t ah = *(const bf8_t*)&fH[(mi * 16 + ln) * stride + k0];
            bf8_t al = *(const bf8_t*)&fL[(mi * 16 + ln) * stride + k0];
            acc[mi] = __builtin_amdgcn_mfma_f32_16x16x32_bf16(ah, bh, acc[mi], 0, 0, 0);
            acc[mi] = __builtin_amdgcn_mfma_f32_16x16x32_bf16(al, bh, acc[mi], 0, 0, 0);
            acc[mi] = __builtin_amdgcn_mfma_f32_16x16x32_bf16(ah, bl, acc[mi], 0, 0, 0);
        }
    }
}

// ---------------- initial node pre-projection (layer 0): P1 = h@W1a, P2 = h@W1b ----------------
__global__ __launch_bounds__(512, 4) void p12_kernel(
    const float* __restrict__ h,
    const short* __restrict__ Ah, const short* __restrict__ Al,
    const short* __restrict__ Bh, const short* __restrict__ Bl,
    float* __restrict__ P1, float* __restrict__ P2)
{
    __shared__ __align__(16) short fH[NBN * FS2];
    __shared__ __align__(16) short fL[NBN * FS2];
    int tid = threadIdx.x;
    int n0 = blockIdx.x * NBN;

    for (int i = tid; i < NBN * (H / 4); i += 512) {
        int nidx = i >> 5, chunk = i & 31;
        int node = n0 + nidx;
        if (node >= N_NODES) node = N_NODES - 1;
        f4_t v = *(const f4_t*)&h[(size_t)node * H + chunk * 4];
        bf4_t hi, lo;
        #pragma unroll
        for (int j = 0; j < 4; j++) {
            hi[j] = f2b(v[j]);
            lo[j] = f2b(v[j] - b2f(hi[j]));
        }
        *(bf4_t*)&fH[nidx * FS2 + chunk * 4] = hi;
        *(bf4_t*)&fL[nidx * FS2 + chunk * 4] = lo;
    }
    __syncthreads();

    int lane = tid & 63;
    int nt = tid >> 6;
    int ln = lane & 15, quad = lane >> 4;

    f4_t accA[4], accB[4];
    #pragma unroll
    for (int mi = 0; mi < 4; mi++) { accA[mi] = (f4_t)(0.0f); accB[mi] = (f4_t)(0.0f); }
    for (int kb = 0; kb < 4; kb++) {
        int k0 = kb * 32 + quad * 8;
        int off = ((kb * 8 + nt) * 64 + lane) * 8;
        bf8_t bhA = *(const bf8_t*)&Ah[off];
        bf8_t blA = *(const bf8_t*)&Al[off];
        bf8_t bhB = *(const bf8_t*)&Bh[off];
        bf8_t blB = *(const bf8_t*)&Bl[off];
        #pragma unroll
        for (int mi = 0; mi < 4; mi++) {
            bf8_t ah = *(const bf8_t*)&fH[(mi * 16 + ln) * FS2 + k0];
            bf8_t al = *(const bf8_t*)&fL[(mi * 16 + ln) * FS2 + k0];
            accA[mi] = __builtin_amdgcn_mfma_f32_16x16x32_bf16(ah, bhA, accA[mi], 0, 0, 0);
            accA[mi] = __builtin_amdgcn_mfma_f32_16x16x32_bf16(al, bhA, accA[mi], 0, 0, 0);
            accA[mi] = __builtin_amdgcn_mfma_f32_16x16x32_bf16(ah, blA, accA[mi], 0, 0, 0);
            accB[mi] = __builtin_amdgcn_mfma_f32_16x16x32_bf16(ah, bhB, accB[mi], 0, 0, 0);
            accB[mi] = __builtin_amdgcn_mfma_f32_16x16x32_bf16(al, bhB, accB[mi], 0, 0, 0);
            accB[mi] = __builtin_amdgcn_mfma_f32_16x16x32_bf16(ah, blB, accB[mi], 0, 0, 0);
        }
    }
    int n = nt * 16 + ln;
    #pragma unroll
    for (int mi = 0; mi < 4; mi++) {
        #pragma unroll
        for (int r = 0; r < 4; r++) {
            int node = n0 + mi * 16 + quad * 4 + r;
            if (node < N_NODES) {
                P1[(size_t)node * H + n] = accA[mi][r];
                P2[(size_t)node * H + n] = accB[mi][r];
            }
        }
    }
}

// ---------------- MFMA edge kernel (EB=32, 256 thr, 8 blocks/CU, XCD-swizzled) ----------------
__global__ __launch_bounds__(256, 8) void edge_mfma_kernel(
    const float* __restrict__ P1, const float* __restrict__ P2,
    const float* __restrict__ pos,
    const int* __restrict__ ei, const float* __restrict__ eattr,
    const int* __restrict__ perm, const int* __restrict__ rowsS,
    const float* __restrict__ W1c, const float* __restrict__ eb1,
    const short* __restrict__ W2h, const short* __restrict__ W2l,
    const short* __restrict__ W3h, const short* __restrict__ W3l,
    const float* __restrict__ eb2,
    const float* __restrict__ cb1, const float* __restrict__ cw2,
    float* __restrict__ magg, float* __restrict__ pagg)
{
    __shared__ __align__(16) short fHL[2 * EB2 * FS2];   // 17408 B; t2f fp32 overlays later
    __shared__ float relS[EB2][3];
    __shared__ float attrS[EB2][5];
    __shared__ float wpart[EB2][4];
    __shared__ int rowS[EB2];
    __shared__ int rowG[EB2];
    __shared__ int colS[EB2];

    short* fH = fHL;
    short* fL = fHL + EB2 * FS2;
    int tid = threadIdx.x;
    int chunk = gridDim.x >> 3;
    int bx = blockIdx.x;
    int bid = (bx & 7) * chunk + (bx >> 3);
    int e0 = bid * EB2;

    // --- edge meta ---
    if (tid < EB2) {
        int e = e0 + tid;
        int eidx = (e < N_EDGES) ? e : (N_EDGES - 1);
        int ec = perm[eidx];
        int r = rowsS[eidx];
        int c = ei[N_EDGES + ec];
        rowG[tid] = r;
        rowS[tid] = (e < N_EDGES) ? r : -1;
        colS[tid] = c;
        float rx = pos[r * 3 + 0] - pos[c * 3 + 0];
        float ry = pos[r * 3 + 1] - pos[c * 3 + 1];
        float rz = pos[r * 3 + 2] - pos[c * 3 + 2];
        relS[tid][0] = rx; relS[tid][1] = ry; relS[tid][2] = rz;
        attrS[tid][0] = rx * rx + ry * ry + rz * rz;
        attrS[tid][1] = eattr[(size_t)ec * 4 + 0];
        attrS[tid][2] = eattr[(size_t)ec * 4 + 1];
        attrS[tid][3] = eattr[(size_t)ec * 4 + 2];
        attrS[tid][4] = eattr[(size_t)ec * 4 + 3];
    }
    __syncthreads();

    // --- fused stage 1, pair-batched for load ILP; ch4 is invariant per thread ---
    {
        int ch4 = (tid & 31) * 4;
        f4_t bb = *(const f4_t*)&eb1[ch4];
        f4_t w0 = *(const f4_t*)&W1c[0 * H + ch4];
        f4_t w1 = *(const f4_t*)&W1c[1 * H + ch4];
        f4_t w2 = *(const f4_t*)&W1c[2 * H + ch4];
        f4_t w3 = *(const f4_t*)&W1c[3 * H + ch4];
        f4_t w4 = *(const f4_t*)&W1c[4 * H + ch4];
        #pragma unroll
        for (int b = 0; b < 2; b++) {
            int i0 = tid + b * 512;
            int i1 = i0 + 256;
            int ea = i0 >> 5;
            int eb_ = i1 >> 5;
            f4_t p1a = *(const f4_t*)&P1[(size_t)rowG[ea] * H + ch4];
            f4_t p2a = *(const f4_t*)&P2[(size_t)colS[ea] * H + ch4];
            f4_t p1b = *(const f4_t*)&P1[(size_t)rowG[eb_] * H + ch4];
            f4_t p2b = *(const f4_t*)&P2[(size_t)colS[eb_] * H + ch4];
            #pragma unroll
            for (int half = 0; half < 2; half++) {
                int e = half ? eb_ : ea;
                f4_t p1 = half ? p1b : p1a;
                f4_t p2 = half ? p2b : p2a;
                float a0 = attrS[e][0], a1 = attrS[e][1], a2 = attrS[e][2];
                float a3 = attrS[e][3], a4 = attrS[e][4];
                bf4_t hi, lo;
                #pragma unroll
                for (int j = 0; j < 4; j++) {
                    float t = p1[j] + p2[j] + bb[j];
                    t = fmaf(a0, w0[j], t);
                    t = fmaf(a1, w1[j], t);
                    t = fmaf(a2, w2[j], t);
                    t = fmaf(a3, w3[j], t);
                    t = fmaf(a4, w4[j], t);
                    float v = silu_f(t);
                    hi[j] = f2b(v);
                    lo[j] = f2b(v - b2f(hi[j]));
                }
                *(bf4_t*)&fH[e * FS2 + ch4] = hi;
                *(bf4_t*)&fL[e * FS2 + ch4] = lo;
            }
        }
    }
    __syncthreads();

    int lane = tid & 63;
    int wv = tid >> 6;            // 4 waves
    int ln = lane & 15, quad = lane >> 4;
    int nt0 = wv * 2;             // each wave: 2 n-tiles

    f4_t acc[2][2];
    float t2s[2][2][4];

    // ===== stage 2: t2 = silu(t1 @ W2 + b2), K=128 (exact 3-term) =====
    mm_hl2(fH, fL, FS2, W2h, W2l, 4, nt0, lane, ln, quad, acc);
    #pragma unroll
    for (int ni = 0; ni < 2; ni++) {
        int n = (nt0 + ni) * 16 + ln;
        float bb = eb2[n];
        #pragma unroll
        for (int mi = 0; mi < 2; mi++)
            #pragma unroll
            for (int r = 0; r < 4; r++)
                t2s[mi][ni][r] = silu_f(acc[mi][ni][r] + bb);
    }
    __syncthreads();   // all stage-2 reads of t1 done
    // t2 stored hi-only: stage 3 (pos path) tolerates bf16 activations
    #pragma unroll
    for (int ni = 0; ni < 2; ni++) {
        int n = (nt0 + ni) * 16 + ln;
        #pragma unroll
        for (int mi = 0; mi < 2; mi++) {
            #pragma unroll
            for (int r = 0; r < 4; r++) {
                int m = mi * 16 + quad * 4 + r;
                fH[m * FS2 + n] = f2b(t2s[mi][ni][r]);
            }
        }
    }
    __syncthreads();

    // ===== stage 3: w = silu(t2 @ Wc1 + cb1) @ cw2, K=128 (2-term) =====
    mm_h2t(fH, FS2, W3h, W3l, 4, nt0, lane, ln, quad, acc);
    {
        #pragma unroll
        for (int mi = 0; mi < 2; mi++) {
            #pragma unroll
            for (int r = 0; r < 4; r++) {
                float v = 0.f;
                #pragma unroll
                for (int ni = 0; ni < 2; ni++) {
                    int n = (nt0 + ni) * 16 + ln;
                    v += silu_f(acc[mi][ni][r] + cb1[n]) * cw2[n];
                }
                v += __shfl_xor(v, 1, 64);
                v += __shfl_xor(v, 2, 64);
                v += __shfl_xor(v, 4, 64);
                v += __shfl_xor(v, 8, 64);
                if (ln == 0) wpart[mi * 16 + quad * 4 + r][wv] = v;
            }
        }
    }
    __syncthreads();   // stage-3 LDS reads done -> safe to overlay t2f

    // --- stage t2 fp32 into LDS (overlay on fHL) ---
    float* t2f = (float*)fHL;   // 32 x T2S fp32 = 16896 B <= 17408 B
    #pragma unroll
    for (int ni = 0; ni < 2; ni++) {
        int n = (nt0 + ni) * 16 + ln;
        #pragma unroll
        for (int mi = 0; mi < 2; mi++)
            #pragma unroll
            for (int r = 0; r < 4; r++)
                t2f[(mi * 16 + quad * 4 + r) * T2S + n] = t2s[mi][ni][r];
    }
    __syncthreads();

    // --- segmented reduction over sorted rows (256 threads: 128 ch x 2 segs) ---
    {
        int ch = tid & 127, seg = tid >> 7;
        int ebeg = seg * 16, eend = ebeg + 16;
        float a2 = 0.f; int cur = -1;
        for (int e2 = ebeg; e2 < eend; e2++) {
            int r2 = rowS[e2];
            float v2 = t2f[e2 * T2S + ch];
            if (r2 != cur) {
                if (cur >= 0) atomicAdd(&magg[(size_t)cur * H + ch], a2);
                cur = r2; a2 = v2;
            } else a2 += v2;
        }
        if (cur >= 0) atomicAdd(&magg[(size_t)cur * H + ch], a2);
    }
    if (tid < 6) {
        int ax = tid % 3, seg = tid / 3;
        int ebeg = seg * 16, eend = ebeg + 16;
        float a2 = 0.f; int cur = -1;
        for (int e2 = ebeg; e2 < eend; e2++) {
            int r2 = rowS[e2];
            float w2 = (wpart[e2][0] + wpart[e2][1] + wpart[e2][2] + wpart[e2][3]) * relS[e2][ax];
            if (r2 != cur) {
                if (cur >= 0) atomicAdd(&pagg[(size_t)cur * 3 + ax], a2);
                cur = r2; a2 = w2;
            } else a2 += w2;
        }
        if (cur >= 0) atomicAdd(&pagg[(size_t)cur * 3 + ax], a2);
    }
}

// ---------------- MFMA node kernel (NB2=32, 256 thr) + fused next-layer P1/P2 ----------------
__global__ __launch_bounds__(256, 8) void node_mfma_kernel(
    float* __restrict__ h, const float* __restrict__ magg,
    const float* __restrict__ pagg, const float* __restrict__ deg,
    float* __restrict__ pos,
    const short* __restrict__ N1h, const short* __restrict__ N1l,
    const short* __restrict__ N2h, const short* __restrict__ N2l,
    const float* __restrict__ nb1, const float* __restrict__ nb2,
    const short* __restrict__ Ah, const short* __restrict__ Al,
    const short* __restrict__ Bh, const short* __restrict__ Bl,
    float* __restrict__ P1, float* __restrict__ P2, int doP)
{
    __shared__ __align__(16) short fH[NB2 * CST];   // 16896 B
    __shared__ __align__(16) short fL[NB2 * CST];   // 16896 B

    int tid = threadIdx.x;
    int n0 = blockIdx.x * NB2;

    if (tid < NB2 * 3) {
        int n = tid / 3, ax = tid - n * 3;
        int node = n0 + n;
        if (node < N_NODES) {
            float d = fmaxf(deg[node], 1.0f);
            pos[node * 3 + ax] += pagg[node * 3 + ax] / d;
        }
    }

    for (int i = tid; i < 2 * NB2 * (H / 4); i += 256) {
        int rrow = i >> 5, chunk = i & 31;
        int nidx = rrow & (NB2 - 1);
        int node = n0 + nidx;
        if (node >= N_NODES) node = N_NODES - 1;
        const float* src = (rrow < NB2) ? h : magg;
        f4_t v = *(const f4_t*)&src[(size_t)node * H + chunk * 4];
        bf4_t hi, lo;
        #pragma unroll
        for (int j = 0; j < 4; j++) {
            hi[j] = f2b(v[j]);
            lo[j] = f2b(v[j] - b2f(hi[j]));
        }
        int dcol = ((rrow < NB2) ? 0 : H) + chunk * 4;
        *(bf4_t*)&fH[nidx * CST + dcol] = hi;
        *(bf4_t*)&fL[nidx * CST + dcol] = lo;
    }
    __syncthreads();

    int lane = tid & 63;
    int wv = tid >> 6;
    int ln = lane & 15, quad = lane >> 4;
    int nt0 = wv * 2;

    f4_t acc[2][2];
    float u1s[2][2][4];

    // stage A: u1 = silu(cat @ N1 + nb1), K=256
    mm_hl2(fH, fL, CST, N1h, N1l, 8, nt0, lane, ln, quad, acc);
    #pragma unroll
    for (int ni = 0; ni < 2; ni++) {
        int n = (nt0 + ni) * 16 + ln;
        float bb = nb1[n];
        #pragma unroll
        for (int mi = 0; mi < 2; mi++)
            #pragma unroll
            for (int r = 0; r < 4; r++)
                u1s[mi][ni][r] = silu_f(acc[mi][ni][r] + bb);
    }
    __syncthreads();
    #pragma unroll
    for (int ni = 0; ni < 2; ni++) {
        int n = (nt0 + ni) * 16 + ln;
        #pragma unroll
        for (int mi = 0; mi < 2; mi++) {
            #pragma unroll
            for (int r = 0; r < 4; r++) {
                int m = mi * 16 + quad * 4 + r;
                float v = u1s[mi][ni][r];
                short hi = f2b(v);
                fH[m * CST + n] = hi;
                fL[m * CST + n] = f2b(v - b2f(hi));
            }
        }
    }
    __syncthreads();

    // stage B: h_new = h + u1 @ N2 + nb2; write h, stage h_new hi/lo for P GEMMs
    mm_hl2(fH, fL, CST, N2h, N2l, 4, nt0, lane, ln, quad, acc);
    __syncthreads();   // all stage-B LDS reads of u1 done before overwrite
    #pragma unroll
    for (int ni = 0; ni < 2; ni++) {
        int n = (nt0 + ni) * 16 + ln;
        float bb = nb2[n];
        #pragma unroll
        for (int mi = 0; mi < 2; mi++) {
            #pragma unroll
            for (int r = 0; r < 4; r++) {
                int m = mi * 16 + quad * 4 + r;
                int node = n0 + m;
                int nc = (node < N_NODES) ? node : (N_NODES - 1);
                float hn = h[(size_t)nc * H + n] + acc[mi][ni][r] + bb;
                if (node < N_NODES) h[(size_t)node * H + n] = hn;
                short hi = f2b(hn);
                fH[m * CST + n] = hi;
                fL[m * CST + n] = f2b(hn - b2f(hi));
            }
        }
    }
    if (!doP) return;
    __syncthreads();

    // fused P GEMMs for next layer: P1 = h_new@W1a, P2 = h_new@W1b (K=128)
    f4_t accA[2][2], accB[2][2];
    #pragma unroll
    for (int mi = 0; mi < 2; mi++)
        #pragma unroll
        for (int ni = 0; ni < 2; ni++) { accA[mi][ni] = (f4_t)(0.0f); accB[mi][ni] = (f4_t)(0.0f); }
    for (int kb = 0; kb < 4; kb++) {
        int k0 = kb * 32 + quad * 8;
        bf8_t ah0 = *(const bf8_t*)&fH[(ln) * CST + k0];
        bf8_t al0 = *(const bf8_t*)&fL[(ln) * CST + k0];
        bf8_t ah1 = *(const bf8_t*)&fH[(16 + ln) * CST + k0];
        bf8_t al1 = *(const bf8_t*)&fL[(16 + ln) * CST + k0];
        #pragma unroll
        for (int ni = 0; ni < 2; ni++) {
            int off = ((kb * 8 + nt0 + ni) * 64 + lane) * 8;
            bf8_t bhA = *(const bf8_t*)&Ah[off];
            bf8_t blA = *(const bf8_t*)&Al[off];
            bf8_t bhB = *(const bf8_t*)&Bh[off];
            bf8_t blB = *(const bf8_t*)&Bl[off];
            accA[0][ni] = __builtin_amdgcn_mfma_f32_16x16x32_bf16(ah0, bhA, accA[0][ni], 0, 0, 0);
            accA[0][ni] = __builtin_amdgcn_mfma_f32_16x16x32_bf16(al0, bhA, accA[0][ni], 0, 0, 0);
            accA[0][ni] = __builtin_amdgcn_mfma_f32_16x16x32_bf16(ah0, blA, accA[0][ni], 0, 0, 0);
            accA[1][ni] = __builtin_amdgcn_mfma_f32_16x16x32_bf16(ah1, bhA, accA[1][ni], 0, 0, 0);
            accA[1][ni] = __builtin_amdgcn_mfma_f32_16x16x32_bf16(al1, bhA, accA[1][ni], 0, 0, 0);
            accA[1][ni] = __builtin_amdgcn_mfma_f32_16x16x32_bf16(ah1, blA, accA[1][ni], 0, 0, 0);
            accB[0][ni] = __builtin_amdgcn_mfma_f32_16x16x32_bf16(ah0, bhB, accB[0][ni], 0, 0, 0);
            accB[0][ni] = __builtin_amdgcn_mfma_f32_16x16x32_bf16(al0, bhB, accB[0][ni], 0, 0, 0);
            accB[0][ni] = __builtin_amdgcn_mfma_f32_16x16x32_bf16(ah0, blB, accB[0][ni], 0, 0, 0);
            accB[1][ni] = __builtin_amdgcn_mfma_f32_16x16x32_bf16(ah1, bhB, accB[1][ni], 0, 0, 0);
            accB[1][ni] = __builtin_amdgcn_mfma_f32_16x16x32_bf16(al1, bhB, accB[1][ni], 0, 0, 0);
            accB[1][ni] = __builtin_amdgcn_mfma_f32_16x16x32_bf16(ah1, blB, accB[1][ni], 0, 0, 0);
        }
    }
    #pragma unroll
    for (int ni = 0; ni < 2; ni++) {
        int n = (nt0 + ni) * 16 + ln;
        #pragma unroll
        for (int mi = 0; mi < 2; mi++) {
            #pragma unroll
            for (int r = 0; r < 4; r++) {
                int node = n0 + mi * 16 + quad * 4 + r;
                if (node < N_NODES) {
                    P1[(size_t)node * H + n] = accA[mi][ni][r];
                    P2[(size_t)node * H + n] = accB[mi][ni][r];
                }
            }
        }
    }
}

// ---------------- pooling + head ----------------
__global__ __launch_bounds__(128) void head_kernel(
    const float* __restrict__ h,
    const float* __restrict__ h1w, const float* __restrict__ h1b,
    const float* __restrict__ h2w, const float* __restrict__ h2b,
    const float* __restrict__ h3w, const float* __restrict__ h3b,
    float* __restrict__ out)
{
    __shared__ float gfeat[256];
    __shared__ float z1[128];
    __shared__ float z2[64];
    int tid = threadIdx.x;
    int g = blockIdx.x;
    size_t base = (size_t)g * NPG * H;
    float s = 0.f;
    for (int i = 0; i < NPG; i++) s += h[base + (size_t)i * H + tid];
    gfeat[tid] = s;
    gfeat[H + tid] = s / (float)NPG;
    __syncthreads();
    float a = h1b[tid];
    for (int k = 0; k < 256; k++) a = fmaf(gfeat[k], h1w[k * H + tid], a);
    z1[tid] = fmaxf(a, 0.0f);
    __syncthreads();
    if (tid < 64) {
        float a2 = h2b[tid];
        for (int k = 0; k < 128; k++) a2 = fmaf(z1[k], h2w[k * 64 + tid], a2);
        z2[tid] = fmaxf(a2, 0.0f);
    }
    __syncthreads();
    if (tid < 64) {
        float v = z2[tid] * h3w[tid];
        #pragma unroll
        for (int off = 32; off > 0; off >>= 1) v += __shfl_xor(v, off, 64);
        if (tid == 0) out[g] = v + h3b[0];
    }
}

extern "C" void kernel_launch(void* const* d_in, const int* in_sizes, int n_in,
                              void* d_out, int out_size, void* d_ws, size_t ws_size,
                              hipStream_t stream) {
    const float* x      = (const float*)d_in[0];
    const float* pos_in = (const float*)d_in[1];
    const int*   ei     = (const int*)d_in[2];
    const float* eattr  = (const float*)d_in[3];
    const float* Wp    = (const float*)d_in[6];
    const float* bp    = (const float*)d_in[7];
    const float* Wl    = (const float*)d_in[8];
    const float* bl    = (const float*)d_in[9];
    const float* gamma = (const float*)d_in[10];
    const float* beta  = (const float*)d_in[11];
    const float* ew1   = (const float*)d_in[12];
    const float* eb1   = (const float*)d_in[13];
    const float* ew2   = (const float*)d_in[14];
    const float* eb2   = (const float*)d_in[15];
    const float* cw1   = (const float*)d_in[16];
    const float* cb1   = (const float*)d_in[17];
    const float* cw2   = (const float*)d_in[18];
    const float* nw1   = (const float*)d_in[19];
    const float* nb1   = (const float*)d_in[20];
    const float* nw2   = (const float*)d_in[21];
    const float* nb2   = (const float*)d_in[22];
    const float* h1w   = (const float*)d_in[23];
    const float* h1b   = (const float*)d_in[24];
    const float* h2w   = (const float*)d_in[25];
    const float* h2b   = (const float*)d_in[26];
    const float* h3w   = (const float*)d_in[27];
    const float* h3b   = (const float*)d_in[28];
    float* out = (float*)d_out;

    float* ws   = (float*)d_ws;
    float* hbuf = ws;                                  // N*H f32
    float* magg = hbuf + (size_t)N_NODES * H;          // N*H f32
    float* P1   = magg + (size_t)N_NODES * H;          // N*H f32
    float* P2   = P1 + (size_t)N_NODES * H;            // N*H f32
    float* posb = P2 + (size_t)N_NODES * H;            // N*3
    float* pagg = posb + (size_t)N_NODES * 3;          // N*3
    float* deg  = pagg + (size_t)N_NODES * 3;          // N
    float* bnS  = deg + N_NODES;                       // 256
    float* bnP  = bnS + 256;                           // 256
    int* cnt    = (int*)(bnP + 256);                   // N
    int* basep  = cnt + N_NODES;                       // N
    int* cursor = basep + N_NODES;                     // N
    int* perm   = cursor + N_NODES;                    // E
    int* rowsS  = perm + N_EDGES;                      // E
    int* bsum   = rowsS + N_EDGES;                     // 64
    int* boff   = bsum + 64;                           // 64
    int szK4 = 4 * 4 * 4096;                           // K=128 weights per plane
    int szK8 = 4 * 8 * 4096;                           // K=256 weights per plane
    short* W1aH = (short*)(boff + 64);
    short* W1aL = W1aH + szK4;
    short* W1bH = W1aL + szK4;
    short* W1bL = W1bH + szK4;
    short* W2h  = W1bL + szK4;
    short* W2l  = W2h + szK4;
    short* W3h  = W2l + szK4;
    short* W3l  = W3h + szK4;
    short* N1h  = W3l + szK4;
    short* N1l  = N1h + szK8;
    short* N2h  = N1l + szK8;
    short* N2l  = N2h + szK4;

    hipMemcpyAsync(posb, pos_in, (size_t)N_NODES * 3 * sizeof(float),
                   hipMemcpyDeviceToDevice, stream);
    hipMemsetAsync(cnt, 0, N_NODES * sizeof(int), stream);
    hipMemsetAsync(cursor, 0, N_NODES * sizeof(int), stream);
    hipMemsetAsync(bnS, 0, 256 * sizeof(float), stream);

    hist_kernel<<<(N_EDGES + 255) / 256, 256, 0, stream>>>(ei, cnt);
    bsum_kernel<<<NCHUNK, 256, 0, stream>>>(cnt, bsum);
    scanb_kernel<<<1, 64, 0, stream>>>(bsum, boff);
    scanc_kernel<<<NCHUNK, 256, 0, stream>>>(cnt, boff, basep);
    scatter_kernel<<<(N_EDGES + 255) / 256, 256, 0, stream>>>(ei, basep, cursor, perm, rowsS);
    deg_from_cnt_kernel<<<(N_NODES + 255) / 256, 256, 0, stream>>>(cnt, deg);

    wprep_frag_kernel<<<(szK4 + 255) / 256, 256, 0, stream>>>(ew1, W1aH, W1aL, DIN, 4, 0);
    wprep_frag_kernel<<<(szK4 + 255) / 256, 256, 0, stream>>>(ew1, W1bH, W1bL, DIN, 4, H);
    wprep_frag_kernel<<<(szK4 + 255) / 256, 256, 0, stream>>>(ew2, W2h, W2l, H, 4, 0);
    wprep_frag_kernel<<<(szK4 + 255) / 256, 256, 0, stream>>>(cw1, W3h, W3l, H, 4, 0);
    wprep_frag_kernel<<<(szK8 + 255) / 256, 256, 0, stream>>>(nw1, N1h, N1l, 256, 8, 0);
    wprep_frag_kernel<<<(szK4 + 255) / 256, 256, 0, stream>>>(nw2, N2h, N2l, H, 4, 0);

    proj_kernel<<<N_NODES / NB, 128, 0, stream>>>(x, Wp, bp, Wl, bl, hbuf);
    bn_stats_kernel<<<N_NODES / NPG, 128, 0, stream>>>(hbuf, bnS);
    bn_final_kernel<<<1, 128, 0, stream>>>(bnS, gamma, beta, bnP);
    bn_apply_kernel<<<(N_NODES * H / 4) / 256, 256, 0, stream>>>(hbuf, bnP);

    int eblocks = (N_EDGES + EB2 - 1) / EB2;
    int echunk = (eblocks + 7) / 8;
    int eblocks_pad = echunk * 8;
    int nblocks = (N_NODES + NBN - 1) / NBN;     // p12 (64-node)
    int nblocks2 = (N_NODES + NB2 - 1) / NB2;    // node kernel (32-node)

    // initial P1/P2 for layer 0
    p12_kernel<<<nblocks, 512, 0, stream>>>(hbuf, W1aH, W1aL, W1bH, W1bL, P1, P2);

    for (int l = 0; l < 4; l++) {
        hipMemsetAsync(magg, 0, (size_t)N_NODES * H * sizeof(float), stream);
        hipMemsetAsync(pagg, 0, (size_t)N_NODES * 3 * sizeof(float), stream);
        edge_mfma_kernel<<<eblocks_pad, 256, 0, stream>>>(
            P1, P2, posb, ei, eattr, perm, rowsS,
            ew1 + (size_t)l * DIN * H + (size_t)2 * H * H,   // W1c rows 256..260
            eb1 + (size_t)l * H,
            W2h + (size_t)l * 4 * 4096, W2l + (size_t)l * 4 * 4096,
            W3h + (size_t)l * 4 * 4096, W3l + (size_t)l * 4 * 4096,
            eb2 + (size_t)l * H,
            cb1 + (size_t)l * H, cw2 + (size_t)l * H,
            magg, pagg);
        int lp = l + 1;
        node_mfma_kernel<<<nblocks2, 256, 0, stream>>>(
            hbuf, magg, pagg, deg, posb,
            N1h + (size_t)l * 8 * 4096, N1l + (size_t)l * 8 * 4096,
            N2h + (size_t)l * 4 * 4096, N2l + (size_t)l * 4 * 4096,
            nb1 + (size_t)l * H, nb2 + (size_t)l * H,
            W1aH + (size_t)(lp & 3) * 4 * 4096, W1aL + (size_t)(lp & 3) * 4 * 4096,
            W1bH + (size_t)(lp & 3) * 4 * 4096, W1bL + (size_t)(lp & 3) * 4 * 4096,
            P1, P2, (l < 3) ? 1 : 0);
    }

    head_kernel<<<G_GRAPHS, 128, 0, stream>>>(hbuf, h1w, h1b, h2w, h2b, h3w, h3b, out);
}

// Round 13
// 1097.362 us; speedup vs baseline: 8.7460x; 1.1533x over previous
//
#include <hip/hip_runtime.h>
#include <math.h>

#define N_NODES 50000
#define N_EDGES 500000
#define G_GRAPHS 100
#define NPG 500
#define NPROT 400
#define H 128
#define PN 35
#define LN 11
#define DIN 261      // 2H + 1 + 4
#define EB2 32       // edges per block (MFMA edge kernel)
#define FS2 136      // bf16 plane row stride (272B = 68 dw, %32=4 -> 2-way, free)
#define T2S 132      // t2 fp32 staging stride (dw, %32=4 -> 2-way, free)
#define NBN 64       // nodes per block (p12 kernel)
#define NB2 32       // nodes per block (MFMA node kernel)
#define CST 264      // node cat plane stride in bf16 (2-way, free)
#define NB 16        // nodes per workgroup (proj kernel)
#define NCHUNK 49    // ceil(N_NODES / 1024) for the scan
#define EPSV 1e-5f

typedef __attribute__((ext_vector_type(8))) short bf8_t;   // 8 bf16 (4 VGPRs)
typedef __attribute__((ext_vector_type(4))) short bf4_t;
typedef __attribute__((ext_vector_type(4))) float f4_t;

// fast silu: v_exp + v_rcp (~1ulp) instead of IEEE div sequence
__device__ __forceinline__ float silu_f(float x) {
    return x * __builtin_amdgcn_rcpf(1.0f + __expf(-x));
}
// RNE bf16 (weight prep only)
__device__ __forceinline__ short f2b(float f) {
    __bf16 b = (__bf16)f;
    return __builtin_bit_cast(short, b);
}
__device__ __forceinline__ float b2f(short s) {
    unsigned u = ((unsigned)(unsigned short)s) << 16;
    return __builtin_bit_cast(float, u);
}
// fast round-half-up bf16 (2 int ops) - error <= 2^-9 rel, same bound as RNE
__device__ __forceinline__ short f2b_fast(float f) {
    unsigned b = __builtin_bit_cast(unsigned, f);
    return (short)((b + 0x8000u) >> 16);
}
// fast hi/lo split: hi rounded-half-up, lo = bf16(v - hi) (value-returning)
__device__ __forceinline__ short2 split_hl(float v) {
    unsigned b = __builtin_bit_cast(unsigned, v);
    unsigned hr = (b + 0x8000u) & 0xFFFF0000u;
    float lf = v - __builtin_bit_cast(float, hr);   // exact (hi within 2^-9 of v)
    unsigned lb = __builtin_bit_cast(unsigned, lf);
    short2 r;
    r.x = (short)(hr >> 16);
    r.y = (short)((lb + 0x8000u) >> 16);
    return r;
}

// ---- combined weight prep: all 6 weight groups in one launch ----
// dst layout per group: [l][kb][nt][lane][8] (fragment-ordered)
__global__ __launch_bounds__(256) void wprep_all_kernel(
    const float* __restrict__ ew1, const float* __restrict__ ew2,
    const float* __restrict__ cw1, const float* __restrict__ nw1,
    const float* __restrict__ nw2,
    short* __restrict__ W1aH, short* __restrict__ W1aL,
    short* __restrict__ W1bH, short* __restrict__ W1bL,
    short* __restrict__ W2h, short* __restrict__ W2l,
    short* __restrict__ W3h, short* __restrict__ W3l,
    short* __restrict__ N1h, short* __restrict__ N1l,
    short* __restrict__ N2h, short* __restrict__ N2l)
{
    int idx = blockIdx.x * 256 + threadIdx.x;
    const float* src; short *dh, *dl; int Ksrc, nkb, koff, base;
    if (idx < 65536)       { src = ew1; dh = W1aH; dl = W1aL; Ksrc = DIN; nkb = 4; koff = 0; base = 0; }
    else if (idx < 131072) { src = ew1; dh = W1bH; dl = W1bL; Ksrc = DIN; nkb = 4; koff = H; base = 65536; }
    else if (idx < 196608) { src = ew2; dh = W2h;  dl = W2l;  Ksrc = H;   nkb = 4; koff = 0; base = 131072; }
    else if (idx < 262144) { src = cw1; dh = W3h;  dl = W3l;  Ksrc = H;   nkb = 4; koff = 0; base = 196608; }
    else if (idx < 393216) { src = nw1; dh = N1h;  dl = N1l;  Ksrc = 256; nkb = 8; koff = 0; base = 262144; }
    else if (idx < 458752) { src = nw2; dh = N2h;  dl = N2l;  Ksrc = H;   nkb = 4; koff = 0; base = 393216; }
    else return;
    int rem0 = idx - base;
    int per_l = nkb * 8 * 64 * 8;
    int l = rem0 / per_l;
    int rem = rem0 - l * per_l;
    int j = rem & 7;
    int lane = (rem >> 3) & 63;
    int nt = (rem >> 9) & 7;
    int kb = rem >> 12;
    int ln = lane & 15, quad = lane >> 4;
    int n = nt * 16 + ln;
    int k = koff + kb * 32 + quad * 8 + j;
    float v = (k < Ksrc) ? src[((size_t)l * Ksrc + k) * H + n] : 0.0f;
    short hi = f2b(v);                       // RNE for weights
    dh[rem0] = hi;
    dl[rem0] = f2b(v - b2f(hi));
}

// ---------------- edge sort: counting sort by target row ----------------
__global__ void hist_kernel(const int* __restrict__ ei, int* __restrict__ cnt)
{
    int e = blockIdx.x * 256 + threadIdx.x;
    if (e < N_EDGES) atomicAdd(&cnt[ei[e]], 1);
}

__global__ __launch_bounds__(256) void bsum_kernel(const int* __restrict__ cnt, int* __restrict__ bsum)
{
    __shared__ int red[4];
    int tid = threadIdx.x;
    int i0 = blockIdx.x * 1024 + tid * 4;
    int s = 0;
    #pragma unroll
    for (int j = 0; j < 4; j++) {
        int i = i0 + j;
        if (i < N_NODES) s += cnt[i];
    }
    #pragma unroll
    for (int off = 32; off > 0; off >>= 1) s += __shfl_down(s, off, 64);
    if ((tid & 63) == 0) red[tid >> 6] = s;
    __syncthreads();
    if (tid == 0) bsum[blockIdx.x] = red[0] + red[1] + red[2] + red[3];
}

__global__ void scanb_kernel(const int* __restrict__ bsum, int* __restrict__ boff)
{
    if (threadIdx.x == 0) {
        int acc = 0;
        for (int i = 0; i < NCHUNK; i++) { boff[i] = acc; acc += bsum[i]; }
    }
}

// pass C: per-chunk local exclusive scan + chunk offset; also emits deg
__global__ __launch_bounds__(256) void scanc_kernel(const int* __restrict__ cnt,
                                                    const int* __restrict__ boff,
                                                    int* __restrict__ base,
                                                    float* __restrict__ deg)
{
    __shared__ int ts[256];
    int tid = threadIdx.x;
    int b = blockIdx.x;
    int i0 = b * 1024 + tid * 4;
    int v0 = (i0 + 0 < N_NODES) ? cnt[i0 + 0] : 0;
    int v1 = (i0 + 1 < N_NODES) ? cnt[i0 + 1] : 0;
    int v2 = (i0 + 2 < N_NODES) ? cnt[i0 + 2] : 0;
    int v3 = (i0 + 3 < N_NODES) ? cnt[i0 + 3] : 0;
    int s0 = v0, s1 = s0 + v1, s2 = s1 + v2, s3 = s2 + v3;
    ts[tid] = s3;
    __syncthreads();
    for (int off = 1; off < 256; off <<= 1) {
        int t = (tid >= off) ? ts[tid - off] : 0;
        __syncthreads();
        ts[tid] += t;
        __syncthreads();
    }
    int excl = ((tid > 0) ? ts[tid - 1] : 0) + boff[b];
    if (i0 + 0 < N_NODES) { base[i0 + 0] = excl;      deg[i0 + 0] = (float)v0; }
    if (i0 + 1 < N_NODES) { base[i0 + 1] = excl + s0; deg[i0 + 1] = (float)v1; }
    if (i0 + 2 < N_NODES) { base[i0 + 2] = excl + s1; deg[i0 + 2] = (float)v2; }
    if (i0 + 3 < N_NODES) { base[i0 + 3] = excl + s2; deg[i0 + 3] = (float)v3; }
}

__global__ void scatter_kernel(const int* __restrict__ ei, const int* __restrict__ base,
                               int* __restrict__ cursor, int* __restrict__ perm,
                               int* __restrict__ rowsS)
{
    int e = blockIdx.x * 256 + threadIdx.x;
    if (e < N_EDGES) {
        int r = ei[e];
        int p = atomicAdd(&cursor[r], 1);
        int d = base[r] + p;
        perm[d] = e;
        rowsS[d] = r;
    }
}

// ---------------- projection ----------------
__global__ __launch_bounds__(128) void proj_kernel(
    const float* __restrict__ x, const float* __restrict__ Wp, const float* __restrict__ bp,
    const float* __restrict__ Wl, const float* __restrict__ bl, float* __restrict__ h)
{
    __shared__ float xs[NB][36];
    int tid = threadIdx.x;
    int n0 = blockIdx.x * NB;
    for (int idx = tid; idx < NB * PN; idx += 128) {
        int n = idx / PN, k = idx % PN;
        xs[n][k] = x[(size_t)(n0 + n) * PN + k];
    }
    __syncthreads();
    for (int n = 0; n < NB; n++) {
        int node = n0 + n;
        bool isp = (node % NPG) < NPROT;
        float acc;
        if (isp) {
            acc = bp[tid];
            for (int k = 0; k < PN; k++) acc = fmaf(xs[n][k], Wp[k * H + tid], acc);
        } else {
            acc = bl[tid];
            for (int k = 0; k < LN; k++) acc = fmaf(xs[n][k], Wl[k * H + tid], acc);
        }
        h[(size_t)node * H + tid] = acc;
    }
}

// ---------------- batchnorm ----------------
__global__ __launch_bounds__(128) void bn_stats_kernel(const float* __restrict__ h, float* __restrict__ bnS)
{
    int tid = threadIdx.x;
    size_t base = (size_t)blockIdx.x * NPG * H;
    float s1 = 0.f, s2 = 0.f;
    for (int i = 0; i < NPG; i++) {
        float v = h[base + (size_t)i * H + tid];
        s1 += v; s2 += v * v;
    }
    atomicAdd(&bnS[tid], s1);
    atomicAdd(&bnS[H + tid], s2);
}

__global__ void bn_final_kernel(const float* __restrict__ bnS, const float* __restrict__ gamma,
                                const float* __restrict__ beta, float* __restrict__ bnP)
{
    int j = threadIdx.x;
    float mu = bnS[j] / (float)N_NODES;
    float var = bnS[H + j] / (float)N_NODES - mu * mu;
    float inv = rsqrtf(var + EPSV);
    float sc = gamma[j] * inv;
    bnP[j] = sc;
    bnP[H + j] = beta[j] - mu * sc;
}

__global__ __launch_bounds__(256) void bn_apply_kernel(float* __restrict__ h, const float* __restrict__ bnP)
{
    int idx = blockIdx.x * 256 + threadIdx.x;
    float4 v = ((float4*)h)[idx];
    int j4 = (idx & 31) * 4;
    v.x = fmaf(v.x, bnP[j4 + 0], bnP[H + j4 + 0]);
    v.y = fmaf(v.y, bnP[j4 + 1], bnP[H + j4 + 1]);
    v.z = fmaf(v.z, bnP[j4 + 2], bnP[H + j4 + 2]);
    v.w = fmaf(v.w, bnP[j4 + 3], bnP[H + j4 + 3]);
    ((float4*)h)[idx] = v;
}

// ---- hi/lo bf16 MFMA k-loop: 2 m-tiles x 2 n-tiles per wave (3-term) ----
__device__ __forceinline__ void mm_hl2(
    const short* fH, const short* fL, int stride,
    const short* __restrict__ WH, const short* __restrict__ WL,
    int nkb, int nt0, int lane, int ln, int quad, f4_t acc[2][2])
{
    #pragma unroll
    for (int mi = 0; mi < 2; mi++)
        #pragma unroll
        for (int ni = 0; ni < 2; ni++) acc[mi][ni] = (f4_t)(0.0f);
    for (int kb = 0; kb < nkb; kb++) {
        int k0 = kb * 32 + quad * 8;
        bf8_t ah0 = *(const bf8_t*)&fH[(ln) * stride + k0];
        bf8_t al0 = *(const bf8_t*)&fL[(ln) * stride + k0];
        bf8_t ah1 = *(const bf8_t*)&fH[(16 + ln) * stride + k0];
        bf8_t al1 = *(const bf8_t*)&fL[(16 + ln) * stride + k0];
        #pragma unroll
        for (int ni = 0; ni < 2; ni++) {
            int off = ((kb * 8 + nt0 + ni) * 64 + lane) * 8;
            bf8_t bh = *(const bf8_t*)&WH[off];
            bf8_t bl = *(const bf8_t*)&WL[off];
            acc[0][ni] = __builtin_amdgcn_mfma_f32_16x16x32_bf16(ah0, bh, acc[0][ni], 0, 0, 0);
            acc[0][ni] = __builtin_amdgcn_mfma_f32_16x16x32_bf16(al0, bh, acc[0][ni], 0, 0, 0);
            acc[0][ni] = __builtin_amdgcn_mfma_f32_16x16x32_bf16(ah0, bl, acc[0][ni], 0, 0, 0);
            acc[1][ni] = __builtin_amdgcn_mfma_f32_16x16x32_bf16(ah1, bh, acc[1][ni], 0, 0, 0);
            acc[1][ni] = __builtin_amdgcn_mfma_f32_16x16x32_bf16(al1, bh, acc[1][ni], 0, 0, 0);
            acc[1][ni] = __builtin_amdgcn_mfma_f32_16x16x32_bf16(ah1, bl, acc[1][ni], 0, 0, 0);
        }
    }
}

// ---- 2-term variant: bf16 activations (hi only) x exact hi/lo weights ----
__device__ __forceinline__ void mm_h2t(
    const short* fH, int stride,
    const short* __restrict__ WH, const short* __restrict__ WL,
    int nkb, int nt0, int lane, int ln, int quad, f4_t acc[2][2])
{
    #pragma unroll
    for (int mi = 0; mi < 2; mi++)
        #pragma unroll
        for (int ni = 0; ni < 2; ni++) acc[mi][ni] = (f4_t)(0.0f);
    for (int kb = 0; kb < nkb; kb++) {
        int k0 = kb * 32 + quad * 8;
        bf8_t ah0 = *(const bf8_t*)&fH[(ln) * stride + k0];
        bf8_t ah1 = *(const bf8_t*)&fH[(16 + ln) * stride + k0];
        #pragma unroll
        for (int ni = 0; ni < 2; ni++) {
            int off = ((kb * 8 + nt0 + ni) * 64 + lane) * 8;
            bf8_t bh = *(const bf8_t*)&WH[off];
            bf8_t bl = *(const bf8_t*)&WL[off];
            acc[0][ni] = __builtin_amdgcn_mfma_f32_16x16x32_bf16(ah0, bh, acc[0][ni], 0, 0, 0);
            acc[0][ni] = __builtin_amdgcn_mfma_f32_16x16x32_bf16(ah0, bl, acc[0][ni], 0, 0, 0);
            acc[1][ni] = __builtin_amdgcn_mfma_f32_16x16x32_bf16(ah1, bh, acc[1][ni], 0, 0, 0);
            acc[1][ni] = __builtin_amdgcn_mfma_f32_16x16x32_bf16(ah1, bl, acc[1][ni], 0, 0, 0);
        }
    }
}

// ---------------- initial node pre-projection (layer 0) ----------------
__global__ __launch_bounds__(512, 4) void p12_kernel(
    const float* __restrict__ h,
    const short* __restrict__ Ah, const short* __restrict__ Al,
    const short* __restrict__ Bh, const short* __restrict__ Bl,
    float* __restrict__ P1, float* __restrict__ P2)
{
    __shared__ __align__(16) short fH[NBN * FS2];
    __shared__ __align__(16) short fL[NBN * FS2];
    int tid = threadIdx.x;
    int n0 = blockIdx.x * NBN;

    for (int i = tid; i < NBN * (H / 4); i += 512) {
        int nidx = i >> 5, chunk = i & 31;
        int node = n0 + nidx;
        if (node >= N_NODES) node = N_NODES - 1;
        f4_t v = *(const f4_t*)&h[(size_t)node * H + chunk * 4];
        bf4_t hi, lo;
        #pragma unroll
        for (int j = 0; j < 4; j++) {
            short2 s = split_hl(v[j]);
            hi[j] = s.x; lo[j] = s.y;
        }
        *(bf4_t*)&fH[nidx * FS2 + chunk * 4] = hi;
        *(bf4_t*)&fL[nidx * FS2 + chunk * 4] = lo;
    }
    __syncthreads();

    int lane = tid & 63;
    int nt = tid >> 6;
    int ln = lane & 15, quad = lane >> 4;

    f4_t accA[4], accB[4];
    #pragma unroll
    for (int mi = 0; mi < 4; mi++) { accA[mi] = (f4_t)(0.0f); accB[mi] = (f4_t)(0.0f); }
    for (int kb = 0; kb < 4; kb++) {
        int k0 = kb * 32 + quad * 8;
        int off = ((kb * 8 + nt) * 64 + lane) * 8;
        bf8_t bhA = *(const bf8_t*)&Ah[off];
        bf8_t blA = *(const bf8_t*)&Al[off];
        bf8_t bhB = *(const bf8_t*)&Bh[off];
        bf8_t blB = *(const bf8_t*)&Bl[off];
        #pragma unroll
        for (int mi = 0; mi < 4; mi++) {
            bf8_t ah = *(const bf8_t*)&fH[(mi * 16 + ln) * FS2 + k0];
            bf8_t al = *(const bf8_t*)&fL[(mi * 16 + ln) * FS2 + k0];
            accA[mi] = __builtin_amdgcn_mfma_f32_16x16x32_bf16(ah, bhA, accA[mi], 0, 0, 0);
            accA[mi] = __builtin_amdgcn_mfma_f32_16x16x32_bf16(al, bhA, accA[mi], 0, 0, 0);
            accA[mi] = __builtin_amdgcn_mfma_f32_16x16x32_bf16(ah, blA, accA[mi], 0, 0, 0);
            accB[mi] = __builtin_amdgcn_mfma_f32_16x16x32_bf16(ah, bhB, accB[mi], 0, 0, 0);
            accB[mi] = __builtin_amdgcn_mfma_f32_16x16x32_bf16(al, bhB, accB[mi], 0, 0, 0);
            accB[mi] = __builtin_amdgcn_mfma_f32_16x16x32_bf16(ah, blB, accB[mi], 0, 0, 0);
        }
    }
    int n = nt * 16 + ln;
    #pragma unroll
    for (int mi = 0; mi < 4; mi++) {
        #pragma unroll
        for (int r = 0; r < 4; r++) {
            int node = n0 + mi * 16 + quad * 4 + r;
            if (node < N_NODES) {
                P1[(size_t)node * H + n] = accA[mi][r];
                P2[(size_t)node * H + n] = accB[mi][r];
            }
        }
    }
}

// ---------------- MFMA edge kernel (EB=32, 256 thr, 8 blocks/CU, XCD-swizzled) ----------------
__global__ __launch_bounds__(256, 8) void edge_mfma_kernel(
    const float* __restrict__ P1, const float* __restrict__ P2,
    const float* __restrict__ pos,
    const int* __restrict__ ei, const float* __restrict__ eattr,
    const int* __restrict__ perm, const int* __restrict__ rowsS,
    const float* __restrict__ W1c, const float* __restrict__ eb1,
    const short* __restrict__ W2h, const short* __restrict__ W2l,
    const short* __restrict__ W3h, const short* __restrict__ W3l,
    const float* __restrict__ eb2,
    const float* __restrict__ cb1, const float* __restrict__ cw2,
    float* __restrict__ magg, float* __restrict__ pagg)
{
    __shared__ __align__(16) short fHL[2 * EB2 * FS2];   // 17408 B; t2f fp32 overlays later
    __shared__ float relS[EB2][3];
    __shared__ float attrS[EB2][5];
    __shared__ float wpart[EB2][4];
    __shared__ int rowS[EB2];
    __shared__ int rowG[EB2];
    __shared__ int colS[EB2];

    short* fH = fHL;
    short* fL = fHL + EB2 * FS2;
    int tid = threadIdx.x;
    int chunk = gridDim.x >> 3;
    int bx = blockIdx.x;
    int bid = (bx & 7) * chunk + (bx >> 3);
    int e0 = bid * EB2;

    // --- edge meta ---
    if (tid < EB2) {
        int e = e0 + tid;
        int eidx = (e < N_EDGES) ? e : (N_EDGES - 1);
        int ec = perm[eidx];
        int r = rowsS[eidx];
        int c = ei[N_EDGES + ec];
        rowG[tid] = r;
        rowS[tid] = (e < N_EDGES) ? r : -1;
        colS[tid] = c;
        float rx = pos[r * 3 + 0] - pos[c * 3 + 0];
        float ry = pos[r * 3 + 1] - pos[c * 3 + 1];
        float rz = pos[r * 3 + 2] - pos[c * 3 + 2];
        relS[tid][0] = rx; relS[tid][1] = ry; relS[tid][2] = rz;
        attrS[tid][0] = rx * rx + ry * ry + rz * rz;
        attrS[tid][1] = eattr[(size_t)ec * 4 + 0];
        attrS[tid][2] = eattr[(size_t)ec * 4 + 1];
        attrS[tid][3] = eattr[(size_t)ec * 4 + 2];
        attrS[tid][4] = eattr[(size_t)ec * 4 + 3];
    }
    __syncthreads();

    // --- fused stage 1, pair-batched for load ILP ---
    {
        int ch4 = (tid & 31) * 4;
        f4_t bb = *(const f4_t*)&eb1[ch4];
        f4_t w0 = *(const f4_t*)&W1c[0 * H + ch4];
        f4_t w1 = *(const f4_t*)&W1c[1 * H + ch4];
        f4_t w2 = *(const f4_t*)&W1c[2 * H + ch4];
        f4_t w3 = *(const f4_t*)&W1c[3 * H + ch4];
        f4_t w4 = *(const f4_t*)&W1c[4 * H + ch4];
        #pragma unroll
        for (int b = 0; b < 2; b++) {
            int i0 = tid + b * 512;
            int i1 = i0 + 256;
            int ea = i0 >> 5;
            int eb_ = i1 >> 5;
            f4_t p1a = *(const f4_t*)&P1[(size_t)rowG[ea] * H + ch4];
            f4_t p2a = *(const f4_t*)&P2[(size_t)colS[ea] * H + ch4];
            f4_t p1b = *(const f4_t*)&P1[(size_t)rowG[eb_] * H + ch4];
            f4_t p2b = *(const f4_t*)&P2[(size_t)colS[eb_] * H + ch4];
            #pragma unroll
            for (int half = 0; half < 2; half++) {
                int e = half ? eb_ : ea;
                f4_t p1 = half ? p1b : p1a;
                f4_t p2 = half ? p2b : p2a;
                float a0 = attrS[e][0], a1 = attrS[e][1], a2 = attrS[e][2];
                float a3 = attrS[e][3], a4 = attrS[e][4];
                bf4_t hi, lo;
                #pragma unroll
                for (int j = 0; j < 4; j++) {
                    float t = p1[j] + p2[j] + bb[j];
                    t = fmaf(a0, w0[j], t);
                    t = fmaf(a1, w1[j], t);
                    t = fmaf(a2, w2[j], t);
                    t = fmaf(a3, w3[j], t);
                    t = fmaf(a4, w4[j], t);
                    float v = silu_f(t);
                    short2 s = split_hl(v);
                    hi[j] = s.x; lo[j] = s.y;
                }
                *(bf4_t*)&fH[e * FS2 + ch4] = hi;
                *(bf4_t*)&fL[e * FS2 + ch4] = lo;
            }
        }
    }
    __syncthreads();

    int lane = tid & 63;
    int wv = tid >> 6;            // 4 waves
    int ln = lane & 15, quad = lane >> 4;
    int nt0 = wv * 2;             // each wave: 2 n-tiles

    f4_t acc[2][2];
    float t2s[2][2][4];

    // ===== stage 2: t2 = silu(t1 @ W2 + b2), K=128 (3-term) =====
    mm_hl2(fH, fL, FS2, W2h, W2l, 4, nt0, lane, ln, quad, acc);
    #pragma unroll
    for (int ni = 0; ni < 2; ni++) {
        int n = (nt0 + ni) * 16 + ln;
        float bb = eb2[n];
        #pragma unroll
        for (int mi = 0; mi < 2; mi++)
            #pragma unroll
            for (int r = 0; r < 4; r++)
                t2s[mi][ni][r] = silu_f(acc[mi][ni][r] + bb);
    }
    __syncthreads();   // all stage-2 reads of t1 done
    // t2 stored hi-only: stage 3 (pos path) tolerates bf16 activations
    #pragma unroll
    for (int ni = 0; ni < 2; ni++) {
        int n = (nt0 + ni) * 16 + ln;
        #pragma unroll
        for (int mi = 0; mi < 2; mi++) {
            #pragma unroll
            for (int r = 0; r < 4; r++) {
                int m = mi * 16 + quad * 4 + r;
                fH[m * FS2 + n] = f2b_fast(t2s[mi][ni][r]);
            }
        }
    }
    __syncthreads();

    // ===== stage 3: w = silu(t2 @ Wc1 + cb1) @ cw2, K=128 (2-term) =====
    mm_h2t(fH, FS2, W3h, W3l, 4, nt0, lane, ln, quad, acc);
    {
        #pragma unroll
        for (int mi = 0; mi < 2; mi++) {
            #pragma unroll
            for (int r = 0; r < 4; r++) {
                float v = 0.f;
                #pragma unroll
                for (int ni = 0; ni < 2; ni++) {
                    int n = (nt0 + ni) * 16 + ln;
                    v += silu_f(acc[mi][ni][r] + cb1[n]) * cw2[n];
                }
                v += __shfl_xor(v, 1, 64);
                v += __shfl_xor(v, 2, 64);
                v += __shfl_xor(v, 4, 64);
                v += __shfl_xor(v, 8, 64);
                if (ln == 0) wpart[mi * 16 + quad * 4 + r][wv] = v;
            }
        }
    }
    __syncthreads();   // stage-3 LDS reads done -> safe to overlay t2f

    // --- stage t2 fp32 into LDS (overlay on fHL) ---
    float* t2f = (float*)fHL;
    #pragma unroll
    for (int ni = 0; ni < 2; ni++) {
        int n = (nt0 + ni) * 16 + ln;
        #pragma unroll
        for (int mi = 0; mi < 2; mi++)
            #pragma unroll
            for (int r = 0; r < 4; r++)
                t2f[(mi * 16 + quad * 4 + r) * T2S + n] = t2s[mi][ni][r];
    }
    __syncthreads();

    // --- segmented reduction over sorted rows (256 threads: 128 ch x 2 segs) ---
    {
        int ch = tid & 127, seg = tid >> 7;
        int ebeg = seg * 16, eend = ebeg + 16;
        float a2 = 0.f; int cur = -1;
        for (int e2 = ebeg; e2 < eend; e2++) {
            int r2 = rowS[e2];
            float v2 = t2f[e2 * T2S + ch];
            if (r2 != cur) {
                if (cur >= 0) atomicAdd(&magg[(size_t)cur * H + ch], a2);
                cur = r2; a2 = v2;
            } else a2 += v2;
        }
        if (cur >= 0) atomicAdd(&magg[(size_t)cur * H + ch], a2);
    }
    if (tid < 6) {
        int ax = tid % 3, seg = tid / 3;
        int ebeg = seg * 16, eend = ebeg + 16;
        float a2 = 0.f; int cur = -1;
        for (int e2 = ebeg; e2 < eend; e2++) {
            int r2 = rowS[e2];
            float w2 = (wpart[e2][0] + wpart[e2][1] + wpart[e2][2] + wpart[e2][3]) * relS[e2][ax];
            if (r2 != cur) {
                if (cur >= 0) atomicAdd(&pagg[(size_t)cur * 3 + ax], a2);
                cur = r2; a2 = w2;
            } else a2 += w2;
        }
        if (cur >= 0) atomicAdd(&pagg[(size_t)cur * 3 + ax], a2);
    }
}

// ---------------- MFMA node kernel (NB2=32, 256 thr) + fused next-layer P1/P2 ----------------
// Also zero-fills magg/pagg in place (replaces per-layer memsets).
__global__ __launch_bounds__(256, 8) void node_mfma_kernel(
    float* __restrict__ h, float* __restrict__ magg,
    float* __restrict__ pagg, const float* __restrict__ deg,
    float* __restrict__ pos,
    const short* __restrict__ N1h, const short* __restrict__ N1l,
    const short* __restrict__ N2h, const short* __restrict__ N2l,
    const float* __restrict__ nb1, const float* __restrict__ nb2,
    const short* __restrict__ Ah, const short* __restrict__ Al,
    const short* __restrict__ Bh, const short* __restrict__ Bl,
    float* __restrict__ P1, float* __restrict__ P2, int doP)
{
    __shared__ __align__(16) short fH[NB2 * CST];   // 16896 B
    __shared__ __align__(16) short fL[NB2 * CST];   // 16896 B

    int tid = threadIdx.x;
    int n0 = blockIdx.x * NB2;

    if (tid < NB2 * 3) {
        int n = tid / 3, ax = tid - n * 3;
        int node = n0 + n;
        if (node < N_NODES) {
            float d = fmaxf(deg[node], 1.0f);
            pos[node * 3 + ax] += pagg[node * 3 + ax] / d;
            if (doP) pagg[node * 3 + ax] = 0.0f;   // reset for next layer
        }
    }

    for (int i = tid; i < 2 * NB2 * (H / 4); i += 256) {
        int rrow = i >> 5, chunk = i & 31;
        int nidx = rrow & (NB2 - 1);
        int node0 = n0 + nidx;
        int node = (node0 < N_NODES) ? node0 : (N_NODES - 1);
        const float* src = (rrow < NB2) ? h : magg;
        f4_t v = *(const f4_t*)&src[(size_t)node * H + chunk * 4];
        // zero magg in place for next layer (owner thread only; clamped rows skip)
        if (rrow >= NB2 && doP && node0 < N_NODES)
            *(f4_t*)&magg[(size_t)node * H + chunk * 4] = (f4_t)(0.0f);
        bf4_t hi, lo;
        #pragma unroll
        for (int j = 0; j < 4; j++) {
            short2 s = split_hl(v[j]);
            hi[j] = s.x; lo[j] = s.y;
        }
        int dcol = ((rrow < NB2) ? 0 : H) + chunk * 4;
        *(bf4_t*)&fH[nidx * CST + dcol] = hi;
        *(bf4_t*)&fL[nidx * CST + dcol] = lo;
    }
    __syncthreads();

    int lane = tid & 63;
    int wv = tid >> 6;
    int ln = lane & 15, quad = lane >> 4;
    int nt0 = wv * 2;

    f4_t acc[2][2];
    float u1s[2][2][4];

    // stage A: u1 = silu(cat @ N1 + nb1), K=256
    mm_hl2(fH, fL, CST, N1h, N1l, 8, nt0, lane, ln, quad, acc);
    #pragma unroll
    for (int ni = 0; ni < 2; ni++) {
        int n = (nt0 + ni) * 16 + ln;
        float bb = nb1[n];
        #pragma unroll
        for (int mi = 0; mi < 2; mi++)
            #pragma unroll
            for (int r = 0; r < 4; r++)
                u1s[mi][ni][r] = silu_f(acc[mi][ni][r] + bb);
    }
    __syncthreads();
    #pragma unroll
    for (int ni = 0; ni < 2; ni++) {
        int n = (nt0 + ni) * 16 + ln;
        #pragma unroll
        for (int mi = 0; mi < 2; mi++) {
            #pragma unroll
            for (int r = 0; r < 4; r++) {
                int m = mi * 16 + quad * 4 + r;
                short2 s = split_hl(u1s[mi][ni][r]);
                fH[m * CST + n] = s.x;
                fL[m * CST + n] = s.y;
            }
        }
    }
    __syncthreads();

    // stage B: h_new = h + u1 @ N2 + nb2; write h, stage h_new hi/lo for P GEMMs
    mm_hl2(fH, fL, CST, N2h, N2l, 4, nt0, lane, ln, quad, acc);
    __syncthreads();   // all stage-B LDS reads of u1 done before overwrite
    #pragma unroll
    for (int ni = 0; ni < 2; ni++) {
        int n = (nt0 + ni) * 16 + ln;
        float bb = nb2[n];
        #pragma unroll
        for (int mi = 0; mi < 2; mi++) {
            #pragma unroll
            for (int r = 0; r < 4; r++) {
                int m = mi * 16 + quad * 4 + r;
                int node = n0 + m;
                int nc = (node < N_NODES) ? node : (N_NODES - 1);
                float hn = h[(size_t)nc * H + n] + acc[mi][ni][r] + bb;
                if (node < N_NODES) h[(size_t)node * H + n] = hn;
                short2 s = split_hl(hn);
                fH[m * CST + n] = s.x;
                fL[m * CST + n] = s.y;
            }
        }
    }
    if (!doP) return;
    __syncthreads();

    // fused P GEMMs for next layer: P1 = h_new@W1a, P2 = h_new@W1b (K=128)
    f4_t accA[2][2], accB[2][2];
    #pragma unroll
    for (int mi = 0; mi < 2; mi++)
        #pragma unroll
        for (int ni = 0; ni < 2; ni++) { accA[mi][ni] = (f4_t)(0.0f); accB[mi][ni] = (f4_t)(0.0f); }
    for (int kb = 0; kb < 4; kb++) {
        int k0 = kb * 32 + quad * 8;
        bf8_t ah0 = *(const bf8_t*)&fH[(ln) * CST + k0];
        bf8_t al0 = *(const bf8_t*)&fL[(ln) * CST + k0];
        bf8_t ah1 = *(const bf8_t*)&fH[(16 + ln) * CST + k0];
        bf8_t al1 = *(const bf8_t*)&fL[(16 + ln) * CST + k0];
        #pragma unroll
        for (int ni = 0; ni < 2; ni++) {
            int off = ((kb * 8 + nt0 + ni) * 64 + lane) * 8;
            bf8_t bhA = *(const bf8_t*)&Ah[off];
            bf8_t blA = *(const bf8_t*)&Al[off];
            bf8_t bhB = *(const bf8_t*)&Bh[off];
            bf8_t blB = *(const bf8_t*)&Bl[off];
            accA[0][ni] = __builtin_amdgcn_mfma_f32_16x16x32_bf16(ah0, bhA, accA[0][ni], 0, 0, 0);
            accA[0][ni] = __builtin_amdgcn_mfma_f32_16x16x32_bf16(al0, bhA, accA[0][ni], 0, 0, 0);
            accA[0][ni] = __builtin_amdgcn_mfma_f32_16x16x32_bf16(ah0, blA, accA[0][ni], 0, 0, 0);
            accA[1][ni] = __builtin_amdgcn_mfma_f32_16x16x32_bf16(ah1, bhA, accA[1][ni], 0, 0, 0);
            accA[1][ni] = __builtin_amdgcn_mfma_f32_16x16x32_bf16(al1, bhA, accA[1][ni], 0, 0, 0);
            accA[1][ni] = __builtin_amdgcn_mfma_f32_16x16x32_bf16(ah1, blA, accA[1][ni], 0, 0, 0);
            accB[0][ni] = __builtin_amdgcn_mfma_f32_16x16x32_bf16(ah0, bhB, accB[0][ni], 0, 0, 0);
            accB[0][ni] = __builtin_amdgcn_mfma_f32_16x16x32_bf16(al0, bhB, accB[0][ni], 0, 0, 0);
            accB[0][ni] = __builtin_amdgcn_mfma_f32_16x16x32_bf16(ah0, blB, accB[0][ni], 0, 0, 0);
            accB[1][ni] = __builtin_amdgcn_mfma_f32_16x16x32_bf16(ah1, bhB, accB[1][ni], 0, 0, 0);
            accB[1][ni] = __builtin_amdgcn_mfma_f32_16x16x32_bf16(al1, bhB, accB[1][ni], 0, 0, 0);
            accB[1][ni] = __builtin_amdgcn_mfma_f32_16x16x32_bf16(ah1, blB, accB[1][ni], 0, 0, 0);
        }
    }
    #pragma unroll
    for (int ni = 0; ni < 2; ni++) {
        int n = (nt0 + ni) * 16 + ln;
        #pragma unroll
        for (int mi = 0; mi < 2; mi++) {
            #pragma unroll
            for (int r = 0; r < 4; r++) {
                int node = n0 + mi * 16 + quad * 4 + r;
                if (node < N_NODES) {
                    P1[(size_t)node * H + n] = accA[mi][ni][r];
                    P2[(size_t)node * H + n] = accB[mi][ni][r];
                }
            }
        }
    }
}

// ---------------- pooling + head ----------------
__global__ __launch_bounds__(128) void head_kernel(
    const float* __restrict__ h,
    const float* __restrict__ h1w, const float* __restrict__ h1b,
    const float* __restrict__ h2w, const float* __restrict__ h2b,
    const float* __restrict__ h3w, const float* __restrict__ h3b,
    float* __restrict__ out)
{
    __shared__ float gfeat[256];
    __shared__ float z1[128];
    __shared__ float z2[64];
    int tid = threadIdx.x;
    int g = blockIdx.x;
    size_t base = (size_t)g * NPG * H;
    float s = 0.f;
    for (int i = 0; i < NPG; i++) s += h[base + (size_t)i * H + tid];
    gfeat[tid] = s;
    gfeat[H + tid] = s / (float)NPG;
    __syncthreads();
    float a = h1b[tid];
    for (int k = 0; k < 256; k++) a = fmaf(gfeat[k], h1w[k * H + tid], a);
    z1[tid] = fmaxf(a, 0.0f);
    __syncthreads();
    if (tid < 64) {
        float a2 = h2b[tid];
        for (int k = 0; k < 128; k++) a2 = fmaf(z1[k], h2w[k * 64 + tid], a2);
        z2[tid] = fmaxf(a2, 0.0f);
    }
    __syncthreads();
    if (tid < 64) {
        float v = z2[tid] * h3w[tid];
        #pragma unroll
        for (int off = 32; off > 0; off >>= 1) v += __shfl_xor(v, off, 64);
        if (tid == 0) out[g] = v + h3b[0];
    }
}

extern "C" void kernel_launch(void* const* d_in, const int* in_sizes, int n_in,
                              void* d_out, int out_size, void* d_ws, size_t ws_size,
                              hipStream_t stream) {
    const float* x      = (const float*)d_in[0];
    const float* pos_in = (const float*)d_in[1];
    const int*   ei     = (const int*)d_in[2];
    const float* eattr  = (const float*)d_in[3];
    const float* Wp    = (const float*)d_in[6];
    const float* bp    = (const float*)d_in[7];
    const float* Wl    = (const float*)d_in[8];
    const float* bl    = (const float*)d_in[9];
    const float* gamma = (const float*)d_in[10];
    const float* beta  = (const float*)d_in[11];
    const float* ew1   = (const float*)d_in[12];
    const float* eb1   = (const float*)d_in[13];
    const float* ew2   = (const float*)d_in[14];
    const float* eb2   = (const float*)d_in[15];
    const float* cw1   = (const float*)d_in[16];
    const float* cb1   = (const float*)d_in[17];
    const float* cw2   = (const float*)d_in[18];
    const float* nw1   = (const float*)d_in[19];
    const float* nb1   = (const float*)d_in[20];
    const float* nw2   = (const float*)d_in[21];
    const float* nb2   = (const float*)d_in[22];
    const float* h1w   = (const float*)d_in[23];
    const float* h1b   = (const float*)d_in[24];
    const float* h2w   = (const float*)d_in[25];
    const float* h2b   = (const float*)d_in[26];
    const float* h3w   = (const float*)d_in[27];
    const float* h3b   = (const float*)d_in[28];
    float* out = (float*)d_out;

    float* ws   = (float*)d_ws;
    float* hbuf = ws;                                  // N*H f32
    float* magg = hbuf + (size_t)N_NODES * H;          // N*H f32
    float* P1   = magg + (size_t)N_NODES * H;          // N*H f32
    float* P2   = P1 + (size_t)N_NODES * H;            // N*H f32
    float* posb = P2 + (size_t)N_NODES * H;            // N*3
    float* pagg = posb + (size_t)N_NODES * 3;          // N*3
    float* deg  = pagg + (size_t)N_NODES * 3;          // N
    float* bnS  = deg + N_NODES;                       // 256
    float* bnP  = bnS + 256;                           // 256
    int* cnt    = (int*)(bnP + 256);                   // N
    int* basep  = cnt + N_NODES;                       // N
    int* cursor = basep + N_NODES;                     // N
    int* perm   = cursor + N_NODES;                    // E
    int* rowsS  = perm + N_EDGES;                      // E
    int* bsum   = rowsS + N_EDGES;                     // 64
    int* boff   = bsum + 64;                           // 64
    int szK4 = 4 * 4 * 4096;                           // K=128 weights per plane
    int szK8 = 4 * 8 * 4096;                           // K=256 weights per plane
    short* W1aH = (short*)(boff + 64);
    short* W1aL = W1aH + szK4;
    short* W1bH = W1aL + szK4;
    short* W1bL = W1bH + szK4;
    short* W2h  = W1bL + szK4;
    short* W2l  = W2h + szK4;
    short* W3h  = W2l + szK4;
    short* W3l  = W3h + szK4;
    short* N1h  = W3l + szK4;
    short* N1l  = N1h + szK8;
    short* N2h  = N1l + szK8;
    short* N2l  = N2h + szK4;

    (void)hipMemcpyAsync(posb, pos_in, (size_t)N_NODES * 3 * sizeof(float),
                         hipMemcpyDeviceToDevice, stream);
    (void)hipMemsetAsync(cnt, 0, N_NODES * sizeof(int), stream);
    (void)hipMemsetAsync(cursor, 0, N_NODES * sizeof(int), stream);
    (void)hipMemsetAsync(bnS, 0, 256 * sizeof(float), stream);
    (void)hipMemsetAsync(magg, 0, (size_t)N_NODES * H * sizeof(float), stream);
    (void)hipMemsetAsync(pagg, 0, (size_t)N_NODES * 3 * sizeof(float), stream);

    hist_kernel<<<(N_EDGES + 255) / 256, 256, 0, stream>>>(ei, cnt);
    bsum_kernel<<<NCHUNK, 256, 0, stream>>>(cnt, bsum);
    scanb_kernel<<<1, 64, 0, stream>>>(bsum, boff);
    scanc_kernel<<<NCHUNK, 256, 0, stream>>>(cnt, boff, basep, deg);
    scatter_kernel<<<(N_EDGES + 255) / 256, 256, 0, stream>>>(ei, basep, cursor, perm, rowsS);

    wprep_all_kernel<<<458752 / 256, 256, 0, stream>>>(
        ew1, ew2, cw1, nw1, nw2,
        W1aH, W1aL, W1bH, W1bL, W2h, W2l, W3h, W3l, N1h, N1l, N2h, N2l);

    proj_kernel<<<N_NODES / NB, 128, 0, stream>>>(x, Wp, bp, Wl, bl, hbuf);
    bn_stats_kernel<<<N_NODES / NPG, 128, 0, stream>>>(hbuf, bnS);
    bn_final_kernel<<<1, 128, 0, stream>>>(bnS, gamma, beta, bnP);
    bn_apply_kernel<<<(N_NODES * H / 4) / 256, 256, 0, stream>>>(hbuf, bnP);

    int eblocks = (N_EDGES + EB2 - 1) / EB2;
    int echunk = (eblocks + 7) / 8;
    int eblocks_pad = echunk * 8;
    int nblocks = (N_NODES + NBN - 1) / NBN;     // p12 (64-node)
    int nblocks2 = (N_NODES + NB2 - 1) / NB2;    // node kernel (32-node)

    // initial P1/P2 for layer 0
    p12_kernel<<<nblocks, 512, 0, stream>>>(hbuf, W1aH, W1aL, W1bH, W1bL, P1, P2);

    for (int l = 0; l < 4; l++) {
        edge_mfma_kernel<<<eblocks_pad, 256, 0, stream>>>(
            P1, P2, posb, ei, eattr, perm, rowsS,
            ew1 + (size_t)l * DIN * H + (size_t)2 * H * H,   // W1c rows 256..260
            eb1 + (size_t)l * H,
            W2h + (size_t)l * 4 * 4096, W2l + (size_t)l * 4 * 4096,
            W3h + (size_t)l * 4 * 4096, W3l + (size_t)l * 4 * 4096,
            eb2 + (size_t)l * H,
            cb1 + (size_t)l * H, cw2 + (size_t)l * H,
            magg, pagg);
        int lp = l + 1;
        node_mfma_kernel<<<nblocks2, 256, 0, stream>>>(
            hbuf, magg, pagg, deg, posb,
            N1h + (size_t)l * 8 * 4096, N1l + (size_t)l * 8 * 4096,
            N2h + (size_t)l * 4 * 4096, N2l + (size_t)l * 4 * 4096,
            nb1 + (size_t)l * H, nb2 + (size_t)l * H,
            W1aH + (size_t)(lp & 3) * 4 * 4096, W1aL + (size_t)(lp & 3) * 4 * 4096,
            W1bH + (size_t)(lp & 3) * 4 * 4096, W1bL + (size_t)(lp & 3) * 4 * 4096,
            P1, P2, (l < 3) ? 1 : 0);
    }

    head_kernel<<<G_GRAPHS, 128, 0, stream>>>(hbuf, h1w, h1b, h2w, h2b, h3w, h3b, out);
}